// Round 10
// baseline (430.620 us; speedup 1.0000x reference)
//
#include <hip/hip_runtime.h>
#include <hip/hip_bf16.h>

// RGCN forward, MI355X. N=100000, E=400000, IN=OUT=256, R=200, B=32.
// Tier A: prep1{wgen|slwpk|hist+feat} -> prep2{etype-scan|deg-blocksums} ->
// prep3{deg-scan} -> prep4{scatter: gsrc/ginv/gout} -> selfA GEMM ->
// barrier-free edge GEMM (wave = 32 rows x 64 cols, acc[2][4]=32 AGPR ->
// ~4 waves/SIMD; msg rows written at DST-SORTED positions) -> sequential
// streaming aggregate (half-wave per node).

#define NN 100000
#define EE 400000
#define RR 200
#define BB 32
#define MAXTILES 6464   // >= E/64 + R ; divisible by 8
#define TQ (MAXTILES / 8)        // 808 tiles per XCD
#define SCHUNK 2048
#define NSCAN ((NN + 255) / 256) // 391

typedef __attribute__((ext_vector_type(8))) short short8v;   // 8 x bf16 (16B)
typedef __attribute__((ext_vector_type(4))) float f32x4;

__device__ __forceinline__ unsigned short f2bf(float f) {
  unsigned u = __float_as_uint(f);
  u += 0x7FFF + ((u >> 16) & 1);          // RNE
  return (unsigned short)(u >> 16);
}
__device__ __forceinline__ float bf2f(unsigned short h) {
  return __uint_as_float(((unsigned)h) << 16);
}

// ---------------------------------------------------------------------------
// prep1: blocks [0,800): wgen (L2-blocked W_r pack); [800,832): slwpk;
// [832,1344): etype hist + dst degree + (FEAT) f32->bf16 feature convert.
// W_pk layout per relation: [ct=16][kt=8][lane=64][j=8] bf16 where
//   value = W_r[k = kt*32 + (lane>>4)*8 + j][n = ct*16 + (lane&15)].
template <bool FEAT>
__global__ __launch_bounds__(256) void k_prep1(
    const float* __restrict__ basis, const float* __restrict__ coef,
    const float* __restrict__ slw, const int* __restrict__ etype,
    const int* __restrict__ dst, const float* __restrict__ in_feat,
    short* __restrict__ wpk, short* __restrict__ spk,
    int* __restrict__ hist, int* __restrict__ deg,
    unsigned short* __restrict__ featb) {
  __shared__ int lh[RR];
  int b = blockIdx.x, tid = threadIdx.x;
  if (b < 800) {                       // ---- wgen ----
    int ord = (b & 7) * 100 + (b >> 3);
    int rg = ord % 25;
    int pk8 = (ord / 25) * 256 + tid;
    int lane = pk8 & 63;
    int kt = (pk8 >> 6) & 7;
    int ct = pk8 >> 9;
    int n  = ct * 16 + (lane & 15);
    int k0 = kt * 32 + ((lane >> 4) << 3);
    float acc[8][8];
#pragma unroll
    for (int r = 0; r < 8; ++r)
#pragma unroll
      for (int j = 0; j < 8; ++j) acc[r][j] = 0.f;
    for (int bb = 0; bb < BB; ++bb) {
      float bas[8];
#pragma unroll
      for (int j = 0; j < 8; ++j) bas[j] = basis[bb * 65536 + (k0 + j) * 256 + n];
#pragma unroll
      for (int r = 0; r < 8; ++r) {
        float c = coef[(rg * 8 + r) * BB + bb];
#pragma unroll
        for (int j = 0; j < 8; ++j) acc[r][j] += c * bas[j];
      }
    }
#pragma unroll
    for (int r = 0; r < 8; ++r) {
      short8v v;
#pragma unroll
      for (int j = 0; j < 8; ++j) v[j] = (short)f2bf(acc[r][j]);
      *(short8v*)(wpk + (size_t)(rg * 8 + r) * 65536 + (size_t)pk8 * 8) = v;
    }
    return;
  }
  if (b < 832) {                       // ---- slwpk ----
    int t = (b - 800) * 256 + tid;
    int lane = t & 63;
    int kt = (t >> 6) & 7;
    int ct = t >> 9;
    int n  = ct * 16 + (lane & 15);
    int k0 = kt * 32 + ((lane >> 4) << 3);
    short8v v;
#pragma unroll
    for (int j = 0; j < 8; ++j) v[j] = (short)f2bf(slw[(k0 + j) * 256 + n]);
    *(short8v*)(spk + (size_t)t * 8) = v;
    return;
  }
  // ---- hist + deg + feat ----
  int hb = b - 832;                    // 512 blocks
  for (int i = tid; i < RR; i += 256) lh[i] = 0;
  __syncthreads();
  for (int e = hb * 256 + tid; e < EE; e += 512 * 256) {
    atomicAdd(&lh[etype[e]], 1);
    atomicAdd(&deg[dst[e]], 1);
  }
  if (FEAT) {
    const int total = NN * 64;         // float4 count
    for (int i = hb * 256 + tid; i < total; i += 512 * 256) {
      float4 v = ((const float4*)in_feat)[i];
      ushort4 h;
      h.x = f2bf(v.x); h.y = f2bf(v.y); h.z = f2bf(v.z); h.w = f2bf(v.w);
      ((ushort4*)featb)[i] = h;
    }
  }
  __syncthreads();
  for (int i = tid; i < RR; i += 256)
    if (lh[i]) atomicAdd(&hist[i], lh[i]);
}

// ---------------------------------------------------------------------------
// prep2: block 0: etype-bin scan -> cur + tdesc; blocks 1..391: deg block sums.
__global__ __launch_bounds__(256) void k_prep2(const int* __restrict__ hist,
                                               const int* __restrict__ deg,
                                               int* __restrict__ cur,
                                               int4* __restrict__ tdesc,
                                               int* __restrict__ bsum) {
  __shared__ int h[RR];
  __shared__ int off[RR];
  __shared__ int toff[RR];
  __shared__ int tot;
  __shared__ int ws4[4];
  int b = blockIdx.x, tid = threadIdx.x;
  if (b == 0) {
    for (int i = tid; i < RR; i += 256) h[i] = hist[i];
    __syncthreads();
    if (tid == 0) {
      int s = 0, ts = 0;
      for (int r = 0; r < RR; ++r) {
        off[r] = s; s += h[r];
        toff[r] = ts; ts += (h[r] + 63) >> 6;
      }
      tot = ts;
    }
    __syncthreads();
    if (tid < RR) {
      int r = tid, cnt = h[r], base = off[r], to = toff[r];
      cur[r] = base;
      int nt = (cnt + 63) >> 6;
      for (int t2 = 0; t2 < nt; ++t2)
        tdesc[to + t2] = make_int4(r, base + t2 * 64, min(64, cnt - t2 * 64), 0);
    }
    for (int i = tot + tid; i < MAXTILES; i += 256)
      tdesc[i] = make_int4(0, 0, 0, 0);
    return;
  }
  int i = (b - 1) * 256 + tid;
  int v = (i < NN) ? deg[i] : 0;
#pragma unroll
  for (int d = 32; d; d >>= 1) v += __shfl_down(v, d, 64);
  if ((tid & 63) == 0) ws4[tid >> 6] = v;
  __syncthreads();
  if (tid == 0) bsum[b - 1] = ws4[0] + ws4[1] + ws4[2] + ws4[3];
}

// prep3 (tier A): deg exclusive scan -> row_ptr/cur2; bsum prefix inline.
__global__ __launch_bounds__(256) void k_prep3(const int* __restrict__ deg,
                                               const int* __restrict__ bsum,
                                               int* __restrict__ row_ptr,
                                               int* __restrict__ cur2) {
  __shared__ int ws4[4];
  __shared__ int wo4[4];
  __shared__ int psum[4];
  int tid = threadIdx.x, b = blockIdx.x;
  int sp = 0;
  for (int i = tid; i < b; i += 256) sp += bsum[i];
#pragma unroll
  for (int d = 32; d; d >>= 1) sp += __shfl_down(sp, d, 64);
  if ((tid & 63) == 0) psum[tid >> 6] = sp;
  int i = b * 256 + tid;
  int v = (i < NN) ? deg[i] : 0;
  int x = v;
#pragma unroll
  for (int d = 1; d < 64; d <<= 1) {
    int y = __shfl_up(x, d, 64);
    if ((tid & 63) >= d) x += y;
  }
  if ((tid & 63) == 63) ws4[tid >> 6] = x;
  __syncthreads();
  if (tid == 0) {
    int s = 0;
    for (int w2 = 0; w2 < 4; ++w2) { wo4[w2] = s; s += ws4[w2]; }
    psum[0] = psum[0] + psum[1] + psum[2] + psum[3];
  }
  __syncthreads();
  int excl = x - v + wo4[tid >> 6] + psum[0];
  if (i < NN) { row_ptr[i] = excl; cur2[i] = excl; }
  if (i == 0 && b == 0) row_ptr[NN] = EE;
}

// prep4: counting-sort scatter; materializes per-position gsrc/gdst/ginv and
// (DL) gout[s] = dst-sorted msg slot (inverse of the old dlist).
template <bool DL>
__global__ __launch_bounds__(256) void k_prep4(const int* __restrict__ etype,
                                               const int* __restrict__ src,
                                               const int* __restrict__ dst,
                                               const int* __restrict__ deg,
                                               int* __restrict__ cur,
                                               int* __restrict__ gsrc,
                                               int* __restrict__ gdst,
                                               float* __restrict__ ginv,
                                               int* __restrict__ cur2,
                                               int* __restrict__ gout) {
  __shared__ int lh[RR];
  __shared__ int lbase[RR];
  __shared__ int lcur[RR];
  int tid = threadIdx.x;
  int e0 = blockIdx.x * SCHUNK;
  for (int i = tid; i < RR; i += 256) lh[i] = 0;
  __syncthreads();
  for (int i = tid; i < SCHUNK; i += 256) {
    int e = e0 + i;
    if (e < EE) atomicAdd(&lh[etype[e]], 1);
  }
  __syncthreads();
  for (int i = tid; i < RR; i += 256) {
    int c = lh[i];
    lbase[i] = c ? atomicAdd(&cur[i], c) : 0;
    lcur[i] = 0;
  }
  __syncthreads();
  for (int i = tid; i < SCHUNK; i += 256) {
    int e = e0 + i;
    if (e < EE) {
      int et = etype[e];
      int s = lbase[et] + atomicAdd(&lcur[et], 1);
      int d = dst[e];
      gsrc[s] = src[e];
      gdst[s] = d;
      ginv[s] = 1.0f / (float)max(deg[d], 1);
      if (DL) {
        int pos = atomicAdd(&cur2[d], 1);
        gout[s] = pos;
      }
    }
  }
}

// ---------------------------------------------------------------------------
// Tier A edge GEMM, barrier-free, HIGH-OCCUPANCY. 256 threads = 4 independent
// waves. Wave = (tile, rowhalf rh, colquad cq): 32 rows x 64 cols, acc[2][4]
// = 32 AGPR, b[4]+a[2] = 48 live VGPR -> ~105 unified -> ~4 waves/SIMD.
// 2 blocks per tile (rh 0/1), paired onto the SAME XCD; a block's 4 waves
// share 32 A-rows -> L1 reuse. msg rows stored at DST-SORTED slot gout[s].
// Wave-private 4KB LDS repack (r9's zero-conflict XOR pattern).
__global__ __launch_bounds__(256) void k_edgeW2(
    const unsigned short* __restrict__ featb, const short* __restrict__ wpk,
    const int* __restrict__ gsrc, const float* __restrict__ ginv,
    const int* __restrict__ gout, const int4* __restrict__ tdesc,
    unsigned short* __restrict__ msg) {
  __shared__ __align__(16) unsigned short lM[4][2048];   // 4KB per wave
  __shared__ float lL[4][32];
  int tid = threadIdx.x, wave = tid >> 6, lane = tid & 63;
  int l15 = lane & 15, lg = lane >> 4;
  int bid = blockIdx.x;
  int xcd = bid & 7;
  int local = bid >> 3;                 // 0..1615
  int rh = local & 1;                   // row half
  int tile = xcd * TQ + (local >> 1);   // both halves on same XCD
  int cq = wave;                        // col quad 0..3
  int4 d = tdesc[tile];
  int rows = d.z;
  if (rows <= 0) return;
  int r = d.x, rs = d.y;
  int rbase = rs + rh * 32;
  if (lane < 32) lL[wave][lane] = ginv[min(rbase + lane, EE - 1)];
  int arow[2];
#pragma unroll
  for (int m = 0; m < 2; ++m) arow[m] = gsrc[min(rbase + m * 16 + l15, EE - 1)];
  f32x4 acc[2][4];
#pragma unroll
  for (int m = 0; m < 2; ++m)
#pragma unroll
    for (int c = 0; c < 4; ++c) acc[m][c] = (f32x4){0.f, 0.f, 0.f, 0.f};
  const short* bp = wpk + (size_t)r * 65536 +
                    (size_t)(cq * 4) * 4096 + (size_t)lane * 8;
#pragma unroll
  for (int kt = 0; kt < 8; ++kt) {
    short8v b[4], a[2];
#pragma unroll
    for (int c = 0; c < 4; ++c) b[c] = *(const short8v*)(bp + c * 4096 + kt * 512);
#pragma unroll
    for (int m = 0; m < 2; ++m)
      a[m] = *(const short8v*)(featb + (size_t)arow[m] * 256 + kt * 32 + lg * 8);
#pragma unroll
    for (int m = 0; m < 2; ++m)
#pragma unroll
      for (int c = 0; c < 4; ++c)
        acc[m][c] = __builtin_amdgcn_mfma_f32_16x16x32_bf16(a[m], b[c], acc[m][c], 0, 0, 0);
  }
  // epilogue: scale + repack via wave-private LDS (32 rows x 64 cols,
  // pos = col ^ ((row&7)<<3) -- r9's measured-zero-conflict pattern)
  unsigned short* w = lM[wave];
#pragma unroll
  for (int m = 0; m < 2; ++m)
#pragma unroll
    for (int j = 0; j < 4; ++j) {
      int rl = m * 16 + lg * 4 + j;     // local row 0..31
      float inv = lL[wave][rl];
      int sw = (rl & 7) << 3;
#pragma unroll
      for (int c = 0; c < 4; ++c) {
        int col = c * 16 + l15;
        w[rl * 64 + (col ^ sw)] = f2bf(acc[m][c][j] * inv);
      }
    }
  // same-wave RAW through LDS -> lgkmcnt ordering only, no barrier
#pragma unroll
  for (int u = 0; u < 4; ++u) {
    int idx = u * 64 + lane;
    int rl = idx >> 3, chunk = idx & 7;
    short8v vv = *(const short8v*)(w + rl * 64 + ((chunk ^ (rl & 7)) << 3));
    int grow = rh * 32 + rl;
    if (grow < rows) {
      int pos = gout[rs + grow];
      *(short8v*)(msg + (size_t)pos * 256 + cq * 64 + chunk * 8) = vv;
    }
  }
}

// ---------------------------------------------------------------------------
// Tier A self-loop GEMM: out[n] = featb[n] @ slw (f32 out, direct store).
__global__ __launch_bounds__(256) void k_selfA(const unsigned short* __restrict__ featb,
                                               const short* __restrict__ spk,
                                               float* __restrict__ out) {
  __shared__ __align__(16) char lA[32768];
  int tid = threadIdx.x, wave = tid >> 6, lane = tid & 63;
  int l15 = lane & 15, lg = lane >> 4;
  int n0 = blockIdx.x * 64;
  short8v sv[8];
#pragma unroll
  for (int u = 0; u < 8; ++u) {
    int idx = u * 256 + tid;
    int row = idx >> 5, q = idx & 31;
    int n = min(n0 + row, NN - 1);
    sv[u] = *(const short8v*)(featb + (size_t)n * 256 + q * 8);
  }
#pragma unroll
  for (int u = 0; u < 8; ++u) {
    int idx = u * 256 + tid;
    int row = idx >> 5, q = idx & 31;
    *(short8v*)(lA + ((row * 512 + q * 16) ^ ((row & 7) << 4))) = sv[u];
  }
  __syncthreads();
  f32x4 acc[4][4];
#pragma unroll
  for (int m = 0; m < 4; ++m)
#pragma unroll
    for (int c = 0; c < 4; ++c) acc[m][c] = (f32x4){0.f, 0.f, 0.f, 0.f};
  const short* bp = spk + (size_t)wave * 4 * 4096 + (size_t)lane * 8;
#pragma unroll
  for (int kt = 0; kt < 8; ++kt) {
    short8v a[4], b[4];
#pragma unroll
    for (int c = 0; c < 4; ++c) b[c] = *(const short8v*)(bp + c * 4096 + kt * 512);
#pragma unroll
    for (int m = 0; m < 4; ++m) {
      int row = m * 16 + l15;
      a[m] = *(const short8v*)(lA + ((row * 512 + kt * 64 + lg * 16) ^ ((row & 7) << 4)));
    }
#pragma unroll
    for (int m = 0; m < 4; ++m)
#pragma unroll
      for (int c = 0; c < 4; ++c)
        acc[m][c] = __builtin_amdgcn_mfma_f32_16x16x32_bf16(a[m], b[c], acc[m][c], 0, 0, 0);
  }
#pragma unroll
  for (int m = 0; m < 4; ++m)
#pragma unroll
    for (int j = 0; j < 4; ++j) {
      int n = n0 + m * 16 + lg * 4 + j;
      if (n < NN) {
        float* op = out + (size_t)n * 256 + wave * 64 + l15;
#pragma unroll
        for (int c = 0; c < 4; ++c) op[c * 16] = acc[m][c][j];
      }
    }
}

// ---------------------------------------------------------------------------
// Tier A aggregate: msg is DST-SORTED -> fully sequential streaming. One
// half-wave (32 lanes x 16B = 512B row) per dst node; RMW of out.
__global__ __launch_bounds__(256) void k_aggregate(
    const unsigned short* __restrict__ msg, const int* __restrict__ row_ptr,
    float* __restrict__ out) {
  int g = blockIdx.x * 8 + (threadIdx.x >> 5);
  if (g >= NN) return;
  int hl = threadIdx.x & 31;
  int lo = row_ptr[g], hi = row_ptr[g + 1];
  if (lo >= hi) return;
  float a[8];
#pragma unroll
  for (int k = 0; k < 8; ++k) a[k] = 0.f;
  for (int p = lo; p < hi; ++p) {
    short8v mv = *(const short8v*)(msg + (size_t)p * 256 + hl * 8);
#pragma unroll
    for (int k = 0; k < 8; ++k) a[k] += bf2f((unsigned short)mv[k]);
  }
  float* op = out + (size_t)g * 256 + hl * 8;
#pragma unroll
  for (int c = 0; c < 2; ++c) {
    f32x4 o = *(const f32x4*)(op + c * 4);
    o[0] += a[c * 4]; o[1] += a[c * 4 + 1]; o[2] += a[c * 4 + 2]; o[3] += a[c * 4 + 3];
    *(f32x4*)(op + c * 4) = o;
  }
}

// ---------------------------------------------------------------------------
// Tier B/C fallbacks (atomic epilogue), using flat gsrc/gdst/ginv metadata.
__device__ __forceinline__ void gemm64(const char* lA, const short* __restrict__ wpk,
                                       f32x4 acc[4][4], int wave, int lane) {
  int l15 = lane & 15, lg = lane >> 4;
  const short* bp = wpk + (size_t)wave * 4 * 4096 + (size_t)lane * 8;
#pragma unroll
  for (int kt = 0; kt < 8; ++kt) {
    short8v a[4], b[4];
#pragma unroll
    for (int c = 0; c < 4; ++c) b[c] = *(const short8v*)(bp + c * 4096 + kt * 512);
#pragma unroll
    for (int m = 0; m < 4; ++m) {
      int row = m * 16 + l15;
      a[m] = *(const short8v*)(lA + ((row * 512 + kt * 64 + lg * 16) ^ ((row & 7) << 4)));
    }
#pragma unroll
    for (int m = 0; m < 4; ++m)
#pragma unroll
      for (int c = 0; c < 4; ++c)
        acc[m][c] = __builtin_amdgcn_mfma_f32_16x16x32_bf16(a[m], b[c], acc[m][c], 0, 0, 0);
  }
}

template <bool B16>
__global__ __launch_bounds__(256) void k_self_gemm(const float* __restrict__ in_feat,
                                                   const unsigned short* __restrict__ featb,
                                                   const short* __restrict__ spk,
                                                   float* __restrict__ out) {
  __shared__ __align__(16) char lA[32768];
  int n0 = blockIdx.x * 64;
  int tid = threadIdx.x;
  if (B16) {
    short8v sv[8];
#pragma unroll
    for (int u = 0; u < 8; ++u) {
      int idx = u * 256 + tid;
      int row = idx >> 5, q = idx & 31;
      int n = min(n0 + row, NN - 1);
      sv[u] = *(const short8v*)(featb + (size_t)n * 256 + q * 8);
    }
#pragma unroll
    for (int u = 0; u < 8; ++u) {
      int idx = u * 256 + tid;
      int row = idx >> 5, q = idx & 31;
      *(short8v*)(lA + ((row * 512 + q * 16) ^ ((row & 7) << 4))) = sv[u];
    }
  } else {
#pragma unroll
    for (int half = 0; half < 2; ++half) {
      float4 v[8];
#pragma unroll
      for (int u = 0; u < 8; ++u) {
        int it = half * 2048 + u * 256 + tid;
        int row = it >> 6, q = it & 63;
        int n = n0 + row;
        v[u] = (n < NN) ? ((const float4*)(in_feat + (size_t)n * 256))[q]
                        : make_float4(0.f, 0.f, 0.f, 0.f);
      }
#pragma unroll
      for (int u = 0; u < 8; ++u) {
        int it = half * 2048 + u * 256 + tid;
        int row = it >> 6, q = it & 63;
        ushort4 hh;
        hh.x = f2bf(v[u].x); hh.y = f2bf(v[u].y); hh.z = f2bf(v[u].z); hh.w = f2bf(v[u].w);
        *(ushort4*)(lA + ((row * 512 + q * 8) ^ ((row & 7) << 4))) = hh;
      }
    }
  }
  __syncthreads();
  f32x4 acc[4][4];
#pragma unroll
  for (int m = 0; m < 4; ++m)
#pragma unroll
    for (int c = 0; c < 4; ++c) acc[m][c] = (f32x4){0.f, 0.f, 0.f, 0.f};
  int wave = tid >> 6, lane = tid & 63;
  gemm64(lA, spk, acc, wave, lane);
  int l15 = lane & 15, lg = lane >> 4;
#pragma unroll
  for (int m = 0; m < 4; ++m)
#pragma unroll
    for (int j = 0; j < 4; ++j) {
      int n = n0 + m * 16 + lg * 4 + j;
      if (n < NN) {
        float* op = out + (size_t)n * 256 + wave * 64 + l15;
#pragma unroll
        for (int c = 0; c < 4; ++c) op[c * 16] = acc[m][c][j];
      }
    }
}

template <int MODE>   // 0: f32 feat, 1: bf16 feat; atomic mean-scatter into out
__global__ __launch_bounds__(256) void k_edge_gemmBC(const float* __restrict__ in_feat,
                                                     const unsigned short* __restrict__ featb,
                                                     const short* __restrict__ wpk,
                                                     const int* __restrict__ gsrc,
                                                     const int* __restrict__ gdst,
                                                     const float* __restrict__ ginv,
                                                     const int4* __restrict__ tdesc,
                                                     float* __restrict__ out) {
  __shared__ __align__(16) char lA[32768];
  __shared__ int lsrc[64];
  __shared__ int ldst[64];
  __shared__ float linv[64];
  int bid = blockIdx.x;
  int tile = (bid & 7) * (MAXTILES / 8) + (bid >> 3);
  int4 d = tdesc[tile];
  int rows = d.z;
  if (rows <= 0) return;
  int r = d.x, rs = d.y;
  int tid = threadIdx.x;
  if (tid < 64) {
    if (tid < rows) {
      lsrc[tid] = gsrc[rs + tid];
      ldst[tid] = gdst[rs + tid];
      linv[tid] = ginv[rs + tid];
    } else {
      lsrc[tid] = -1; ldst[tid] = -1; linv[tid] = 0.f;
    }
  }
  __syncthreads();
  if (MODE == 1) {
    short8v sv[8];
#pragma unroll
    for (int u = 0; u < 8; ++u) {
      int idx = u * 256 + tid;
      int row = idx >> 5, q = idx & 31;
      int s = lsrc[row];
      sv[u] = (s >= 0) ? *(const short8v*)(featb + (size_t)s * 256 + q * 8)
                       : (short8v){0, 0, 0, 0, 0, 0, 0, 0};
    }
#pragma unroll
    for (int u = 0; u < 8; ++u) {
      int idx = u * 256 + tid;
      int row = idx >> 5, q = idx & 31;
      *(short8v*)(lA + ((row * 512 + q * 16) ^ ((row & 7) << 4))) = sv[u];
    }
  } else {
#pragma unroll
    for (int half = 0; half < 2; ++half) {
      float4 v[8];
#pragma unroll
      for (int u = 0; u < 8; ++u) {
        int it = half * 2048 + u * 256 + tid;
        int row = it >> 6, q = it & 63;
        int s = lsrc[row];
        v[u] = (s >= 0) ? ((const float4*)(in_feat + (size_t)s * 256))[q]
                        : make_float4(0.f, 0.f, 0.f, 0.f);
      }
#pragma unroll
      for (int u = 0; u < 8; ++u) {
        int it = half * 2048 + u * 256 + tid;
        int row = it >> 6, q = it & 63;
        ushort4 hh;
        hh.x = f2bf(v[u].x); hh.y = f2bf(v[u].y); hh.z = f2bf(v[u].z); hh.w = f2bf(v[u].w);
        *(ushort4*)(lA + ((row * 512 + q * 8) ^ ((row & 7) << 4))) = hh;
      }
    }
  }
  __syncthreads();
  f32x4 acc[4][4];
#pragma unroll
  for (int m = 0; m < 4; ++m)
#pragma unroll
    for (int c = 0; c < 4; ++c) acc[m][c] = (f32x4){0.f, 0.f, 0.f, 0.f};
  int wave = tid >> 6, lane = tid & 63;
  gemm64(lA, wpk + (size_t)r * 65536, acc, wave, lane);
  int l15 = lane & 15, lg = lane >> 4;
#pragma unroll
  for (int m = 0; m < 4; ++m)
#pragma unroll
    for (int j = 0; j < 4; ++j) {
      int row = m * 16 + lg * 4 + j;
      int dd = ldst[row];
      if (dd >= 0) {
        float inv = linv[row];
        float* op = out + (size_t)dd * 256 + wave * 64 + l15;
#pragma unroll
        for (int c = 0; c < 4; ++c) unsafeAtomicAdd(op + c * 16, acc[m][c][j] * inv);
      }
    }
}

// ---------------------------------------------------------------------------
extern "C" void kernel_launch(void* const* d_in, const int* in_sizes, int n_in,
                              void* d_out, int out_size, void* d_ws, size_t ws_size,
                              hipStream_t stream) {
  const float* in_feat = (const float*)d_in[0];
  const float* basis   = (const float*)d_in[1];
  const float* coef    = (const float*)d_in[2];
  const float* slw     = (const float*)d_in[3];
  const int*   src     = (const int*)d_in[4];
  const int*   dst     = (const int*)d_in[5];
  const int*   etype   = (const int*)d_in[6];
  float* out = (float*)d_out;

  char* base = (char*)d_ws;
  char* w = base;
  auto alloc = [&](size_t bytes) {
    char* p = w;
    w += (bytes + 255) & ~(size_t)255;
    return p;
  };
  // base group (tiers B/C)
  short* wpk  = (short*)alloc((size_t)RR * 65536 * 2);   // 26.2 MB
  short* spk  = (short*)alloc(65536 * 2);
  int*   gsrc = (int*)alloc((size_t)EE * 4);
  int*   gdst = (int*)alloc((size_t)EE * 4);
  float* ginv = (float*)alloc((size_t)EE * 4);
  int*   deg  = (int*)alloc((size_t)NN * 4);
  int*   hist = (int*)alloc(RR * 4);
  int*   cur  = (int*)alloc(RR * 4);
  int4*  tdesc = (int4*)alloc((size_t)MAXTILES * 16);
  int*   bsum = (int*)alloc(NSCAN * 4);
  // tier B adds bf16 feat
  unsigned short* featb = (unsigned short*)alloc((size_t)NN * 256 * 2);  // 51.2 MB
  size_t need_b = (size_t)(w - base);
  // tier A adds dst-CSR + msg buffer
  int* row_ptr = (int*)alloc((size_t)(NN + 1) * 4);
  int* cur2    = (int*)alloc((size_t)NN * 4);
  int* gout    = (int*)alloc((size_t)EE * 4);
  unsigned short* msg = (unsigned short*)alloc((size_t)EE * 256 * 2);    // 204.8 MB
  size_t need_a = (size_t)(w - base);

  bool tierA = ws_size >= need_a;
  bool tierB = ws_size >= need_b;

  hipMemsetAsync(hist, 0, RR * 4, stream);
  hipMemsetAsync(deg, 0, (size_t)NN * 4, stream);

  if (tierA) {
    k_prep1<true><<<1344, 256, 0, stream>>>(basis, coef, slw, etype, dst, in_feat,
                                            wpk, spk, hist, deg, featb);
    k_prep2<<<NSCAN + 1, 256, 0, stream>>>(hist, deg, cur, tdesc, bsum);
    k_prep3<<<NSCAN, 256, 0, stream>>>(deg, bsum, row_ptr, cur2);
    k_prep4<true><<<(EE + SCHUNK - 1) / SCHUNK, 256, 0, stream>>>(
        etype, src, dst, deg, cur, gsrc, gdst, ginv, cur2, gout);
    k_selfA<<<(NN + 63) / 64, 256, 0, stream>>>(featb, spk, out);
    k_edgeW2<<<MAXTILES * 2, 256, 0, stream>>>(featb, wpk, gsrc, ginv, gout,
                                               tdesc, msg);
    k_aggregate<<<(NN + 7) / 8, 256, 0, stream>>>(msg, row_ptr, out);
  } else if (tierB) {
    k_prep1<true><<<1344, 256, 0, stream>>>(basis, coef, slw, etype, dst, in_feat,
                                            wpk, spk, hist, deg, featb);
    k_prep2<<<NSCAN + 1, 256, 0, stream>>>(hist, deg, cur, tdesc, bsum);
    k_prep4<false><<<(EE + SCHUNK - 1) / SCHUNK, 256, 0, stream>>>(
        etype, src, dst, deg, cur, gsrc, gdst, ginv, nullptr, nullptr);
    k_self_gemm<true><<<(NN + 63) / 64, 256, 0, stream>>>(in_feat, featb, spk, out);
    k_edge_gemmBC<1><<<MAXTILES, 256, 0, stream>>>(in_feat, featb, wpk, gsrc, gdst,
                                                   ginv, tdesc, out);
  } else {
    k_prep1<false><<<1344, 256, 0, stream>>>(basis, coef, slw, etype, dst, in_feat,
                                             wpk, spk, hist, deg, nullptr);
    k_prep2<<<NSCAN + 1, 256, 0, stream>>>(hist, deg, cur, tdesc, bsum);
    k_prep4<false><<<(EE + SCHUNK - 1) / SCHUNK, 256, 0, stream>>>(
        etype, src, dst, deg, cur, gsrc, gdst, ginv, nullptr, nullptr);
    k_self_gemm<false><<<(NN + 63) / 64, 256, 0, stream>>>(in_feat, nullptr, spk, out);
    k_edge_gemmBC<0><<<MAXTILES, 256, 0, stream>>>(in_feat, nullptr, wpk, gsrc, gdst,
                                                   ginv, tdesc, out);
  }
}

// Round 11
// 364.374 us; speedup vs baseline: 1.1818x; 1.1818x over previous
//
#include <hip/hip_runtime.h>
#include <hip/hip_bf16.h>

// RGCN forward, MI355X. N=100000, E=400000, IN=OUT=256, R=200, B=32.
// Tier A: prep1{wgen|slwpk|hist+feat} -> prep2{etype-scan|deg-blocksums} ->
// prep3{deg-scan} -> prep4{scatter: gsrc/ginv/gout} -> selfA GEMM ->
// col-split edge GEMM (r5 structure: 2 blocks/tile, 64x128 out, acc[4][2],
// LDS-staged A; msg rows stored at DST-SORTED gout slots) -> sequential
// streaming aggregate (half-wave per node).

#define NN 100000
#define EE 400000
#define RR 200
#define BB 32
#define MAXTILES 6464   // >= E/64 + R ; divisible by 8
#define EQ2 (MAXTILES * 2 / 8)   // 1616 ords per XCD
#define SCHUNK 2048
#define NSCAN ((NN + 255) / 256) // 391

typedef __attribute__((ext_vector_type(8))) short short8v;   // 8 x bf16 (16B)
typedef __attribute__((ext_vector_type(4))) float f32x4;

__device__ __forceinline__ unsigned short f2bf(float f) {
  unsigned u = __float_as_uint(f);
  u += 0x7FFF + ((u >> 16) & 1);          // RNE
  return (unsigned short)(u >> 16);
}
__device__ __forceinline__ float bf2f(unsigned short h) {
  return __uint_as_float(((unsigned)h) << 16);
}

// ---------------------------------------------------------------------------
// prep1: blocks [0,800): wgen (L2-blocked W_r pack); [800,832): slwpk;
// [832,1344): etype hist + dst degree + (FEAT) f32->bf16 feature convert.
// W_pk layout per relation: [ct=16][kt=8][lane=64][j=8] bf16 where
//   value = W_r[k = kt*32 + (lane>>4)*8 + j][n = ct*16 + (lane&15)].
template <bool FEAT>
__global__ __launch_bounds__(256) void k_prep1(
    const float* __restrict__ basis, const float* __restrict__ coef,
    const float* __restrict__ slw, const int* __restrict__ etype,
    const int* __restrict__ dst, const float* __restrict__ in_feat,
    short* __restrict__ wpk, short* __restrict__ spk,
    int* __restrict__ hist, int* __restrict__ deg,
    unsigned short* __restrict__ featb) {
  __shared__ int lh[RR];
  int b = blockIdx.x, tid = threadIdx.x;
  if (b < 800) {                       // ---- wgen ----
    int ord = (b & 7) * 100 + (b >> 3);
    int rg = ord % 25;
    int pk8 = (ord / 25) * 256 + tid;
    int lane = pk8 & 63;
    int kt = (pk8 >> 6) & 7;
    int ct = pk8 >> 9;
    int n  = ct * 16 + (lane & 15);
    int k0 = kt * 32 + ((lane >> 4) << 3);
    float acc[8][8];
#pragma unroll
    for (int r = 0; r < 8; ++r)
#pragma unroll
      for (int j = 0; j < 8; ++j) acc[r][j] = 0.f;
    for (int bb = 0; bb < BB; ++bb) {
      float bas[8];
#pragma unroll
      for (int j = 0; j < 8; ++j) bas[j] = basis[bb * 65536 + (k0 + j) * 256 + n];
#pragma unroll
      for (int r = 0; r < 8; ++r) {
        float c = coef[(rg * 8 + r) * BB + bb];
#pragma unroll
        for (int j = 0; j < 8; ++j) acc[r][j] += c * bas[j];
      }
    }
#pragma unroll
    for (int r = 0; r < 8; ++r) {
      short8v v;
#pragma unroll
      for (int j = 0; j < 8; ++j) v[j] = (short)f2bf(acc[r][j]);
      *(short8v*)(wpk + (size_t)(rg * 8 + r) * 65536 + (size_t)pk8 * 8) = v;
    }
    return;
  }
  if (b < 832) {                       // ---- slwpk ----
    int t = (b - 800) * 256 + tid;
    int lane = t & 63;
    int kt = (t >> 6) & 7;
    int ct = t >> 9;
    int n  = ct * 16 + (lane & 15);
    int k0 = kt * 32 + ((lane >> 4) << 3);
    short8v v;
#pragma unroll
    for (int j = 0; j < 8; ++j) v[j] = (short)f2bf(slw[(k0 + j) * 256 + n]);
    *(short8v*)(spk + (size_t)t * 8) = v;
    return;
  }
  // ---- hist + deg + feat ----
  int hb = b - 832;                    // 512 blocks
  for (int i = tid; i < RR; i += 256) lh[i] = 0;
  __syncthreads();
  for (int e = hb * 256 + tid; e < EE; e += 512 * 256) {
    atomicAdd(&lh[etype[e]], 1);
    atomicAdd(&deg[dst[e]], 1);
  }
  if (FEAT) {
    const int total = NN * 64;         // float4 count
    for (int i = hb * 256 + tid; i < total; i += 512 * 256) {
      float4 v = ((const float4*)in_feat)[i];
      ushort4 h;
      h.x = f2bf(v.x); h.y = f2bf(v.y); h.z = f2bf(v.z); h.w = f2bf(v.w);
      ((ushort4*)featb)[i] = h;
    }
  }
  __syncthreads();
  for (int i = tid; i < RR; i += 256)
    if (lh[i]) atomicAdd(&hist[i], lh[i]);
}

// ---------------------------------------------------------------------------
// prep2: block 0: etype-bin scan -> cur + tdesc; blocks 1..391: deg block sums.
__global__ __launch_bounds__(256) void k_prep2(const int* __restrict__ hist,
                                               const int* __restrict__ deg,
                                               int* __restrict__ cur,
                                               int4* __restrict__ tdesc,
                                               int* __restrict__ bsum) {
  __shared__ int h[RR];
  __shared__ int off[RR];
  __shared__ int toff[RR];
  __shared__ int tot;
  __shared__ int ws4[4];
  int b = blockIdx.x, tid = threadIdx.x;
  if (b == 0) {
    for (int i = tid; i < RR; i += 256) h[i] = hist[i];
    __syncthreads();
    if (tid == 0) {
      int s = 0, ts = 0;
      for (int r = 0; r < RR; ++r) {
        off[r] = s; s += h[r];
        toff[r] = ts; ts += (h[r] + 63) >> 6;
      }
      tot = ts;
    }
    __syncthreads();
    if (tid < RR) {
      int r = tid, cnt = h[r], base = off[r], to = toff[r];
      cur[r] = base;
      int nt = (cnt + 63) >> 6;
      for (int t2 = 0; t2 < nt; ++t2)
        tdesc[to + t2] = make_int4(r, base + t2 * 64, min(64, cnt - t2 * 64), 0);
    }
    for (int i = tot + tid; i < MAXTILES; i += 256)
      tdesc[i] = make_int4(0, 0, 0, 0);
    return;
  }
  int i = (b - 1) * 256 + tid;
  int v = (i < NN) ? deg[i] : 0;
#pragma unroll
  for (int d = 32; d; d >>= 1) v += __shfl_down(v, d, 64);
  if ((tid & 63) == 0) ws4[tid >> 6] = v;
  __syncthreads();
  if (tid == 0) bsum[b - 1] = ws4[0] + ws4[1] + ws4[2] + ws4[3];
}

// prep3 (tier A): deg exclusive scan -> row_ptr/cur2; bsum prefix inline.
__global__ __launch_bounds__(256) void k_prep3(const int* __restrict__ deg,
                                               const int* __restrict__ bsum,
                                               int* __restrict__ row_ptr,
                                               int* __restrict__ cur2) {
  __shared__ int ws4[4];
  __shared__ int wo4[4];
  __shared__ int psum[4];
  int tid = threadIdx.x, b = blockIdx.x;
  int sp = 0;
  for (int i = tid; i < b; i += 256) sp += bsum[i];
#pragma unroll
  for (int d = 32; d; d >>= 1) sp += __shfl_down(sp, d, 64);
  if ((tid & 63) == 0) psum[tid >> 6] = sp;
  int i = b * 256 + tid;
  int v = (i < NN) ? deg[i] : 0;
  int x = v;
#pragma unroll
  for (int d = 1; d < 64; d <<= 1) {
    int y = __shfl_up(x, d, 64);
    if ((tid & 63) >= d) x += y;
  }
  if ((tid & 63) == 63) ws4[tid >> 6] = x;
  __syncthreads();
  if (tid == 0) {
    int s = 0;
    for (int w2 = 0; w2 < 4; ++w2) { wo4[w2] = s; s += ws4[w2]; }
    psum[0] = psum[0] + psum[1] + psum[2] + psum[3];
  }
  __syncthreads();
  int excl = x - v + wo4[tid >> 6] + psum[0];
  if (i < NN) { row_ptr[i] = excl; cur2[i] = excl; }
  if (i == 0 && b == 0) row_ptr[NN] = EE;
}

// prep4: counting-sort scatter; materializes per-position gsrc/gdst/ginv and
// (DL) gout[s] = dst-sorted msg slot.
template <bool DL>
__global__ __launch_bounds__(256) void k_prep4(const int* __restrict__ etype,
                                               const int* __restrict__ src,
                                               const int* __restrict__ dst,
                                               const int* __restrict__ deg,
                                               int* __restrict__ cur,
                                               int* __restrict__ gsrc,
                                               int* __restrict__ gdst,
                                               float* __restrict__ ginv,
                                               int* __restrict__ cur2,
                                               int* __restrict__ gout) {
  __shared__ int lh[RR];
  __shared__ int lbase[RR];
  __shared__ int lcur[RR];
  int tid = threadIdx.x;
  int e0 = blockIdx.x * SCHUNK;
  for (int i = tid; i < RR; i += 256) lh[i] = 0;
  __syncthreads();
  for (int i = tid; i < SCHUNK; i += 256) {
    int e = e0 + i;
    if (e < EE) atomicAdd(&lh[etype[e]], 1);
  }
  __syncthreads();
  for (int i = tid; i < RR; i += 256) {
    int c = lh[i];
    lbase[i] = c ? atomicAdd(&cur[i], c) : 0;
    lcur[i] = 0;
  }
  __syncthreads();
  for (int i = tid; i < SCHUNK; i += 256) {
    int e = e0 + i;
    if (e < EE) {
      int et = etype[e];
      int s = lbase[et] + atomicAdd(&lcur[et], 1);
      int d = dst[e];
      gsrc[s] = src[e];
      gdst[s] = d;
      ginv[s] = 1.0f / (float)max(deg[d], 1);
      if (DL) {
        int pos = atomicAdd(&cur2[d], 1);
        gout[s] = pos;
      }
    }
  }
}

// ---------------------------------------------------------------------------
// Tier A edge GEMM (r5 structure — measured best): 2 blocks per 64-edge tile;
// block computes 64 rows x 128 cols -> acc[4][2] (32 AGPR), ~52 arch VGPR ->
// 3-4 waves/SIMD. Full A tile staged once in swizzled LDS. B fragments
// prefetched one kt ahead. msg rows stored at DST-SORTED gout slots.
__global__ __launch_bounds__(256) void k_edge5(
    const unsigned short* __restrict__ featb, const short* __restrict__ wpk,
    const int* __restrict__ gsrc, const float* __restrict__ ginv,
    const int* __restrict__ gout, const int4* __restrict__ tdesc,
    unsigned short* __restrict__ msg) {
  __shared__ __align__(16) char lA[32768];
  __shared__ int lsrc[64];
  __shared__ float linv[64];
  __shared__ int lout[64];
  int tid = threadIdx.x, wave = tid >> 6, lane = tid & 63;
  int l15 = lane & 15, lg = lane >> 4;
  // XCD x processes ords [x*1616,(x+1)*1616) = tiles [x*808,(x+1)*808) x 2 halves
  int bid = blockIdx.x;
  int ord = (bid & 7) * EQ2 + (bid >> 3);
  int tile = ord >> 1, half = ord & 1;
  int4 d = tdesc[tile];
  int rows = d.z;
  if (rows <= 0) return;
  int r = d.x, rs = d.y;
  if (tid < 64) {
    int s = min(rs + tid, EE - 1);
    lsrc[tid] = gsrc[s];
    linv[tid] = ginv[s];
    lout[tid] = gout[s];
  }
  __syncthreads();
  // stage full 64x256 A tile (K unsplit), swizzled
  short8v sv[8];
#pragma unroll
  for (int u = 0; u < 8; ++u) {
    int idx = u * 256 + tid;
    int row = idx >> 5, q = idx & 31;
    sv[u] = *(const short8v*)(featb + (size_t)lsrc[row] * 256 + q * 8);
  }
#pragma unroll
  for (int u = 0; u < 8; ++u) {
    int idx = u * 256 + tid;
    int row = idx >> 5, q = idx & 31;
    *(short8v*)(lA + ((row * 512 + q * 16) ^ ((row & 7) << 4))) = sv[u];
  }
  __syncthreads();
  f32x4 acc[4][2];
#pragma unroll
  for (int m = 0; m < 4; ++m)
#pragma unroll
    for (int c = 0; c < 2; ++c) acc[m][c] = (f32x4){0.f, 0.f, 0.f, 0.f};
  // B: this block's ct range = half*8 + wave*2 + {0,1}
  const short* bp = wpk + (size_t)r * 65536 +
                    (size_t)(half * 8 + wave * 2) * 4096 + (size_t)lane * 8;
  short8v b0 = *(const short8v*)(bp);
  short8v b1 = *(const short8v*)(bp + 4096);
#pragma unroll
  for (int kt = 0; kt < 8; ++kt) {
    short8v bn0, bn1;
    if (kt < 7) {
      bn0 = *(const short8v*)(bp + (kt + 1) * 512);
      bn1 = *(const short8v*)(bp + 4096 + (kt + 1) * 512);
    }
    short8v a[4];
#pragma unroll
    for (int m = 0; m < 4; ++m) {
      int row = m * 16 + l15;
      a[m] = *(const short8v*)(lA + ((row * 512 + kt * 64 + lg * 16) ^ ((row & 7) << 4)));
    }
#pragma unroll
    for (int m = 0; m < 4; ++m) {
      acc[m][0] = __builtin_amdgcn_mfma_f32_16x16x32_bf16(a[m], b0, acc[m][0], 0, 0, 0);
      acc[m][1] = __builtin_amdgcn_mfma_f32_16x16x32_bf16(a[m], b1, acc[m][1], 0, 0, 0);
    }
    if (kt < 7) { b0 = bn0; b1 = bn1; }
  }
  __syncthreads();                            // done reading lA
  // scale + repack bf16 (cols local [0,128)) via lA, then coalesced store
#pragma unroll
  for (int m = 0; m < 4; ++m)
#pragma unroll
    for (int j = 0; j < 4; ++j) {
      int row = m * 16 + lg * 4 + j;
      float inv = linv[row];
      int rb = row * 512, sw = (row & 7) << 4;
#pragma unroll
      for (int c = 0; c < 2; ++c) {
        int col = wave * 32 + c * 16 + l15;
        *(unsigned short*)(lA + ((rb + col * 2) ^ sw)) = f2bf(acc[m][c][j] * inv);
      }
    }
  __syncthreads();
#pragma unroll
  for (int u = 0; u < 4; ++u) {
    int idx = u * 256 + tid;
    int row = idx >> 4, q = idx & 15;         // 64 rows x 16 chunks of 16B
    if (row < rows) {
      short8v vv = *(const short8v*)(lA + ((row * 512 + q * 16) ^ ((row & 7) << 4)));
      *(short8v*)(msg + (size_t)lout[row] * 256 + half * 128 + q * 8) = vv;
    }
  }
}

// ---------------------------------------------------------------------------
// Tier A self-loop GEMM: out[n] = featb[n] @ slw (f32 out, direct store).
__global__ __launch_bounds__(256) void k_selfA(const unsigned short* __restrict__ featb,
                                               const short* __restrict__ spk,
                                               float* __restrict__ out) {
  __shared__ __align__(16) char lA[32768];
  int tid = threadIdx.x, wave = tid >> 6, lane = tid & 63;
  int l15 = lane & 15, lg = lane >> 4;
  int n0 = blockIdx.x * 64;
  short8v sv[8];
#pragma unroll
  for (int u = 0; u < 8; ++u) {
    int idx = u * 256 + tid;
    int row = idx >> 5, q = idx & 31;
    int n = min(n0 + row, NN - 1);
    sv[u] = *(const short8v*)(featb + (size_t)n * 256 + q * 8);
  }
#pragma unroll
  for (int u = 0; u < 8; ++u) {
    int idx = u * 256 + tid;
    int row = idx >> 5, q = idx & 31;
    *(short8v*)(lA + ((row * 512 + q * 16) ^ ((row & 7) << 4))) = sv[u];
  }
  __syncthreads();
  f32x4 acc[4][4];
#pragma unroll
  for (int m = 0; m < 4; ++m)
#pragma unroll
    for (int c = 0; c < 4; ++c) acc[m][c] = (f32x4){0.f, 0.f, 0.f, 0.f};
  const short* bp = spk + (size_t)wave * 4 * 4096 + (size_t)lane * 8;
#pragma unroll
  for (int kt = 0; kt < 8; ++kt) {
    short8v a[4], b[4];
#pragma unroll
    for (int c = 0; c < 4; ++c) b[c] = *(const short8v*)(bp + c * 4096 + kt * 512);
#pragma unroll
    for (int m = 0; m < 4; ++m) {
      int row = m * 16 + l15;
      a[m] = *(const short8v*)(lA + ((row * 512 + kt * 64 + lg * 16) ^ ((row & 7) << 4)));
    }
#pragma unroll
    for (int m = 0; m < 4; ++m)
#pragma unroll
      for (int c = 0; c < 4; ++c)
        acc[m][c] = __builtin_amdgcn_mfma_f32_16x16x32_bf16(a[m], b[c], acc[m][c], 0, 0, 0);
  }
#pragma unroll
  for (int m = 0; m < 4; ++m)
#pragma unroll
    for (int j = 0; j < 4; ++j) {
      int n = n0 + m * 16 + lg * 4 + j;
      if (n < NN) {
        float* op = out + (size_t)n * 256 + wave * 64 + l15;
#pragma unroll
        for (int c = 0; c < 4; ++c) op[c * 16] = acc[m][c][j];
      }
    }
}

// ---------------------------------------------------------------------------
// Tier A aggregate: msg is DST-SORTED -> fully sequential streaming. One
// half-wave (32 lanes x 16B = 512B row) per dst node; RMW of out.
__global__ __launch_bounds__(256) void k_aggregate(
    const unsigned short* __restrict__ msg, const int* __restrict__ row_ptr,
    float* __restrict__ out) {
  int g = blockIdx.x * 8 + (threadIdx.x >> 5);
  if (g >= NN) return;
  int hl = threadIdx.x & 31;
  int lo = row_ptr[g], hi = row_ptr[g + 1];
  if (lo >= hi) return;
  float a[8];
#pragma unroll
  for (int k = 0; k < 8; ++k) a[k] = 0.f;
  for (int p = lo; p < hi; ++p) {
    short8v mv = *(const short8v*)(msg + (size_t)p * 256 + hl * 8);
#pragma unroll
    for (int k = 0; k < 8; ++k) a[k] += bf2f((unsigned short)mv[k]);
  }
  float* op = out + (size_t)g * 256 + hl * 8;
#pragma unroll
  for (int c = 0; c < 2; ++c) {
    f32x4 o = *(const f32x4*)(op + c * 4);
    o[0] += a[c * 4]; o[1] += a[c * 4 + 1]; o[2] += a[c * 4 + 2]; o[3] += a[c * 4 + 3];
    *(f32x4*)(op + c * 4) = o;
  }
}

// ---------------------------------------------------------------------------
// Tier B/C fallbacks (atomic epilogue), using flat gsrc/gdst/ginv metadata.
__device__ __forceinline__ void gemm64(const char* lA, const short* __restrict__ wpk,
                                       f32x4 acc[4][4], int wave, int lane) {
  int l15 = lane & 15, lg = lane >> 4;
  const short* bp = wpk + (size_t)wave * 4 * 4096 + (size_t)lane * 8;
#pragma unroll
  for (int kt = 0; kt < 8; ++kt) {
    short8v a[4], b[4];
#pragma unroll
    for (int c = 0; c < 4; ++c) b[c] = *(const short8v*)(bp + c * 4096 + kt * 512);
#pragma unroll
    for (int m = 0; m < 4; ++m) {
      int row = m * 16 + l15;
      a[m] = *(const short8v*)(lA + ((row * 512 + kt * 64 + lg * 16) ^ ((row & 7) << 4)));
    }
#pragma unroll
    for (int m = 0; m < 4; ++m)
#pragma unroll
      for (int c = 0; c < 4; ++c)
        acc[m][c] = __builtin_amdgcn_mfma_f32_16x16x32_bf16(a[m], b[c], acc[m][c], 0, 0, 0);
  }
}

template <bool B16>
__global__ __launch_bounds__(256) void k_self_gemm(const float* __restrict__ in_feat,
                                                   const unsigned short* __restrict__ featb,
                                                   const short* __restrict__ spk,
                                                   float* __restrict__ out) {
  __shared__ __align__(16) char lA[32768];
  int n0 = blockIdx.x * 64;
  int tid = threadIdx.x;
  if (B16) {
    short8v sv[8];
#pragma unroll
    for (int u = 0; u < 8; ++u) {
      int idx = u * 256 + tid;
      int row = idx >> 5, q = idx & 31;
      int n = min(n0 + row, NN - 1);
      sv[u] = *(const short8v*)(featb + (size_t)n * 256 + q * 8);
    }
#pragma unroll
    for (int u = 0; u < 8; ++u) {
      int idx = u * 256 + tid;
      int row = idx >> 5, q = idx & 31;
      *(short8v*)(lA + ((row * 512 + q * 16) ^ ((row & 7) << 4))) = sv[u];
    }
  } else {
#pragma unroll
    for (int half = 0; half < 2; ++half) {
      float4 v[8];
#pragma unroll
      for (int u = 0; u < 8; ++u) {
        int it = half * 2048 + u * 256 + tid;
        int row = it >> 6, q = it & 63;
        int n = n0 + row;
        v[u] = (n < NN) ? ((const float4*)(in_feat + (size_t)n * 256))[q]
                        : make_float4(0.f, 0.f, 0.f, 0.f);
      }
#pragma unroll
      for (int u = 0; u < 8; ++u) {
        int it = half * 2048 + u * 256 + tid;
        int row = it >> 6, q = it & 63;
        ushort4 hh;
        hh.x = f2bf(v[u].x); hh.y = f2bf(v[u].y); hh.z = f2bf(v[u].z); hh.w = f2bf(v[u].w);
        *(ushort4*)(lA + ((row * 512 + q * 8) ^ ((row & 7) << 4))) = hh;
      }
    }
  }
  __syncthreads();
  f32x4 acc[4][4];
#pragma unroll
  for (int m = 0; m < 4; ++m)
#pragma unroll
    for (int c = 0; c < 4; ++c) acc[m][c] = (f32x4){0.f, 0.f, 0.f, 0.f};
  int wave = tid >> 6, lane = tid & 63;
  gemm64(lA, spk, acc, wave, lane);
  int l15 = lane & 15, lg = lane >> 4;
#pragma unroll
  for (int m = 0; m < 4; ++m)
#pragma unroll
    for (int j = 0; j < 4; ++j) {
      int n = n0 + m * 16 + lg * 4 + j;
      if (n < NN) {
        float* op = out + (size_t)n * 256 + wave * 64 + l15;
#pragma unroll
        for (int c = 0; c < 4; ++c) op[c * 16] = acc[m][c][j];
      }
    }
}

template <int MODE>   // 0: f32 feat, 1: bf16 feat; atomic mean-scatter into out
__global__ __launch_bounds__(256) void k_edge_gemmBC(const float* __restrict__ in_feat,
                                                     const unsigned short* __restrict__ featb,
                                                     const short* __restrict__ wpk,
                                                     const int* __restrict__ gsrc,
                                                     const int* __restrict__ gdst,
                                                     const float* __restrict__ ginv,
                                                     const int4* __restrict__ tdesc,
                                                     float* __restrict__ out) {
  __shared__ __align__(16) char lA[32768];
  __shared__ int lsrc[64];
  __shared__ int ldst[64];
  __shared__ float linv[64];
  int bid = blockIdx.x;
  int tile = (bid & 7) * (MAXTILES / 8) + (bid >> 3);
  int4 d = tdesc[tile];
  int rows = d.z;
  if (rows <= 0) return;
  int r = d.x, rs = d.y;
  int tid = threadIdx.x;
  if (tid < 64) {
    if (tid < rows) {
      lsrc[tid] = gsrc[rs + tid];
      ldst[tid] = gdst[rs + tid];
      linv[tid] = ginv[rs + tid];
    } else {
      lsrc[tid] = -1; ldst[tid] = -1; linv[tid] = 0.f;
    }
  }
  __syncthreads();
  if (MODE == 1) {
    short8v sv[8];
#pragma unroll
    for (int u = 0; u < 8; ++u) {
      int idx = u * 256 + tid;
      int row = idx >> 5, q = idx & 31;
      int s = lsrc[row];
      sv[u] = (s >= 0) ? *(const short8v*)(featb + (size_t)s * 256 + q * 8)
                       : (short8v){0, 0, 0, 0, 0, 0, 0, 0};
    }
#pragma unroll
    for (int u = 0; u < 8; ++u) {
      int idx = u * 256 + tid;
      int row = idx >> 5, q = idx & 31;
      *(short8v*)(lA + ((row * 512 + q * 16) ^ ((row & 7) << 4))) = sv[u];
    }
  } else {
#pragma unroll
    for (int half = 0; half < 2; ++half) {
      float4 v[8];
#pragma unroll
      for (int u = 0; u < 8; ++u) {
        int it = half * 2048 + u * 256 + tid;
        int row = it >> 6, q = it & 63;
        int s = lsrc[row];
        v[u] = (s >= 0) ? ((const float4*)(in_feat + (size_t)s * 256))[q]
                        : make_float4(0.f, 0.f, 0.f, 0.f);
      }
#pragma unroll
      for (int u = 0; u < 8; ++u) {
        int it = half * 2048 + u * 256 + tid;
        int row = it >> 6, q = it & 63;
        ushort4 hh;
        hh.x = f2bf(v[u].x); hh.y = f2bf(v[u].y); hh.z = f2bf(v[u].z); hh.w = f2bf(v[u].w);
        *(ushort4*)(lA + ((row * 512 + q * 8) ^ ((row & 7) << 4))) = hh;
      }
    }
  }
  __syncthreads();
  f32x4 acc[4][4];
#pragma unroll
  for (int m = 0; m < 4; ++m)
#pragma unroll
    for (int c = 0; c < 4; ++c) acc[m][c] = (f32x4){0.f, 0.f, 0.f, 0.f};
  int wave = tid >> 6, lane = tid & 63;
  gemm64(lA, wpk + (size_t)r * 65536, acc, wave, lane);
  int l15 = lane & 15, lg = lane >> 4;
#pragma unroll
  for (int m = 0; m < 4; ++m)
#pragma unroll
    for (int j = 0; j < 4; ++j) {
      int row = m * 16 + lg * 4 + j;
      int dd = ldst[row];
      if (dd >= 0) {
        float inv = linv[row];
        float* op = out + (size_t)dd * 256 + wave * 64 + l15;
#pragma unroll
        for (int c = 0; c < 4; ++c) unsafeAtomicAdd(op + c * 16, acc[m][c][j] * inv);
      }
    }
}

// ---------------------------------------------------------------------------
extern "C" void kernel_launch(void* const* d_in, const int* in_sizes, int n_in,
                              void* d_out, int out_size, void* d_ws, size_t ws_size,
                              hipStream_t stream) {
  const float* in_feat = (const float*)d_in[0];
  const float* basis   = (const float*)d_in[1];
  const float* coef    = (const float*)d_in[2];
  const float* slw     = (const float*)d_in[3];
  const int*   src     = (const int*)d_in[4];
  const int*   dst     = (const int*)d_in[5];
  const int*   etype   = (const int*)d_in[6];
  float* out = (float*)d_out;

  char* base = (char*)d_ws;
  char* w = base;
  auto alloc = [&](size_t bytes) {
    char* p = w;
    w += (bytes + 255) & ~(size_t)255;
    return p;
  };
  // base group (tiers B/C)
  short* wpk  = (short*)alloc((size_t)RR * 65536 * 2);   // 26.2 MB
  short* spk  = (short*)alloc(65536 * 2);
  int*   gsrc = (int*)alloc((size_t)EE * 4);
  int*   gdst = (int*)alloc((size_t)EE * 4);
  float* ginv = (float*)alloc((size_t)EE * 4);
  int*   deg  = (int*)alloc((size_t)NN * 4);
  int*   hist = (int*)alloc(RR * 4);
  int*   cur  = (int*)alloc(RR * 4);
  int4*  tdesc = (int4*)alloc((size_t)MAXTILES * 16);
  int*   bsum = (int*)alloc(NSCAN * 4);
  // tier B adds bf16 feat
  unsigned short* featb = (unsigned short*)alloc((size_t)NN * 256 * 2);  // 51.2 MB
  size_t need_b = (size_t)(w - base);
  // tier A adds dst-CSR + msg buffer
  int* row_ptr = (int*)alloc((size_t)(NN + 1) * 4);
  int* cur2    = (int*)alloc((size_t)NN * 4);
  int* gout    = (int*)alloc((size_t)EE * 4);
  unsigned short* msg = (unsigned short*)alloc((size_t)EE * 256 * 2);    // 204.8 MB
  size_t need_a = (size_t)(w - base);

  bool tierA = ws_size >= need_a;
  bool tierB = ws_size >= need_b;

  hipMemsetAsync(hist, 0, RR * 4, stream);
  hipMemsetAsync(deg, 0, (size_t)NN * 4, stream);

  if (tierA) {
    k_prep1<true><<<1344, 256, 0, stream>>>(basis, coef, slw, etype, dst, in_feat,
                                            wpk, spk, hist, deg, featb);
    k_prep2<<<NSCAN + 1, 256, 0, stream>>>(hist, deg, cur, tdesc, bsum);
    k_prep3<<<NSCAN, 256, 0, stream>>>(deg, bsum, row_ptr, cur2);
    k_prep4<true><<<(EE + SCHUNK - 1) / SCHUNK, 256, 0, stream>>>(
        etype, src, dst, deg, cur, gsrc, gdst, ginv, cur2, gout);
    k_selfA<<<(NN + 63) / 64, 256, 0, stream>>>(featb, spk, out);
    k_edge5<<<MAXTILES * 2, 256, 0, stream>>>(featb, wpk, gsrc, ginv, gout,
                                              tdesc, msg);
    k_aggregate<<<(NN + 7) / 8, 256, 0, stream>>>(msg, row_ptr, out);
  } else if (tierB) {
    k_prep1<true><<<1344, 256, 0, stream>>>(basis, coef, slw, etype, dst, in_feat,
                                            wpk, spk, hist, deg, featb);
    k_prep2<<<NSCAN + 1, 256, 0, stream>>>(hist, deg, cur, tdesc, bsum);
    k_prep4<false><<<(EE + SCHUNK - 1) / SCHUNK, 256, 0, stream>>>(
        etype, src, dst, deg, cur, gsrc, gdst, ginv, nullptr, nullptr);
    k_self_gemm<true><<<(NN + 63) / 64, 256, 0, stream>>>(in_feat, featb, spk, out);
    k_edge_gemmBC<1><<<MAXTILES, 256, 0, stream>>>(in_feat, featb, wpk, gsrc, gdst,
                                                   ginv, tdesc, out);
  } else {
    k_prep1<false><<<1344, 256, 0, stream>>>(basis, coef, slw, etype, dst, in_feat,
                                             wpk, spk, hist, deg, nullptr);
    k_prep2<<<NSCAN + 1, 256, 0, stream>>>(hist, deg, cur, tdesc, bsum);
    k_prep4<false><<<(EE + SCHUNK - 1) / SCHUNK, 256, 0, stream>>>(
        etype, src, dst, deg, cur, gsrc, gdst, ginv, nullptr, nullptr);
    k_self_gemm<false><<<(NN + 63) / 64, 256, 0, stream>>>(in_feat, nullptr, spk, out);
    k_edge_gemmBC<0><<<MAXTILES, 256, 0, stream>>>(in_feat, nullptr, wpk, gsrc, gdst,
                                                   ginv, tdesc, out);
  }
}

// Round 12
// 344.296 us; speedup vs baseline: 1.2507x; 1.0583x over previous
//
#include <hip/hip_runtime.h>
#include <hip/hip_bf16.h>

// RGCN forward, MI355X. N=100000, E=400000, IN=OUT=256, R=200, B=32.
// Tier A: prep1{wgen|slwpk|hist+feat} -> prep2{etype-scan|deg-blocksums} ->
// prep3{deg-scan} -> prep4{scatter: gsrc/ginv/gout} ->
// k_main{edge GEMM (r11 structure) MERGED with col-split selfA GEMM — the
// two are independent, one launch lets selfA MFMA fill edge's memory slack}
// -> sequential streaming aggregate (half-wave per node, RMW out).

#define NN 100000
#define EE 400000
#define RR 200
#define BB 32
#define MAXTILES 6464   // >= E/64 + R ; divisible by 8
#define EQ2 (MAXTILES * 2 / 8)   // 1616 ords per XCD
#define EGRID2 (MAXTILES * 2)    // 12928 edge blocks
#define SGRID (((NN + 63) / 64) * 2)  // 3126 selfA blocks
#define SCHUNK 2048
#define NSCAN ((NN + 255) / 256) // 391

typedef __attribute__((ext_vector_type(8))) short short8v;   // 8 x bf16 (16B)
typedef __attribute__((ext_vector_type(4))) float f32x4;

__device__ __forceinline__ unsigned short f2bf(float f) {
  unsigned u = __float_as_uint(f);
  u += 0x7FFF + ((u >> 16) & 1);          // RNE
  return (unsigned short)(u >> 16);
}
__device__ __forceinline__ float bf2f(unsigned short h) {
  return __uint_as_float(((unsigned)h) << 16);
}

// ---------------------------------------------------------------------------
// prep1: blocks [0,800): wgen (L2-blocked W_r pack); [800,832): slwpk;
// [832,1344): etype hist + dst degree + (FEAT) f32->bf16 feature convert.
// W_pk layout per relation: [ct=16][kt=8][lane=64][j=8] bf16 where
//   value = W_r[k = kt*32 + (lane>>4)*8 + j][n = ct*16 + (lane&15)].
template <bool FEAT>
__global__ __launch_bounds__(256) void k_prep1(
    const float* __restrict__ basis, const float* __restrict__ coef,
    const float* __restrict__ slw, const int* __restrict__ etype,
    const int* __restrict__ dst, const float* __restrict__ in_feat,
    short* __restrict__ wpk, short* __restrict__ spk,
    int* __restrict__ hist, int* __restrict__ deg,
    unsigned short* __restrict__ featb) {
  __shared__ int lh[RR];
  int b = blockIdx.x, tid = threadIdx.x;
  if (b < 800) {                       // ---- wgen ----
    int ord = (b & 7) * 100 + (b >> 3);
    int rg = ord % 25;
    int pk8 = (ord / 25) * 256 + tid;
    int lane = pk8 & 63;
    int kt = (pk8 >> 6) & 7;
    int ct = pk8 >> 9;
    int n  = ct * 16 + (lane & 15);
    int k0 = kt * 32 + ((lane >> 4) << 3);
    float acc[8][8];
#pragma unroll
    for (int r = 0; r < 8; ++r)
#pragma unroll
      for (int j = 0; j < 8; ++j) acc[r][j] = 0.f;
    for (int bb = 0; bb < BB; ++bb) {
      float bas[8];
#pragma unroll
      for (int j = 0; j < 8; ++j) bas[j] = basis[bb * 65536 + (k0 + j) * 256 + n];
#pragma unroll
      for (int r = 0; r < 8; ++r) {
        float c = coef[(rg * 8 + r) * BB + bb];
#pragma unroll
        for (int j = 0; j < 8; ++j) acc[r][j] += c * bas[j];
      }
    }
#pragma unroll
    for (int r = 0; r < 8; ++r) {
      short8v v;
#pragma unroll
      for (int j = 0; j < 8; ++j) v[j] = (short)f2bf(acc[r][j]);
      *(short8v*)(wpk + (size_t)(rg * 8 + r) * 65536 + (size_t)pk8 * 8) = v;
    }
    return;
  }
  if (b < 832) {                       // ---- slwpk ----
    int t = (b - 800) * 256 + tid;
    int lane = t & 63;
    int kt = (t >> 6) & 7;
    int ct = t >> 9;
    int n  = ct * 16 + (lane & 15);
    int k0 = kt * 32 + ((lane >> 4) << 3);
    short8v v;
#pragma unroll
    for (int j = 0; j < 8; ++j) v[j] = (short)f2bf(slw[(k0 + j) * 256 + n]);
    *(short8v*)(spk + (size_t)t * 8) = v;
    return;
  }
  // ---- hist + deg + feat ----
  int hb = b - 832;                    // 512 blocks
  for (int i = tid; i < RR; i += 256) lh[i] = 0;
  __syncthreads();
  for (int e = hb * 256 + tid; e < EE; e += 512 * 256) {
    atomicAdd(&lh[etype[e]], 1);
    atomicAdd(&deg[dst[e]], 1);
  }
  if (FEAT) {
    const int total = NN * 64;         // float4 count
    for (int i = hb * 256 + tid; i < total; i += 512 * 256) {
      float4 v = ((const float4*)in_feat)[i];
      ushort4 h;
      h.x = f2bf(v.x); h.y = f2bf(v.y); h.z = f2bf(v.z); h.w = f2bf(v.w);
      ((ushort4*)featb)[i] = h;
    }
  }
  __syncthreads();
  for (int i = tid; i < RR; i += 256)
    if (lh[i]) atomicAdd(&hist[i], lh[i]);
}

// ---------------------------------------------------------------------------
// prep2: block 0: etype-bin scan -> cur + tdesc; blocks 1..391: deg block sums.
__global__ __launch_bounds__(256) void k_prep2(const int* __restrict__ hist,
                                               const int* __restrict__ deg,
                                               int* __restrict__ cur,
                                               int4* __restrict__ tdesc,
                                               int* __restrict__ bsum) {
  __shared__ int h[RR];
  __shared__ int off[RR];
  __shared__ int toff[RR];
  __shared__ int tot;
  __shared__ int ws4[4];
  int b = blockIdx.x, tid = threadIdx.x;
  if (b == 0) {
    for (int i = tid; i < RR; i += 256) h[i] = hist[i];
    __syncthreads();
    if (tid == 0) {
      int s = 0, ts = 0;
      for (int r = 0; r < RR; ++r) {
        off[r] = s; s += h[r];
        toff[r] = ts; ts += (h[r] + 63) >> 6;
      }
      tot = ts;
    }
    __syncthreads();
    if (tid < RR) {
      int r = tid, cnt = h[r], base = off[r], to = toff[r];
      cur[r] = base;
      int nt = (cnt + 63) >> 6;
      for (int t2 = 0; t2 < nt; ++t2)
        tdesc[to + t2] = make_int4(r, base + t2 * 64, min(64, cnt - t2 * 64), 0);
    }
    for (int i = tot + tid; i < MAXTILES; i += 256)
      tdesc[i] = make_int4(0, 0, 0, 0);
    return;
  }
  int i = (b - 1) * 256 + tid;
  int v = (i < NN) ? deg[i] : 0;
#pragma unroll
  for (int d = 32; d; d >>= 1) v += __shfl_down(v, d, 64);
  if ((tid & 63) == 0) ws4[tid >> 6] = v;
  __syncthreads();
  if (tid == 0) bsum[b - 1] = ws4[0] + ws4[1] + ws4[2] + ws4[3];
}

// prep3 (tier A): deg exclusive scan -> row_ptr/cur2; bsum prefix inline.
__global__ __launch_bounds__(256) void k_prep3(const int* __restrict__ deg,
                                               const int* __restrict__ bsum,
                                               int* __restrict__ row_ptr,
                                               int* __restrict__ cur2) {
  __shared__ int ws4[4];
  __shared__ int wo4[4];
  __shared__ int psum[4];
  int tid = threadIdx.x, b = blockIdx.x;
  int sp = 0;
  for (int i = tid; i < b; i += 256) sp += bsum[i];
#pragma unroll
  for (int d = 32; d; d >>= 1) sp += __shfl_down(sp, d, 64);
  if ((tid & 63) == 0) psum[tid >> 6] = sp;
  int i = b * 256 + tid;
  int v = (i < NN) ? deg[i] : 0;
  int x = v;
#pragma unroll
  for (int d = 1; d < 64; d <<= 1) {
    int y = __shfl_up(x, d, 64);
    if ((tid & 63) >= d) x += y;
  }
  if ((tid & 63) == 63) ws4[tid >> 6] = x;
  __syncthreads();
  if (tid == 0) {
    int s = 0;
    for (int w2 = 0; w2 < 4; ++w2) { wo4[w2] = s; s += ws4[w2]; }
    psum[0] = psum[0] + psum[1] + psum[2] + psum[3];
  }
  __syncthreads();
  int excl = x - v + wo4[tid >> 6] + psum[0];
  if (i < NN) { row_ptr[i] = excl; cur2[i] = excl; }
  if (i == 0 && b == 0) row_ptr[NN] = EE;
}

// prep4: counting-sort scatter; materializes per-position gsrc/ginv and
// (DL) gout[s] = dst-sorted msg slot. gdst only written for tiers B/C (!DL).
template <bool DL>
__global__ __launch_bounds__(256) void k_prep4(const int* __restrict__ etype,
                                               const int* __restrict__ src,
                                               const int* __restrict__ dst,
                                               const int* __restrict__ deg,
                                               int* __restrict__ cur,
                                               int* __restrict__ gsrc,
                                               int* __restrict__ gdst,
                                               float* __restrict__ ginv,
                                               int* __restrict__ cur2,
                                               int* __restrict__ gout) {
  __shared__ int lh[RR];
  __shared__ int lbase[RR];
  __shared__ int lcur[RR];
  int tid = threadIdx.x;
  int e0 = blockIdx.x * SCHUNK;
  for (int i = tid; i < RR; i += 256) lh[i] = 0;
  __syncthreads();
  for (int i = tid; i < SCHUNK; i += 256) {
    int e = e0 + i;
    if (e < EE) atomicAdd(&lh[etype[e]], 1);
  }
  __syncthreads();
  for (int i = tid; i < RR; i += 256) {
    int c = lh[i];
    lbase[i] = c ? atomicAdd(&cur[i], c) : 0;
    lcur[i] = 0;
  }
  __syncthreads();
  for (int i = tid; i < SCHUNK; i += 256) {
    int e = e0 + i;
    if (e < EE) {
      int et = etype[e];
      int s = lbase[et] + atomicAdd(&lcur[et], 1);
      int d = dst[e];
      gsrc[s] = src[e];
      ginv[s] = 1.0f / (float)max(deg[d], 1);
      if (DL) {
        int pos = atomicAdd(&cur2[d], 1);
        gout[s] = pos;
      } else {
        gdst[s] = d;
      }
    }
  }
}

// ---------------------------------------------------------------------------
// Tier A main kernel: blocks [0, EGRID2) = edge GEMM (r11 structure, measured
// best: 2 blocks/64-edge tile, 64x128 out, acc[4][2], LDS-staged A, dst-sorted
// msg stores); blocks [EGRID2, EGRID2+SGRID) = col-split self-loop GEMM
// (same register/LDS shape -> one allocation fits both; independent outputs
// let the CU scheduler overlap selfA's MFMA with edge's memory stalls).
__global__ __launch_bounds__(256) void k_main(
    const unsigned short* __restrict__ featb, const short* __restrict__ wpk,
    const short* __restrict__ spk, const int* __restrict__ gsrc,
    const float* __restrict__ ginv, const int* __restrict__ gout,
    const int4* __restrict__ tdesc, unsigned short* __restrict__ msg,
    float* __restrict__ out) {
  __shared__ __align__(16) char lA[32768];
  __shared__ int lsrc[64];
  __shared__ float linv[64];
  __shared__ int lout[64];
  int tid = threadIdx.x, wave = tid >> 6, lane = tid & 63;
  int l15 = lane & 15, lg = lane >> 4;
  int bid = blockIdx.x;

  if (bid < EGRID2) {
    // ---------------- edge path ----------------
    int ord = (bid & 7) * EQ2 + (bid >> 3);
    int tile = ord >> 1, half = ord & 1;
    int4 d = tdesc[tile];
    int rows = d.z;
    if (rows <= 0) return;
    int r = d.x, rs = d.y;
    if (tid < 64) {
      int s = min(rs + tid, EE - 1);
      lsrc[tid] = gsrc[s];
      linv[tid] = ginv[s];
      lout[tid] = gout[s];
    }
    __syncthreads();
    short8v sv[8];
#pragma unroll
    for (int u = 0; u < 8; ++u) {
      int idx = u * 256 + tid;
      int row = idx >> 5, q = idx & 31;
      sv[u] = *(const short8v*)(featb + (size_t)lsrc[row] * 256 + q * 8);
    }
#pragma unroll
    for (int u = 0; u < 8; ++u) {
      int idx = u * 256 + tid;
      int row = idx >> 5, q = idx & 31;
      *(short8v*)(lA + ((row * 512 + q * 16) ^ ((row & 7) << 4))) = sv[u];
    }
    __syncthreads();
    f32x4 acc[4][2];
#pragma unroll
    for (int m = 0; m < 4; ++m)
#pragma unroll
      for (int c = 0; c < 2; ++c) acc[m][c] = (f32x4){0.f, 0.f, 0.f, 0.f};
    const short* bp = wpk + (size_t)r * 65536 +
                      (size_t)(half * 8 + wave * 2) * 4096 + (size_t)lane * 8;
    short8v b0 = *(const short8v*)(bp);
    short8v b1 = *(const short8v*)(bp + 4096);
#pragma unroll
    for (int kt = 0; kt < 8; ++kt) {
      short8v bn0, bn1;
      if (kt < 7) {
        bn0 = *(const short8v*)(bp + (kt + 1) * 512);
        bn1 = *(const short8v*)(bp + 4096 + (kt + 1) * 512);
      }
      short8v a[4];
#pragma unroll
      for (int m = 0; m < 4; ++m) {
        int row = m * 16 + l15;
        a[m] = *(const short8v*)(lA + ((row * 512 + kt * 64 + lg * 16) ^ ((row & 7) << 4)));
      }
#pragma unroll
      for (int m = 0; m < 4; ++m) {
        acc[m][0] = __builtin_amdgcn_mfma_f32_16x16x32_bf16(a[m], b0, acc[m][0], 0, 0, 0);
        acc[m][1] = __builtin_amdgcn_mfma_f32_16x16x32_bf16(a[m], b1, acc[m][1], 0, 0, 0);
      }
      if (kt < 7) { b0 = bn0; b1 = bn1; }
    }
    __syncthreads();                          // done reading lA
#pragma unroll
    for (int m = 0; m < 4; ++m)
#pragma unroll
      for (int j = 0; j < 4; ++j) {
        int row = m * 16 + lg * 4 + j;
        float inv = linv[row];
        int rb = row * 512, sw = (row & 7) << 4;
#pragma unroll
        for (int c = 0; c < 2; ++c) {
          int col = wave * 32 + c * 16 + l15;
          *(unsigned short*)(lA + ((rb + col * 2) ^ sw)) = f2bf(acc[m][c][j] * inv);
        }
      }
    __syncthreads();
#pragma unroll
    for (int u = 0; u < 4; ++u) {
      int idx = u * 256 + tid;
      int row = idx >> 4, q = idx & 15;       // 64 rows x 16 chunks of 16B
      if (row < rows) {
        short8v vv = *(const short8v*)(lA + ((row * 512 + q * 16) ^ ((row & 7) << 4)));
        *(short8v*)(msg + (size_t)lout[row] * 256 + half * 128 + q * 8) = vv;
      }
    }
    return;
  }

  // ---------------- selfA path (col-split, acc[4][2], direct f32 store) ----
  int b2 = bid - EGRID2;
  int n0 = (b2 >> 1) * 64, half = b2 & 1;
  short8v sv[8];
#pragma unroll
  for (int u = 0; u < 8; ++u) {
    int idx = u * 256 + tid;
    int row = idx >> 5, q = idx & 31;
    int n = min(n0 + row, NN - 1);
    sv[u] = *(const short8v*)(featb + (size_t)n * 256 + q * 8);
  }
#pragma unroll
  for (int u = 0; u < 8; ++u) {
    int idx = u * 256 + tid;
    int row = idx >> 5, q = idx & 31;
    *(short8v*)(lA + ((row * 512 + q * 16) ^ ((row & 7) << 4))) = sv[u];
  }
  __syncthreads();
  f32x4 acc[4][2];
#pragma unroll
  for (int m = 0; m < 4; ++m)
#pragma unroll
    for (int c = 0; c < 2; ++c) acc[m][c] = (f32x4){0.f, 0.f, 0.f, 0.f};
  const short* bp = spk + (size_t)(half * 8 + wave * 2) * 4096 + (size_t)lane * 8;
  short8v b0 = *(const short8v*)(bp);
  short8v b1 = *(const short8v*)(bp + 4096);
#pragma unroll
  for (int kt = 0; kt < 8; ++kt) {
    short8v bn0, bn1;
    if (kt < 7) {
      bn0 = *(const short8v*)(bp + (kt + 1) * 512);
      bn1 = *(const short8v*)(bp + 4096 + (kt + 1) * 512);
    }
    short8v a[4];
#pragma unroll
    for (int m = 0; m < 4; ++m) {
      int row = m * 16 + l15;
      a[m] = *(const short8v*)(lA + ((row * 512 + kt * 64 + lg * 16) ^ ((row & 7) << 4)));
    }
#pragma unroll
    for (int m = 0; m < 4; ++m) {
      acc[m][0] = __builtin_amdgcn_mfma_f32_16x16x32_bf16(a[m], b0, acc[m][0], 0, 0, 0);
      acc[m][1] = __builtin_amdgcn_mfma_f32_16x16x32_bf16(a[m], b1, acc[m][1], 0, 0, 0);
    }
    if (kt < 7) { b0 = bn0; b1 = bn1; }
  }
#pragma unroll
  for (int m = 0; m < 4; ++m)
#pragma unroll
    for (int j = 0; j < 4; ++j) {
      int n = n0 + m * 16 + lg * 4 + j;
      if (n < NN) {
        float* op = out + (size_t)n * 256 + half * 128 + wave * 32 + l15;
        op[0]  = acc[m][0][j];
        op[16] = acc[m][1][j];
      }
    }
}

// ---------------------------------------------------------------------------
// Tier A aggregate: msg is DST-SORTED -> fully sequential streaming. One
// half-wave (32 lanes x 16B = 512B row) per dst node; RMW of out.
__global__ __launch_bounds__(256) void k_aggregate(
    const unsigned short* __restrict__ msg, const int* __restrict__ row_ptr,
    float* __restrict__ out) {
  int g = blockIdx.x * 8 + (threadIdx.x >> 5);
  if (g >= NN) return;
  int hl = threadIdx.x & 31;
  int lo = row_ptr[g], hi = row_ptr[g + 1];
  if (lo >= hi) return;
  float a[8];
#pragma unroll
  for (int k = 0; k < 8; ++k) a[k] = 0.f;
  for (int p = lo; p < hi; ++p) {
    short8v mv = *(const short8v*)(msg + (size_t)p * 256 + hl * 8);
#pragma unroll
    for (int k = 0; k < 8; ++k) a[k] += bf2f((unsigned short)mv[k]);
  }
  float* op = out + (size_t)g * 256 + hl * 8;
#pragma unroll
  for (int c = 0; c < 2; ++c) {
    f32x4 o = *(const f32x4*)(op + c * 4);
    o[0] += a[c * 4]; o[1] += a[c * 4 + 1]; o[2] += a[c * 4 + 2]; o[3] += a[c * 4 + 3];
    *(f32x4*)(op + c * 4) = o;
  }
}

// ---------------------------------------------------------------------------
// Tier B/C fallbacks (atomic epilogue), using flat gsrc/gdst/ginv metadata.
__device__ __forceinline__ void gemm64(const char* lA, const short* __restrict__ wpk,
                                       f32x4 acc[4][4], int wave, int lane) {
  int l15 = lane & 15, lg = lane >> 4;
  const short* bp = wpk + (size_t)wave * 4 * 4096 + (size_t)lane * 8;
#pragma unroll
  for (int kt = 0; kt < 8; ++kt) {
    short8v a[4], b[4];
#pragma unroll
    for (int c = 0; c < 4; ++c) b[c] = *(const short8v*)(bp + c * 4096 + kt * 512);
#pragma unroll
    for (int m = 0; m < 4; ++m) {
      int row = m * 16 + l15;
      a[m] = *(const short8v*)(lA + ((row * 512 + kt * 64 + lg * 16) ^ ((row & 7) << 4)));
    }
#pragma unroll
    for (int m = 0; m < 4; ++m)
#pragma unroll
      for (int c = 0; c < 4; ++c)
        acc[m][c] = __builtin_amdgcn_mfma_f32_16x16x32_bf16(a[m], b[c], acc[m][c], 0, 0, 0);
  }
}

template <bool B16>
__global__ __launch_bounds__(256) void k_self_gemm(const float* __restrict__ in_feat,
                                                   const unsigned short* __restrict__ featb,
                                                   const short* __restrict__ spk,
                                                   float* __restrict__ out) {
  __shared__ __align__(16) char lA[32768];
  int n0 = blockIdx.x * 64;
  int tid = threadIdx.x;
  if (B16) {
    short8v sv[8];
#pragma unroll
    for (int u = 0; u < 8; ++u) {
      int idx = u * 256 + tid;
      int row = idx >> 5, q = idx & 31;
      int n = min(n0 + row, NN - 1);
      sv[u] = *(const short8v*)(featb + (size_t)n * 256 + q * 8);
    }
#pragma unroll
    for (int u = 0; u < 8; ++u) {
      int idx = u * 256 + tid;
      int row = idx >> 5, q = idx & 31;
      *(short8v*)(lA + ((row * 512 + q * 16) ^ ((row & 7) << 4))) = sv[u];
    }
  } else {
#pragma unroll
    for (int half = 0; half < 2; ++half) {
      float4 v[8];
#pragma unroll
      for (int u = 0; u < 8; ++u) {
        int it = half * 2048 + u * 256 + tid;
        int row = it >> 6, q = it & 63;
        int n = n0 + row;
        v[u] = (n < NN) ? ((const float4*)(in_feat + (size_t)n * 256))[q]
                        : make_float4(0.f, 0.f, 0.f, 0.f);
      }
#pragma unroll
      for (int u = 0; u < 8; ++u) {
        int it = half * 2048 + u * 256 + tid;
        int row = it >> 6, q = it & 63;
        ushort4 hh;
        hh.x = f2bf(v[u].x); hh.y = f2bf(v[u].y); hh.z = f2bf(v[u].z); hh.w = f2bf(v[u].w);
        *(ushort4*)(lA + ((row * 512 + q * 8) ^ ((row & 7) << 4))) = hh;
      }
    }
  }
  __syncthreads();
  f32x4 acc[4][4];
#pragma unroll
  for (int m = 0; m < 4; ++m)
#pragma unroll
    for (int c = 0; c < 4; ++c) acc[m][c] = (f32x4){0.f, 0.f, 0.f, 0.f};
  int wave = tid >> 6, lane = tid & 63;
  gemm64(lA, spk, acc, wave, lane);
  int l15 = lane & 15, lg = lane >> 4;
#pragma unroll
  for (int m = 0; m < 4; ++m)
#pragma unroll
    for (int j = 0; j < 4; ++j) {
      int n = n0 + m * 16 + lg * 4 + j;
      if (n < NN) {
        float* op = out + (size_t)n * 256 + wave * 64 + l15;
#pragma unroll
        for (int c = 0; c < 4; ++c) op[c * 16] = acc[m][c][j];
      }
    }
}

template <int MODE>   // 0: f32 feat, 1: bf16 feat; atomic mean-scatter into out
__global__ __launch_bounds__(256) void k_edge_gemmBC(const float* __restrict__ in_feat,
                                                     const unsigned short* __restrict__ featb,
                                                     const short* __restrict__ wpk,
                                                     const int* __restrict__ gsrc,
                                                     const int* __restrict__ gdst,
                                                     const float* __restrict__ ginv,
                                                     const int4* __restrict__ tdesc,
                                                     float* __restrict__ out) {
  __shared__ __align__(16) char lA[32768];
  __shared__ int lsrc[64];
  __shared__ int ldst[64];
  __shared__ float linv[64];
  int bid = blockIdx.x;
  int tile = (bid & 7) * (MAXTILES / 8) + (bid >> 3);
  int4 d = tdesc[tile];
  int rows = d.z;
  if (rows <= 0) return;
  int r = d.x, rs = d.y;
  int tid = threadIdx.x;
  if (tid < 64) {
    if (tid < rows) {
      lsrc[tid] = gsrc[rs + tid];
      ldst[tid] = gdst[rs + tid];
      linv[tid] = ginv[rs + tid];
    } else {
      lsrc[tid] = -1; ldst[tid] = -1; linv[tid] = 0.f;
    }
  }
  __syncthreads();
  if (MODE == 1) {
    short8v sv[8];
#pragma unroll
    for (int u = 0; u < 8; ++u) {
      int idx = u * 256 + tid;
      int row = idx >> 5, q = idx & 31;
      int s = lsrc[row];
      sv[u] = (s >= 0) ? *(const short8v*)(featb + (size_t)s * 256 + q * 8)
                       : (short8v){0, 0, 0, 0, 0, 0, 0, 0};
    }
#pragma unroll
    for (int u = 0; u < 8; ++u) {
      int idx = u * 256 + tid;
      int row = idx >> 5, q = idx & 31;
      *(short8v*)(lA + ((row * 512 + q * 16) ^ ((row & 7) << 4))) = sv[u];
    }
  } else {
#pragma unroll
    for (int half = 0; half < 2; ++half) {
      float4 v[8];
#pragma unroll
      for (int u = 0; u < 8; ++u) {
        int it = half * 2048 + u * 256 + tid;
        int row = it >> 6, q = it & 63;
        int s = lsrc[row];
        v[u] = (s >= 0) ? ((const float4*)(in_feat + (size_t)s * 256))[q]
                        : make_float4(0.f, 0.f, 0.f, 0.f);
      }
#pragma unroll
      for (int u = 0; u < 8; ++u) {
        int it = half * 2048 + u * 256 + tid;
        int row = it >> 6, q = it & 63;
        ushort4 hh;
        hh.x = f2bf(v[u].x); hh.y = f2bf(v[u].y); hh.z = f2bf(v[u].z); hh.w = f2bf(v[u].w);
        *(ushort4*)(lA + ((row * 512 + q * 8) ^ ((row & 7) << 4))) = hh;
      }
    }
  }
  __syncthreads();
  f32x4 acc[4][4];
#pragma unroll
  for (int m = 0; m < 4; ++m)
#pragma unroll
    for (int c = 0; c < 4; ++c) acc[m][c] = (f32x4){0.f, 0.f, 0.f, 0.f};
  int wave = tid >> 6, lane = tid & 63;
  gemm64(lA, wpk + (size_t)r * 65536, acc, wave, lane);
  int l15 = lane & 15, lg = lane >> 4;
#pragma unroll
  for (int m = 0; m < 4; ++m)
#pragma unroll
    for (int j = 0; j < 4; ++j) {
      int row = m * 16 + lg * 4 + j;
      int dd = ldst[row];
      if (dd >= 0) {
        float inv = linv[row];
        float* op = out + (size_t)dd * 256 + wave * 64 + l15;
#pragma unroll
        for (int c = 0; c < 4; ++c) unsafeAtomicAdd(op + c * 16, acc[m][c][j] * inv);
      }
    }
}

// ---------------------------------------------------------------------------
extern "C" void kernel_launch(void* const* d_in, const int* in_sizes, int n_in,
                              void* d_out, int out_size, void* d_ws, size_t ws_size,
                              hipStream_t stream) {
  const float* in_feat = (const float*)d_in[0];
  const float* basis   = (const float*)d_in[1];
  const float* coef    = (const float*)d_in[2];
  const float* slw     = (const float*)d_in[3];
  const int*   src     = (const int*)d_in[4];
  const int*   dst     = (const int*)d_in[5];
  const int*   etype   = (const int*)d_in[6];
  float* out = (float*)d_out;

  char* base = (char*)d_ws;
  char* w = base;
  auto alloc = [&](size_t bytes) {
    char* p = w;
    w += (bytes + 255) & ~(size_t)255;
    return p;
  };
  // base group (tiers B/C)
  short* wpk  = (short*)alloc((size_t)RR * 65536 * 2);   // 26.2 MB
  short* spk  = (short*)alloc(65536 * 2);
  int*   gsrc = (int*)alloc((size_t)EE * 4);
  int*   gdst = (int*)alloc((size_t)EE * 4);
  float* ginv = (float*)alloc((size_t)EE * 4);
  int*   deg  = (int*)alloc((size_t)NN * 4);
  int*   hist = (int*)alloc(RR * 4);
  int*   cur  = (int*)alloc(RR * 4);
  int4*  tdesc = (int4*)alloc((size_t)MAXTILES * 16);
  int*   bsum = (int*)alloc(NSCAN * 4);
  // tier B adds bf16 feat
  unsigned short* featb = (unsigned short*)alloc((size_t)NN * 256 * 2);  // 51.2 MB
  size_t need_b = (size_t)(w - base);
  // tier A adds dst-CSR + msg buffer
  int* row_ptr = (int*)alloc((size_t)(NN + 1) * 4);
  int* cur2    = (int*)alloc((size_t)NN * 4);
  int* gout    = (int*)alloc((size_t)EE * 4);
  unsigned short* msg = (unsigned short*)alloc((size_t)EE * 256 * 2);    // 204.8 MB
  size_t need_a = (size_t)(w - base);

  bool tierA = ws_size >= need_a;
  bool tierB = ws_size >= need_b;

  hipMemsetAsync(hist, 0, RR * 4, stream);
  hipMemsetAsync(deg, 0, (size_t)NN * 4, stream);

  if (tierA) {
    k_prep1<true><<<1344, 256, 0, stream>>>(basis, coef, slw, etype, dst, in_feat,
                                            wpk, spk, hist, deg, featb);
    k_prep2<<<NSCAN + 1, 256, 0, stream>>>(hist, deg, cur, tdesc, bsum);
    k_prep3<<<NSCAN, 256, 0, stream>>>(deg, bsum, row_ptr, cur2);
    k_prep4<true><<<(EE + SCHUNK - 1) / SCHUNK, 256, 0, stream>>>(
        etype, src, dst, deg, cur, gsrc, gdst, ginv, cur2, gout);
    k_main<<<EGRID2 + SGRID, 256, 0, stream>>>(featb, wpk, spk, gsrc, ginv, gout,
                                               tdesc, msg, out);
    k_aggregate<<<(NN + 7) / 8, 256, 0, stream>>>(msg, row_ptr, out);
  } else if (tierB) {
    k_prep1<true><<<1344, 256, 0, stream>>>(basis, coef, slw, etype, dst, in_feat,
                                            wpk, spk, hist, deg, featb);
    k_prep2<<<NSCAN + 1, 256, 0, stream>>>(hist, deg, cur, tdesc, bsum);
    k_prep4<false><<<(EE + SCHUNK - 1) / SCHUNK, 256, 0, stream>>>(
        etype, src, dst, deg, cur, gsrc, gdst, ginv, nullptr, nullptr);
    k_self_gemm<true><<<(NN + 63) / 64, 256, 0, stream>>>(in_feat, featb, spk, out);
    k_edge_gemmBC<1><<<MAXTILES, 256, 0, stream>>>(in_feat, featb, wpk, gsrc, gdst,
                                                   ginv, tdesc, out);
  } else {
    k_prep1<false><<<1344, 256, 0, stream>>>(basis, coef, slw, etype, dst, in_feat,
                                             wpk, spk, hist, deg, nullptr);
    k_prep2<<<NSCAN + 1, 256, 0, stream>>>(hist, deg, cur, tdesc, bsum);
    k_prep4<false><<<(EE + SCHUNK - 1) / SCHUNK, 256, 0, stream>>>(
        etype, src, dst, deg, cur, gsrc, gdst, ginv, nullptr, nullptr);
    k_self_gemm<false><<<(NN + 63) / 64, 256, 0, stream>>>(in_feat, nullptr, spk, out);
    k_edge_gemmBC<0><<<MAXTILES, 256, 0, stream>>>(in_feat, nullptr, wpk, gsrc, gdst,
                                                   ginv, tdesc, out);
  }
}

// Round 13
// 329.200 us; speedup vs baseline: 1.3081x; 1.0459x over previous
//
#include <hip/hip_runtime.h>
#include <hip/hip_bf16.h>

// RGCN forward, MI355X. N=100000, E=400000, IN=OUT=256, R=200, B=32.
// Tier A+: prep1{wgen|slwpk|hist+feat} -> prep2{etype-scan|deg-blocksums} ->
// prep3{deg-scan} -> prep4{scatter: gsrc/ginv/gout} ->
// k_main{edge GEMM (r11 structure) + col-split selfA GEMM -> bf16 sbuf} ->
// aggregate{out[n] = sbuf[n] + sum msg rows, single write, no RMW}.
// Tier A: r12 behavior (selfA -> f32 out, aggregate RMW). Tiers B/C: atomic.

#define NN 100000
#define EE 400000
#define RR 200
#define BB 32
#define MAXTILES 6464   // >= E/64 + R ; divisible by 8
#define EQ2 (MAXTILES * 2 / 8)   // 1616 ords per XCD
#define EGRID2 (MAXTILES * 2)    // 12928 edge blocks
#define SGRID (((NN + 63) / 64) * 2)  // 3126 selfA blocks
#define SCHUNK 2048
#define NSCAN ((NN + 255) / 256) // 391

typedef __attribute__((ext_vector_type(8))) short short8v;   // 8 x bf16 (16B)
typedef __attribute__((ext_vector_type(4))) float f32x4;

__device__ __forceinline__ unsigned short f2bf(float f) {
  unsigned u = __float_as_uint(f);
  u += 0x7FFF + ((u >> 16) & 1);          // RNE
  return (unsigned short)(u >> 16);
}
__device__ __forceinline__ float bf2f(unsigned short h) {
  return __uint_as_float(((unsigned)h) << 16);
}

// ---------------------------------------------------------------------------
// prep1: blocks [0,800): wgen (L2-blocked W_r pack); [800,832): slwpk;
// [832,1344): etype hist + dst degree + (FEAT) f32->bf16 feature convert.
// W_pk layout per relation: [ct=16][kt=8][lane=64][j=8] bf16 where
//   value = W_r[k = kt*32 + (lane>>4)*8 + j][n = ct*16 + (lane&15)].
template <bool FEAT>
__global__ __launch_bounds__(256) void k_prep1(
    const float* __restrict__ basis, const float* __restrict__ coef,
    const float* __restrict__ slw, const int* __restrict__ etype,
    const int* __restrict__ dst, const float* __restrict__ in_feat,
    short* __restrict__ wpk, short* __restrict__ spk,
    int* __restrict__ hist, int* __restrict__ deg,
    unsigned short* __restrict__ featb) {
  __shared__ int lh[RR];
  int b = blockIdx.x, tid = threadIdx.x;
  if (b < 800) {                       // ---- wgen ----
    int ord = (b & 7) * 100 + (b >> 3);
    int rg = ord % 25;
    int pk8 = (ord / 25) * 256 + tid;
    int lane = pk8 & 63;
    int kt = (pk8 >> 6) & 7;
    int ct = pk8 >> 9;
    int n  = ct * 16 + (lane & 15);
    int k0 = kt * 32 + ((lane >> 4) << 3);
    float acc[8][8];
#pragma unroll
    for (int r = 0; r < 8; ++r)
#pragma unroll
      for (int j = 0; j < 8; ++j) acc[r][j] = 0.f;
    for (int bb = 0; bb < BB; ++bb) {
      float bas[8];
#pragma unroll
      for (int j = 0; j < 8; ++j) bas[j] = basis[bb * 65536 + (k0 + j) * 256 + n];
#pragma unroll
      for (int r = 0; r < 8; ++r) {
        float c = coef[(rg * 8 + r) * BB + bb];
#pragma unroll
        for (int j = 0; j < 8; ++j) acc[r][j] += c * bas[j];
      }
    }
#pragma unroll
    for (int r = 0; r < 8; ++r) {
      short8v v;
#pragma unroll
      for (int j = 0; j < 8; ++j) v[j] = (short)f2bf(acc[r][j]);
      *(short8v*)(wpk + (size_t)(rg * 8 + r) * 65536 + (size_t)pk8 * 8) = v;
    }
    return;
  }
  if (b < 832) {                       // ---- slwpk ----
    int t = (b - 800) * 256 + tid;
    int lane = t & 63;
    int kt = (t >> 6) & 7;
    int ct = t >> 9;
    int n  = ct * 16 + (lane & 15);
    int k0 = kt * 32 + ((lane >> 4) << 3);
    short8v v;
#pragma unroll
    for (int j = 0; j < 8; ++j) v[j] = (short)f2bf(slw[(k0 + j) * 256 + n]);
    *(short8v*)(spk + (size_t)t * 8) = v;
    return;
  }
  // ---- hist + deg + feat ----
  int hb = b - 832;                    // 512 blocks
  for (int i = tid; i < RR; i += 256) lh[i] = 0;
  __syncthreads();
  for (int e = hb * 256 + tid; e < EE; e += 512 * 256) {
    atomicAdd(&lh[etype[e]], 1);
    atomicAdd(&deg[dst[e]], 1);
  }
  if (FEAT) {
    const int total = NN * 64;         // float4 count
    for (int i = hb * 256 + tid; i < total; i += 512 * 256) {
      float4 v = ((const float4*)in_feat)[i];
      ushort4 h;
      h.x = f2bf(v.x); h.y = f2bf(v.y); h.z = f2bf(v.z); h.w = f2bf(v.w);
      ((ushort4*)featb)[i] = h;
    }
  }
  __syncthreads();
  for (int i = tid; i < RR; i += 256)
    if (lh[i]) atomicAdd(&hist[i], lh[i]);
}

// ---------------------------------------------------------------------------
// prep2: block 0: etype-bin scan -> cur + tdesc; blocks 1..391: deg block sums.
__global__ __launch_bounds__(256) void k_prep2(const int* __restrict__ hist,
                                               const int* __restrict__ deg,
                                               int* __restrict__ cur,
                                               int4* __restrict__ tdesc,
                                               int* __restrict__ bsum) {
  __shared__ int h[RR];
  __shared__ int off[RR];
  __shared__ int toff[RR];
  __shared__ int tot;
  __shared__ int ws4[4];
  int b = blockIdx.x, tid = threadIdx.x;
  if (b == 0) {
    for (int i = tid; i < RR; i += 256) h[i] = hist[i];
    __syncthreads();
    if (tid == 0) {
      int s = 0, ts = 0;
      for (int r = 0; r < RR; ++r) {
        off[r] = s; s += h[r];
        toff[r] = ts; ts += (h[r] + 63) >> 6;
      }
      tot = ts;
    }
    __syncthreads();
    if (tid < RR) {
      int r = tid, cnt = h[r], base = off[r], to = toff[r];
      cur[r] = base;
      int nt = (cnt + 63) >> 6;
      for (int t2 = 0; t2 < nt; ++t2)
        tdesc[to + t2] = make_int4(r, base + t2 * 64, min(64, cnt - t2 * 64), 0);
    }
    for (int i = tot + tid; i < MAXTILES; i += 256)
      tdesc[i] = make_int4(0, 0, 0, 0);
    return;
  }
  int i = (b - 1) * 256 + tid;
  int v = (i < NN) ? deg[i] : 0;
#pragma unroll
  for (int d = 32; d; d >>= 1) v += __shfl_down(v, d, 64);
  if ((tid & 63) == 0) ws4[tid >> 6] = v;
  __syncthreads();
  if (tid == 0) bsum[b - 1] = ws4[0] + ws4[1] + ws4[2] + ws4[3];
}

// prep3 (tier A): deg exclusive scan -> row_ptr/cur2; bsum prefix inline.
__global__ __launch_bounds__(256) void k_prep3(const int* __restrict__ deg,
                                               const int* __restrict__ bsum,
                                               int* __restrict__ row_ptr,
                                               int* __restrict__ cur2) {
  __shared__ int ws4[4];
  __shared__ int wo4[4];
  __shared__ int psum[4];
  int tid = threadIdx.x, b = blockIdx.x;
  int sp = 0;
  for (int i = tid; i < b; i += 256) sp += bsum[i];
#pragma unroll
  for (int d = 32; d; d >>= 1) sp += __shfl_down(sp, d, 64);
  if ((tid & 63) == 0) psum[tid >> 6] = sp;
  int i = b * 256 + tid;
  int v = (i < NN) ? deg[i] : 0;
  int x = v;
#pragma unroll
  for (int d = 1; d < 64; d <<= 1) {
    int y = __shfl_up(x, d, 64);
    if ((tid & 63) >= d) x += y;
  }
  if ((tid & 63) == 63) ws4[tid >> 6] = x;
  __syncthreads();
  if (tid == 0) {
    int s = 0;
    for (int w2 = 0; w2 < 4; ++w2) { wo4[w2] = s; s += ws4[w2]; }
    psum[0] = psum[0] + psum[1] + psum[2] + psum[3];
  }
  __syncthreads();
  int excl = x - v + wo4[tid >> 6] + psum[0];
  if (i < NN) { row_ptr[i] = excl; cur2[i] = excl; }
  if (i == 0 && b == 0) row_ptr[NN] = EE;
}

// prep4: counting-sort scatter; materializes per-position gsrc/ginv and
// (DL) gout[s] = dst-sorted msg slot. gdst only written for tiers B/C (!DL).
template <bool DL>
__global__ __launch_bounds__(256) void k_prep4(const int* __restrict__ etype,
                                               const int* __restrict__ src,
                                               const int* __restrict__ dst,
                                               const int* __restrict__ deg,
                                               int* __restrict__ cur,
                                               int* __restrict__ gsrc,
                                               int* __restrict__ gdst,
                                               float* __restrict__ ginv,
                                               int* __restrict__ cur2,
                                               int* __restrict__ gout) {
  __shared__ int lh[RR];
  __shared__ int lbase[RR];
  __shared__ int lcur[RR];
  int tid = threadIdx.x;
  int e0 = blockIdx.x * SCHUNK;
  for (int i = tid; i < RR; i += 256) lh[i] = 0;
  __syncthreads();
  for (int i = tid; i < SCHUNK; i += 256) {
    int e = e0 + i;
    if (e < EE) atomicAdd(&lh[etype[e]], 1);
  }
  __syncthreads();
  for (int i = tid; i < RR; i += 256) {
    int c = lh[i];
    lbase[i] = c ? atomicAdd(&cur[i], c) : 0;
    lcur[i] = 0;
  }
  __syncthreads();
  for (int i = tid; i < SCHUNK; i += 256) {
    int e = e0 + i;
    if (e < EE) {
      int et = etype[e];
      int s = lbase[et] + atomicAdd(&lcur[et], 1);
      int d = dst[e];
      gsrc[s] = src[e];
      ginv[s] = 1.0f / (float)max(deg[d], 1);
      if (DL) {
        int pos = atomicAdd(&cur2[d], 1);
        gout[s] = pos;
      } else {
        gdst[s] = d;
      }
    }
  }
}

// ---------------------------------------------------------------------------
// Tier A/A+ main kernel. Blocks [0, EGRID2) = edge GEMM (r11 structure);
// blocks [EGRID2, EGRID2+SGRID) = col-split self-loop GEMM.
// SB=true (tier A+): selfA stores bf16 rows to sbuf via LDS repack (coalesced
// 16B) instead of strided f32 out stores — aggregate then writes out once.
template <bool SB>
__global__ __launch_bounds__(256) void k_main(
    const unsigned short* __restrict__ featb, const short* __restrict__ wpk,
    const short* __restrict__ spk, const int* __restrict__ gsrc,
    const float* __restrict__ ginv, const int* __restrict__ gout,
    const int4* __restrict__ tdesc, unsigned short* __restrict__ msg,
    float* __restrict__ out, unsigned short* __restrict__ sbuf) {
  __shared__ __align__(16) char lA[32768];
  __shared__ int lsrc[64];
  __shared__ float linv[64];
  __shared__ int lout[64];
  int tid = threadIdx.x, wave = tid >> 6, lane = tid & 63;
  int l15 = lane & 15, lg = lane >> 4;
  int bid = blockIdx.x;

  if (bid < EGRID2) {
    // ---------------- edge path ----------------
    int ord = (bid & 7) * EQ2 + (bid >> 3);
    int tile = ord >> 1, half = ord & 1;
    int4 d = tdesc[tile];
    int rows = d.z;
    if (rows <= 0) return;
    int r = d.x, rs = d.y;
    if (tid < 64) {
      int s = min(rs + tid, EE - 1);
      lsrc[tid] = gsrc[s];
      linv[tid] = ginv[s];
      lout[tid] = gout[s];
    }
    __syncthreads();
    short8v sv[8];
#pragma unroll
    for (int u = 0; u < 8; ++u) {
      int idx = u * 256 + tid;
      int row = idx >> 5, q = idx & 31;
      sv[u] = *(const short8v*)(featb + (size_t)lsrc[row] * 256 + q * 8);
    }
#pragma unroll
    for (int u = 0; u < 8; ++u) {
      int idx = u * 256 + tid;
      int row = idx >> 5, q = idx & 31;
      *(short8v*)(lA + ((row * 512 + q * 16) ^ ((row & 7) << 4))) = sv[u];
    }
    __syncthreads();
    f32x4 acc[4][2];
#pragma unroll
    for (int m = 0; m < 4; ++m)
#pragma unroll
      for (int c = 0; c < 2; ++c) acc[m][c] = (f32x4){0.f, 0.f, 0.f, 0.f};
    const short* bp = wpk + (size_t)r * 65536 +
                      (size_t)(half * 8 + wave * 2) * 4096 + (size_t)lane * 8;
    short8v b0 = *(const short8v*)(bp);
    short8v b1 = *(const short8v*)(bp + 4096);
#pragma unroll
    for (int kt = 0; kt < 8; ++kt) {
      short8v bn0, bn1;
      if (kt < 7) {
        bn0 = *(const short8v*)(bp + (kt + 1) * 512);
        bn1 = *(const short8v*)(bp + 4096 + (kt + 1) * 512);
      }
      short8v a[4];
#pragma unroll
      for (int m = 0; m < 4; ++m) {
        int row = m * 16 + l15;
        a[m] = *(const short8v*)(lA + ((row * 512 + kt * 64 + lg * 16) ^ ((row & 7) << 4)));
      }
#pragma unroll
      for (int m = 0; m < 4; ++m) {
        acc[m][0] = __builtin_amdgcn_mfma_f32_16x16x32_bf16(a[m], b0, acc[m][0], 0, 0, 0);
        acc[m][1] = __builtin_amdgcn_mfma_f32_16x16x32_bf16(a[m], b1, acc[m][1], 0, 0, 0);
      }
      if (kt < 7) { b0 = bn0; b1 = bn1; }
    }
    __syncthreads();                          // done reading lA
#pragma unroll
    for (int m = 0; m < 4; ++m)
#pragma unroll
      for (int j = 0; j < 4; ++j) {
        int row = m * 16 + lg * 4 + j;
        float inv = linv[row];
        int rb = row * 512, sw = (row & 7) << 4;
#pragma unroll
        for (int c = 0; c < 2; ++c) {
          int col = wave * 32 + c * 16 + l15;
          *(unsigned short*)(lA + ((rb + col * 2) ^ sw)) = f2bf(acc[m][c][j] * inv);
        }
      }
    __syncthreads();
#pragma unroll
    for (int u = 0; u < 4; ++u) {
      int idx = u * 256 + tid;
      int row = idx >> 4, q = idx & 15;       // 64 rows x 16 chunks of 16B
      if (row < rows) {
        short8v vv = *(const short8v*)(lA + ((row * 512 + q * 16) ^ ((row & 7) << 4)));
        *(short8v*)(msg + (size_t)lout[row] * 256 + half * 128 + q * 8) = vv;
      }
    }
    return;
  }

  // ---------------- selfA path (col-split, acc[4][2]) ----------------
  int b2 = bid - EGRID2;
  int n0 = (b2 >> 1) * 64, half = b2 & 1;
  int rows = min(64, NN - n0);
  short8v sv[8];
#pragma unroll
  for (int u = 0; u < 8; ++u) {
    int idx = u * 256 + tid;
    int row = idx >> 5, q = idx & 31;
    int n = min(n0 + row, NN - 1);
    sv[u] = *(const short8v*)(featb + (size_t)n * 256 + q * 8);
  }
#pragma unroll
  for (int u = 0; u < 8; ++u) {
    int idx = u * 256 + tid;
    int row = idx >> 5, q = idx & 31;
    *(short8v*)(lA + ((row * 512 + q * 16) ^ ((row & 7) << 4))) = sv[u];
  }
  __syncthreads();
  f32x4 acc[4][2];
#pragma unroll
  for (int m = 0; m < 4; ++m)
#pragma unroll
    for (int c = 0; c < 2; ++c) acc[m][c] = (f32x4){0.f, 0.f, 0.f, 0.f};
  const short* bp = spk + (size_t)(half * 8 + wave * 2) * 4096 + (size_t)lane * 8;
  short8v b0 = *(const short8v*)(bp);
  short8v b1 = *(const short8v*)(bp + 4096);
#pragma unroll
  for (int kt = 0; kt < 8; ++kt) {
    short8v bn0, bn1;
    if (kt < 7) {
      bn0 = *(const short8v*)(bp + (kt + 1) * 512);
      bn1 = *(const short8v*)(bp + 4096 + (kt + 1) * 512);
    }
    short8v a[4];
#pragma unroll
    for (int m = 0; m < 4; ++m) {
      int row = m * 16 + l15;
      a[m] = *(const short8v*)(lA + ((row * 512 + kt * 64 + lg * 16) ^ ((row & 7) << 4)));
    }
#pragma unroll
    for (int m = 0; m < 4; ++m) {
      acc[m][0] = __builtin_amdgcn_mfma_f32_16x16x32_bf16(a[m], b0, acc[m][0], 0, 0, 0);
      acc[m][1] = __builtin_amdgcn_mfma_f32_16x16x32_bf16(a[m], b1, acc[m][1], 0, 0, 0);
    }
    if (kt < 7) { b0 = bn0; b1 = bn1; }
  }
  if (SB) {
    // repack to bf16 via lA, coalesced 16B stores to sbuf
    __syncthreads();                          // done reading lA
#pragma unroll
    for (int m = 0; m < 4; ++m)
#pragma unroll
      for (int j = 0; j < 4; ++j) {
        int row = m * 16 + lg * 4 + j;
        int rb = row * 512, sw = (row & 7) << 4;
#pragma unroll
        for (int c = 0; c < 2; ++c) {
          int col = wave * 32 + c * 16 + l15;
          *(unsigned short*)(lA + ((rb + col * 2) ^ sw)) = f2bf(acc[m][c][j]);
        }
      }
    __syncthreads();
#pragma unroll
    for (int u = 0; u < 4; ++u) {
      int idx = u * 256 + tid;
      int row = idx >> 4, q = idx & 15;
      if (row < rows) {
        short8v vv = *(const short8v*)(lA + ((row * 512 + q * 16) ^ ((row & 7) << 4)));
        *(short8v*)(sbuf + (size_t)(n0 + row) * 256 + half * 128 + q * 8) = vv;
      }
    }
  } else {
#pragma unroll
    for (int m = 0; m < 4; ++m)
#pragma unroll
      for (int j = 0; j < 4; ++j) {
        int n = n0 + m * 16 + lg * 4 + j;
        if (n < NN) {
          float* op = out + (size_t)n * 256 + half * 128 + wave * 32 + l15;
          op[0]  = acc[m][0][j];
          op[16] = acc[m][1][j];
        }
      }
  }
}

// ---------------------------------------------------------------------------
// Aggregate. SB=true: out[n] = sbuf[n] + sum msg rows (single write, all n).
// SB=false: RMW out (selfA already wrote it). msg is dst-sorted -> contiguous.
template <bool SB>
__global__ __launch_bounds__(256) void k_aggregate(
    const unsigned short* __restrict__ msg, const int* __restrict__ row_ptr,
    const unsigned short* __restrict__ sbuf, float* __restrict__ out) {
  int g = blockIdx.x * 8 + (threadIdx.x >> 5);
  if (g >= NN) return;
  int hl = threadIdx.x & 31;
  int lo = row_ptr[g], hi = row_ptr[g + 1];
  float a[8];
  if (SB) {
    short8v s0 = *(const short8v*)(sbuf + (size_t)g * 256 + hl * 8);
#pragma unroll
    for (int k = 0; k < 8; ++k) a[k] = bf2f((unsigned short)s0[k]);
  } else {
    if (lo >= hi) return;
#pragma unroll
    for (int k = 0; k < 8; ++k) a[k] = 0.f;
  }
  for (int p = lo; p < hi; ++p) {
    short8v mv = *(const short8v*)(msg + (size_t)p * 256 + hl * 8);
#pragma unroll
    for (int k = 0; k < 8; ++k) a[k] += bf2f((unsigned short)mv[k]);
  }
  float* op = out + (size_t)g * 256 + hl * 8;
  if (SB) {
#pragma unroll
    for (int c = 0; c < 2; ++c) {
      f32x4 o;
      o[0] = a[c * 4]; o[1] = a[c * 4 + 1]; o[2] = a[c * 4 + 2]; o[3] = a[c * 4 + 3];
      *(f32x4*)(op + c * 4) = o;
    }
  } else {
#pragma unroll
    for (int c = 0; c < 2; ++c) {
      f32x4 o = *(const f32x4*)(op + c * 4);
      o[0] += a[c * 4]; o[1] += a[c * 4 + 1]; o[2] += a[c * 4 + 2]; o[3] += a[c * 4 + 3];
      *(f32x4*)(op + c * 4) = o;
    }
  }
}

// ---------------------------------------------------------------------------
// Tier B/C fallbacks (atomic epilogue), using flat gsrc/gdst/ginv metadata.
__device__ __forceinline__ void gemm64(const char* lA, const short* __restrict__ wpk,
                                       f32x4 acc[4][4], int wave, int lane) {
  int l15 = lane & 15, lg = lane >> 4;
  const short* bp = wpk + (size_t)wave * 4 * 4096 + (size_t)lane * 8;
#pragma unroll
  for (int kt = 0; kt < 8; ++kt) {
    short8v a[4], b[4];
#pragma unroll
    for (int c = 0; c < 4; ++c) b[c] = *(const short8v*)(bp + c * 4096 + kt * 512);
#pragma unroll
    for (int m = 0; m < 4; ++m) {
      int row = m * 16 + l15;
      a[m] = *(const short8v*)(lA + ((row * 512 + kt * 64 + lg * 16) ^ ((row & 7) << 4)));
    }
#pragma unroll
    for (int m = 0; m < 4; ++m)
#pragma unroll
      for (int c = 0; c < 4; ++c)
        acc[m][c] = __builtin_amdgcn_mfma_f32_16x16x32_bf16(a[m], b[c], acc[m][c], 0, 0, 0);
  }
}

template <bool B16>
__global__ __launch_bounds__(256) void k_self_gemm(const float* __restrict__ in_feat,
                                                   const unsigned short* __restrict__ featb,
                                                   const short* __restrict__ spk,
                                                   float* __restrict__ out) {
  __shared__ __align__(16) char lA[32768];
  int n0 = blockIdx.x * 64;
  int tid = threadIdx.x;
  if (B16) {
    short8v sv[8];
#pragma unroll
    for (int u = 0; u < 8; ++u) {
      int idx = u * 256 + tid;
      int row = idx >> 5, q = idx & 31;
      int n = min(n0 + row, NN - 1);
      sv[u] = *(const short8v*)(featb + (size_t)n * 256 + q * 8);
    }
#pragma unroll
    for (int u = 0; u < 8; ++u) {
      int idx = u * 256 + tid;
      int row = idx >> 5, q = idx & 31;
      *(short8v*)(lA + ((row * 512 + q * 16) ^ ((row & 7) << 4))) = sv[u];
    }
  } else {
#pragma unroll
    for (int half = 0; half < 2; ++half) {
      float4 v[8];
#pragma unroll
      for (int u = 0; u < 8; ++u) {
        int it = half * 2048 + u * 256 + tid;
        int row = it >> 6, q = it & 63;
        int n = n0 + row;
        v[u] = (n < NN) ? ((const float4*)(in_feat + (size_t)n * 256))[q]
                        : make_float4(0.f, 0.f, 0.f, 0.f);
      }
#pragma unroll
      for (int u = 0; u < 8; ++u) {
        int it = half * 2048 + u * 256 + tid;
        int row = it >> 6, q = it & 63;
        ushort4 hh;
        hh.x = f2bf(v[u].x); hh.y = f2bf(v[u].y); hh.z = f2bf(v[u].z); hh.w = f2bf(v[u].w);
        *(ushort4*)(lA + ((row * 512 + q * 8) ^ ((row & 7) << 4))) = hh;
      }
    }
  }
  __syncthreads();
  f32x4 acc[4][4];
#pragma unroll
  for (int m = 0; m < 4; ++m)
#pragma unroll
    for (int c = 0; c < 4; ++c) acc[m][c] = (f32x4){0.f, 0.f, 0.f, 0.f};
  int wave = tid >> 6, lane = tid & 63;
  gemm64(lA, spk, acc, wave, lane);
  int l15 = lane & 15, lg = lane >> 4;
#pragma unroll
  for (int m = 0; m < 4; ++m)
#pragma unroll
    for (int j = 0; j < 4; ++j) {
      int n = n0 + m * 16 + lg * 4 + j;
      if (n < NN) {
        float* op = out + (size_t)n * 256 + wave * 64 + l15;
#pragma unroll
        for (int c = 0; c < 4; ++c) op[c * 16] = acc[m][c][j];
      }
    }
}

template <int MODE>   // 0: f32 feat, 1: bf16 feat; atomic mean-scatter into out
__global__ __launch_bounds__(256) void k_edge_gemmBC(const float* __restrict__ in_feat,
                                                     const unsigned short* __restrict__ featb,
                                                     const short* __restrict__ wpk,
                                                     const int* __restrict__ gsrc,
                                                     const int* __restrict__ gdst,
                                                     const float* __restrict__ ginv,
                                                     const int4* __restrict__ tdesc,
                                                     float* __restrict__ out) {
  __shared__ __align__(16) char lA[32768];
  __shared__ int lsrc[64];
  __shared__ int ldst[64];
  __shared__ float linv[64];
  int bid = blockIdx.x;
  int tile = (bid & 7) * (MAXTILES / 8) + (bid >> 3);
  int4 d = tdesc[tile];
  int rows = d.z;
  if (rows <= 0) return;
  int r = d.x, rs = d.y;
  int tid = threadIdx.x;
  if (tid < 64) {
    if (tid < rows) {
      lsrc[tid] = gsrc[rs + tid];
      ldst[tid] = gdst[rs + tid];
      linv[tid] = ginv[rs + tid];
    } else {
      lsrc[tid] = -1; ldst[tid] = -1; linv[tid] = 0.f;
    }
  }
  __syncthreads();
  if (MODE == 1) {
    short8v sv[8];
#pragma unroll
    for (int u = 0; u < 8; ++u) {
      int idx = u * 256 + tid;
      int row = idx >> 5, q = idx & 31;
      int s = lsrc[row];
      sv[u] = (s >= 0) ? *(const short8v*)(featb + (size_t)s * 256 + q * 8)
                       : (short8v){0, 0, 0, 0, 0, 0, 0, 0};
    }
#pragma unroll
    for (int u = 0; u < 8; ++u) {
      int idx = u * 256 + tid;
      int row = idx >> 5, q = idx & 31;
      *(short8v*)(lA + ((row * 512 + q * 16) ^ ((row & 7) << 4))) = sv[u];
    }
  } else {
#pragma unroll
    for (int half = 0; half < 2; ++half) {
      float4 v[8];
#pragma unroll
      for (int u = 0; u < 8; ++u) {
        int it = half * 2048 + u * 256 + tid;
        int row = it >> 6, q = it & 63;
        int s = lsrc[row];
        v[u] = (s >= 0) ? ((const float4*)(in_feat + (size_t)s * 256))[q]
                        : make_float4(0.f, 0.f, 0.f, 0.f);
      }
#pragma unroll
      for (int u = 0; u < 8; ++u) {
        int it = half * 2048 + u * 256 + tid;
        int row = it >> 6, q = it & 63;
        ushort4 hh;
        hh.x = f2bf(v[u].x); hh.y = f2bf(v[u].y); hh.z = f2bf(v[u].z); hh.w = f2bf(v[u].w);
        *(ushort4*)(lA + ((row * 512 + q * 8) ^ ((row & 7) << 4))) = hh;
      }
    }
  }
  __syncthreads();
  f32x4 acc[4][4];
#pragma unroll
  for (int m = 0; m < 4; ++m)
#pragma unroll
    for (int c = 0; c < 4; ++c) acc[m][c] = (f32x4){0.f, 0.f, 0.f, 0.f};
  int wave = tid >> 6, lane = tid & 63;
  gemm64(lA, wpk + (size_t)r * 65536, acc, wave, lane);
  int l15 = lane & 15, lg = lane >> 4;
#pragma unroll
  for (int m = 0; m < 4; ++m)
#pragma unroll
    for (int j = 0; j < 4; ++j) {
      int row = m * 16 + lg * 4 + j;
      int dd = ldst[row];
      if (dd >= 0) {
        float inv = linv[row];
        float* op = out + (size_t)dd * 256 + wave * 64 + l15;
#pragma unroll
        for (int c = 0; c < 4; ++c) unsafeAtomicAdd(op + c * 16, acc[m][c][j] * inv);
      }
    }
}

// ---------------------------------------------------------------------------
extern "C" void kernel_launch(void* const* d_in, const int* in_sizes, int n_in,
                              void* d_out, int out_size, void* d_ws, size_t ws_size,
                              hipStream_t stream) {
  const float* in_feat = (const float*)d_in[0];
  const float* basis   = (const float*)d_in[1];
  const float* coef    = (const float*)d_in[2];
  const float* slw     = (const float*)d_in[3];
  const int*   src     = (const int*)d_in[4];
  const int*   dst     = (const int*)d_in[5];
  const int*   etype   = (const int*)d_in[6];
  float* out = (float*)d_out;

  char* base = (char*)d_ws;
  char* w = base;
  auto alloc = [&](size_t bytes) {
    char* p = w;
    w += (bytes + 255) & ~(size_t)255;
    return p;
  };
  // base group (tiers B/C)
  short* wpk  = (short*)alloc((size_t)RR * 65536 * 2);   // 26.2 MB
  short* spk  = (short*)alloc(65536 * 2);
  int*   gsrc = (int*)alloc((size_t)EE * 4);
  int*   gdst = (int*)alloc((size_t)EE * 4);
  float* ginv = (float*)alloc((size_t)EE * 4);
  int*   deg  = (int*)alloc((size_t)NN * 4);
  int*   hist = (int*)alloc(RR * 4);
  int*   cur  = (int*)alloc(RR * 4);
  int4*  tdesc = (int4*)alloc((size_t)MAXTILES * 16);
  int*   bsum = (int*)alloc(NSCAN * 4);
  // tier B adds bf16 feat
  unsigned short* featb = (unsigned short*)alloc((size_t)NN * 256 * 2);  // 51.2 MB
  size_t need_b = (size_t)(w - base);
  // tier A adds dst-CSR + msg buffer
  int* row_ptr = (int*)alloc((size_t)(NN + 1) * 4);
  int* cur2    = (int*)alloc((size_t)NN * 4);
  int* gout    = (int*)alloc((size_t)EE * 4);
  unsigned short* msg = (unsigned short*)alloc((size_t)EE * 256 * 2);    // 204.8 MB
  size_t need_a = (size_t)(w - base);
  // tier A+ adds bf16 self buffer
  unsigned short* sbuf = (unsigned short*)alloc((size_t)NN * 256 * 2);   // 51.2 MB
  size_t need_ap = (size_t)(w - base);

  bool tierAP = ws_size >= need_ap;
  bool tierA  = ws_size >= need_a;
  bool tierB  = ws_size >= need_b;

  hipMemsetAsync(hist, 0, RR * 4, stream);
  hipMemsetAsync(deg, 0, (size_t)NN * 4, stream);

  if (tierA || tierAP) {
    k_prep1<true><<<1344, 256, 0, stream>>>(basis, coef, slw, etype, dst, in_feat,
                                            wpk, spk, hist, deg, featb);
    k_prep2<<<NSCAN + 1, 256, 0, stream>>>(hist, deg, cur, tdesc, bsum);
    k_prep3<<<NSCAN, 256, 0, stream>>>(deg, bsum, row_ptr, cur2);
    k_prep4<true><<<(EE + SCHUNK - 1) / SCHUNK, 256, 0, stream>>>(
        etype, src, dst, deg, cur, gsrc, gdst, ginv, cur2, gout);
    if (tierAP) {
      k_main<true><<<EGRID2 + SGRID, 256, 0, stream>>>(featb, wpk, spk, gsrc, ginv,
                                                       gout, tdesc, msg, out, sbuf);
      k_aggregate<true><<<(NN + 7) / 8, 256, 0, stream>>>(msg, row_ptr, sbuf, out);
    } else {
      k_main<false><<<EGRID2 + SGRID, 256, 0, stream>>>(featb, wpk, spk, gsrc, ginv,
                                                        gout, tdesc, msg, out, nullptr);
      k_aggregate<false><<<(NN + 7) / 8, 256, 0, stream>>>(msg, row_ptr, nullptr, out);
    }
  } else if (tierB) {
    k_prep1<true><<<1344, 256, 0, stream>>>(basis, coef, slw, etype, dst, in_feat,
                                            wpk, spk, hist, deg, featb);
    k_prep2<<<NSCAN + 1, 256, 0, stream>>>(hist, deg, cur, tdesc, bsum);
    k_prep4<false><<<(EE + SCHUNK - 1) / SCHUNK, 256, 0, stream>>>(
        etype, src, dst, deg, cur, gsrc, gdst, ginv, nullptr, nullptr);
    k_self_gemm<true><<<(NN + 63) / 64, 256, 0, stream>>>(in_feat, featb, spk, out);
    k_edge_gemmBC<1><<<MAXTILES, 256, 0, stream>>>(in_feat, featb, wpk, gsrc, gdst,
                                                   ginv, tdesc, out);
  } else {
    k_prep1<false><<<1344, 256, 0, stream>>>(basis, coef, slw, etype, dst, in_feat,
                                             wpk, spk, hist, deg, nullptr);
    k_prep2<<<NSCAN + 1, 256, 0, stream>>>(hist, deg, cur, tdesc, bsum);
    k_prep4<false><<<(EE + SCHUNK - 1) / SCHUNK, 256, 0, stream>>>(
        etype, src, dst, deg, cur, gsrc, gdst, ginv, nullptr, nullptr);
    k_self_gemm<false><<<(NN + 63) / 64, 256, 0, stream>>>(in_feat, nullptr, spk, out);
    k_edge_gemmBC<0><<<MAXTILES, 256, 0, stream>>>(in_feat, nullptr, wpk, gsrc, gdst,
                                                   ginv, tdesc, out);
  }
}

// Round 14
// 301.288 us; speedup vs baseline: 1.4293x; 1.0926x over previous
//
#include <hip/hip_runtime.h>
#include <hip/hip_bf16.h>
#include <hip/hip_fp8.h>

// RGCN forward, MI355X. N=100000, E=400000, IN=OUT=256, R=200, B=32.
// Tier A+: prep1{wgen|slwpk|hist+feat} -> prep2{etype-scan|deg-blocksums} ->
// prep3{deg-scan} -> prep4{scatter: gsrc/ginv/gout} ->
// k_main{edge GEMM (bf16 MFMA) -> FP8 msg rows (dst-sorted) + col-split selfA
// GEMM -> bf16 sbuf} -> aggregate{out[n] = sbuf[n] + sum fp8 msg rows}.
// msg is storage-fp8 only (values pre-scaled by 1/deg, |v|~0.1 -> e4m3 rel
// err ~3% -> well under the 8.9e-2 absmax threshold). Tiers A/B/C fallbacks.

#define NN 100000
#define EE 400000
#define RR 200
#define BB 32
#define MAXTILES 6464   // >= E/64 + R ; divisible by 8
#define EQ2 (MAXTILES * 2 / 8)   // 1616 ords per XCD
#define EGRID2 (MAXTILES * 2)    // 12928 edge blocks
#define SGRID (((NN + 63) / 64) * 2)  // 3126 selfA blocks
#define SCHUNK 2048
#define NSCAN ((NN + 255) / 256) // 391

typedef __attribute__((ext_vector_type(8))) short short8v;   // 8 x bf16 (16B)
typedef __attribute__((ext_vector_type(4))) float f32x4;

__device__ __forceinline__ unsigned short f2bf(float f) {
  unsigned u = __float_as_uint(f);
  u += 0x7FFF + ((u >> 16) & 1);          // RNE
  return (unsigned short)(u >> 16);
}
__device__ __forceinline__ float bf2f(unsigned short h) {
  return __uint_as_float(((unsigned)h) << 16);
}
__device__ __forceinline__ unsigned char f2e4m3(float f) {
  __hip_fp8_e4m3 q(f);
  return (unsigned char)q.__x;
}
__device__ __forceinline__ float e4m32f(unsigned char b) {
  __hip_fp8_e4m3 q;
  q.__x = (__hip_fp8_storage_t)b;
  return (float)q;
}

// ---------------------------------------------------------------------------
// prep1: blocks [0,800): wgen (L2-blocked W_r pack); [800,832): slwpk;
// [832,1344): etype hist + dst degree + (FEAT) f32->bf16 feature convert.
// W_pk layout per relation: [ct=16][kt=8][lane=64][j=8] bf16 where
//   value = W_r[k = kt*32 + (lane>>4)*8 + j][n = ct*16 + (lane&15)].
template <bool FEAT>
__global__ __launch_bounds__(256) void k_prep1(
    const float* __restrict__ basis, const float* __restrict__ coef,
    const float* __restrict__ slw, const int* __restrict__ etype,
    const int* __restrict__ dst, const float* __restrict__ in_feat,
    short* __restrict__ wpk, short* __restrict__ spk,
    int* __restrict__ hist, int* __restrict__ deg,
    unsigned short* __restrict__ featb) {
  __shared__ int lh[RR];
  int b = blockIdx.x, tid = threadIdx.x;
  if (b < 800) {                       // ---- wgen ----
    int ord = (b & 7) * 100 + (b >> 3);
    int rg = ord % 25;
    int pk8 = (ord / 25) * 256 + tid;
    int lane = pk8 & 63;
    int kt = (pk8 >> 6) & 7;
    int ct = pk8 >> 9;
    int n  = ct * 16 + (lane & 15);
    int k0 = kt * 32 + ((lane >> 4) << 3);
    float acc[8][8];
#pragma unroll
    for (int r = 0; r < 8; ++r)
#pragma unroll
      for (int j = 0; j < 8; ++j) acc[r][j] = 0.f;
    for (int bb = 0; bb < BB; ++bb) {
      float bas[8];
#pragma unroll
      for (int j = 0; j < 8; ++j) bas[j] = basis[bb * 65536 + (k0 + j) * 256 + n];
#pragma unroll
      for (int r = 0; r < 8; ++r) {
        float c = coef[(rg * 8 + r) * BB + bb];
#pragma unroll
        for (int j = 0; j < 8; ++j) acc[r][j] += c * bas[j];
      }
    }
#pragma unroll
    for (int r = 0; r < 8; ++r) {
      short8v v;
#pragma unroll
      for (int j = 0; j < 8; ++j) v[j] = (short)f2bf(acc[r][j]);
      *(short8v*)(wpk + (size_t)(rg * 8 + r) * 65536 + (size_t)pk8 * 8) = v;
    }
    return;
  }
  if (b < 832) {                       // ---- slwpk ----
    int t = (b - 800) * 256 + tid;
    int lane = t & 63;
    int kt = (t >> 6) & 7;
    int ct = t >> 9;
    int n  = ct * 16 + (lane & 15);
    int k0 = kt * 32 + ((lane >> 4) << 3);
    short8v v;
#pragma unroll
    for (int j = 0; j < 8; ++j) v[j] = (short)f2bf(slw[(k0 + j) * 256 + n]);
    *(short8v*)(spk + (size_t)t * 8) = v;
    return;
  }
  // ---- hist + deg + feat ----
  int hb = b - 832;                    // 512 blocks
  for (int i = tid; i < RR; i += 256) lh[i] = 0;
  __syncthreads();
  for (int e = hb * 256 + tid; e < EE; e += 512 * 256) {
    atomicAdd(&lh[etype[e]], 1);
    atomicAdd(&deg[dst[e]], 1);
  }
  if (FEAT) {
    const int total = NN * 64;         // float4 count
    for (int i = hb * 256 + tid; i < total; i += 512 * 256) {
      float4 v = ((const float4*)in_feat)[i];
      ushort4 h;
      h.x = f2bf(v.x); h.y = f2bf(v.y); h.z = f2bf(v.z); h.w = f2bf(v.w);
      ((ushort4*)featb)[i] = h;
    }
  }
  __syncthreads();
  for (int i = tid; i < RR; i += 256)
    if (lh[i]) atomicAdd(&hist[i], lh[i]);
}

// ---------------------------------------------------------------------------
// prep2: block 0: etype-bin scan -> cur + tdesc; blocks 1..391: deg block sums.
__global__ __launch_bounds__(256) void k_prep2(const int* __restrict__ hist,
                                               const int* __restrict__ deg,
                                               int* __restrict__ cur,
                                               int4* __restrict__ tdesc,
                                               int* __restrict__ bsum) {
  __shared__ int h[RR];
  __shared__ int off[RR];
  __shared__ int toff[RR];
  __shared__ int tot;
  __shared__ int ws4[4];
  int b = blockIdx.x, tid = threadIdx.x;
  if (b == 0) {
    for (int i = tid; i < RR; i += 256) h[i] = hist[i];
    __syncthreads();
    if (tid == 0) {
      int s = 0, ts = 0;
      for (int r = 0; r < RR; ++r) {
        off[r] = s; s += h[r];
        toff[r] = ts; ts += (h[r] + 63) >> 6;
      }
      tot = ts;
    }
    __syncthreads();
    if (tid < RR) {
      int r = tid, cnt = h[r], base = off[r], to = toff[r];
      cur[r] = base;
      int nt = (cnt + 63) >> 6;
      for (int t2 = 0; t2 < nt; ++t2)
        tdesc[to + t2] = make_int4(r, base + t2 * 64, min(64, cnt - t2 * 64), 0);
    }
    for (int i = tot + tid; i < MAXTILES; i += 256)
      tdesc[i] = make_int4(0, 0, 0, 0);
    return;
  }
  int i = (b - 1) * 256 + tid;
  int v = (i < NN) ? deg[i] : 0;
#pragma unroll
  for (int d = 32; d; d >>= 1) v += __shfl_down(v, d, 64);
  if ((tid & 63) == 0) ws4[tid >> 6] = v;
  __syncthreads();
  if (tid == 0) bsum[b - 1] = ws4[0] + ws4[1] + ws4[2] + ws4[3];
}

// prep3 (tier A): deg exclusive scan -> row_ptr/cur2; bsum prefix inline.
__global__ __launch_bounds__(256) void k_prep3(const int* __restrict__ deg,
                                               const int* __restrict__ bsum,
                                               int* __restrict__ row_ptr,
                                               int* __restrict__ cur2) {
  __shared__ int ws4[4];
  __shared__ int wo4[4];
  __shared__ int psum[4];
  int tid = threadIdx.x, b = blockIdx.x;
  int sp = 0;
  for (int i = tid; i < b; i += 256) sp += bsum[i];
#pragma unroll
  for (int d = 32; d; d >>= 1) sp += __shfl_down(sp, d, 64);
  if ((tid & 63) == 0) psum[tid >> 6] = sp;
  int i = b * 256 + tid;
  int v = (i < NN) ? deg[i] : 0;
  int x = v;
#pragma unroll
  for (int d = 1; d < 64; d <<= 1) {
    int y = __shfl_up(x, d, 64);
    if ((tid & 63) >= d) x += y;
  }
  if ((tid & 63) == 63) ws4[tid >> 6] = x;
  __syncthreads();
  if (tid == 0) {
    int s = 0;
    for (int w2 = 0; w2 < 4; ++w2) { wo4[w2] = s; s += ws4[w2]; }
    psum[0] = psum[0] + psum[1] + psum[2] + psum[3];
  }
  __syncthreads();
  int excl = x - v + wo4[tid >> 6] + psum[0];
  if (i < NN) { row_ptr[i] = excl; cur2[i] = excl; }
  if (i == 0 && b == 0) row_ptr[NN] = EE;
}

// prep4: counting-sort scatter; materializes per-position gsrc/ginv and
// (DL) gout[s] = dst-sorted msg slot. gdst only written for tiers B/C (!DL).
template <bool DL>
__global__ __launch_bounds__(256) void k_prep4(const int* __restrict__ etype,
                                               const int* __restrict__ src,
                                               const int* __restrict__ dst,
                                               const int* __restrict__ deg,
                                               int* __restrict__ cur,
                                               int* __restrict__ gsrc,
                                               int* __restrict__ gdst,
                                               float* __restrict__ ginv,
                                               int* __restrict__ cur2,
                                               int* __restrict__ gout) {
  __shared__ int lh[RR];
  __shared__ int lbase[RR];
  __shared__ int lcur[RR];
  int tid = threadIdx.x;
  int e0 = blockIdx.x * SCHUNK;
  for (int i = tid; i < RR; i += 256) lh[i] = 0;
  __syncthreads();
  for (int i = tid; i < SCHUNK; i += 256) {
    int e = e0 + i;
    if (e < EE) atomicAdd(&lh[etype[e]], 1);
  }
  __syncthreads();
  for (int i = tid; i < RR; i += 256) {
    int c = lh[i];
    lbase[i] = c ? atomicAdd(&cur[i], c) : 0;
    lcur[i] = 0;
  }
  __syncthreads();
  for (int i = tid; i < SCHUNK; i += 256) {
    int e = e0 + i;
    if (e < EE) {
      int et = etype[e];
      int s = lbase[et] + atomicAdd(&lcur[et], 1);
      int d = dst[e];
      gsrc[s] = src[e];
      ginv[s] = 1.0f / (float)max(deg[d], 1);
      if (DL) {
        int pos = atomicAdd(&cur2[d], 1);
        gout[s] = pos;
      } else {
        gdst[s] = d;
      }
    }
  }
}

// ---------------------------------------------------------------------------
// Tier A/A+ main kernel. Blocks [0, EGRID2) = edge GEMM (r11 structure);
// blocks [EGRID2, EGRID2+SGRID) = col-split self-loop GEMM.
// Edge msg rows stored as FP8 e4m3 at dst-sorted slots (storage only; MFMA
// stays bf16). SB=true: selfA -> bf16 sbuf; SB=false: selfA -> f32 out.
template <bool SB>
__global__ __launch_bounds__(256) void k_main(
    const unsigned short* __restrict__ featb, const short* __restrict__ wpk,
    const short* __restrict__ spk, const int* __restrict__ gsrc,
    const float* __restrict__ ginv, const int* __restrict__ gout,
    const int4* __restrict__ tdesc, unsigned char* __restrict__ msg,
    float* __restrict__ out, unsigned short* __restrict__ sbuf) {
  __shared__ __align__(16) char lA[32768];
  __shared__ int lsrc[64];
  __shared__ float linv[64];
  __shared__ int lout[64];
  int tid = threadIdx.x, wave = tid >> 6, lane = tid & 63;
  int l15 = lane & 15, lg = lane >> 4;
  int bid = blockIdx.x;

  if (bid < EGRID2) {
    // ---------------- edge path ----------------
    int ord = (bid & 7) * EQ2 + (bid >> 3);
    int tile = ord >> 1, half = ord & 1;
    int4 d = tdesc[tile];
    int rows = d.z;
    if (rows <= 0) return;
    int r = d.x, rs = d.y;
    if (tid < 64) {
      int s = min(rs + tid, EE - 1);
      lsrc[tid] = gsrc[s];
      linv[tid] = ginv[s];
      lout[tid] = gout[s];
    }
    __syncthreads();
    short8v sv[8];
#pragma unroll
    for (int u = 0; u < 8; ++u) {
      int idx = u * 256 + tid;
      int row = idx >> 5, q = idx & 31;
      sv[u] = *(const short8v*)(featb + (size_t)lsrc[row] * 256 + q * 8);
    }
#pragma unroll
    for (int u = 0; u < 8; ++u) {
      int idx = u * 256 + tid;
      int row = idx >> 5, q = idx & 31;
      *(short8v*)(lA + ((row * 512 + q * 16) ^ ((row & 7) << 4))) = sv[u];
    }
    __syncthreads();
    f32x4 acc[4][2];
#pragma unroll
    for (int m = 0; m < 4; ++m)
#pragma unroll
      for (int c = 0; c < 2; ++c) acc[m][c] = (f32x4){0.f, 0.f, 0.f, 0.f};
    const short* bp = wpk + (size_t)r * 65536 +
                      (size_t)(half * 8 + wave * 2) * 4096 + (size_t)lane * 8;
    short8v b0 = *(const short8v*)(bp);
    short8v b1 = *(const short8v*)(bp + 4096);
#pragma unroll
    for (int kt = 0; kt < 8; ++kt) {
      short8v bn0, bn1;
      if (kt < 7) {
        bn0 = *(const short8v*)(bp + (kt + 1) * 512);
        bn1 = *(const short8v*)(bp + 4096 + (kt + 1) * 512);
      }
      short8v a[4];
#pragma unroll
      for (int m = 0; m < 4; ++m) {
        int row = m * 16 + l15;
        a[m] = *(const short8v*)(lA + ((row * 512 + kt * 64 + lg * 16) ^ ((row & 7) << 4)));
      }
#pragma unroll
      for (int m = 0; m < 4; ++m) {
        acc[m][0] = __builtin_amdgcn_mfma_f32_16x16x32_bf16(a[m], b0, acc[m][0], 0, 0, 0);
        acc[m][1] = __builtin_amdgcn_mfma_f32_16x16x32_bf16(a[m], b1, acc[m][1], 0, 0, 0);
      }
      if (kt < 7) { b0 = bn0; b1 = bn1; }
    }
    __syncthreads();                          // done reading lA
#pragma unroll
    for (int m = 0; m < 4; ++m)
#pragma unroll
      for (int j = 0; j < 4; ++j) {
        int row = m * 16 + lg * 4 + j;
        float inv = linv[row];
        int rb = row * 512, sw = (row & 7) << 4;
#pragma unroll
        for (int c = 0; c < 2; ++c) {
          int col = wave * 32 + c * 16 + l15;
          *(unsigned short*)(lA + ((rb + col * 2) ^ sw)) = f2bf(acc[m][c][j] * inv);
        }
      }
    __syncthreads();
#pragma unroll
    for (int u = 0; u < 4; ++u) {
      int idx = u * 256 + tid;
      int row = idx >> 4, q = idx & 15;       // 64 rows x 16 chunks (8 cols)
      if (row < rows) {
        short8v vv = *(const short8v*)(lA + ((row * 512 + q * 16) ^ ((row & 7) << 4)));
        unsigned long long pk = 0;
#pragma unroll
        for (int k = 0; k < 8; ++k)
          pk |= (unsigned long long)f2e4m3(bf2f((unsigned short)vv[k])) << (k * 8);
        *(unsigned long long*)(msg + (size_t)lout[row] * 256 + half * 128 + q * 8) = pk;
      }
    }
    return;
  }

  // ---------------- selfA path (col-split, acc[4][2]) ----------------
  int b2 = bid - EGRID2;
  int n0 = (b2 >> 1) * 64, half = b2 & 1;
  int rows = min(64, NN - n0);
  short8v sv[8];
#pragma unroll
  for (int u = 0; u < 8; ++u) {
    int idx = u * 256 + tid;
    int row = idx >> 5, q = idx & 31;
    int n = min(n0 + row, NN - 1);
    sv[u] = *(const short8v*)(featb + (size_t)n * 256 + q * 8);
  }
#pragma unroll
  for (int u = 0; u < 8; ++u) {
    int idx = u * 256 + tid;
    int row = idx >> 5, q = idx & 31;
    *(short8v*)(lA + ((row * 512 + q * 16) ^ ((row & 7) << 4))) = sv[u];
  }
  __syncthreads();
  f32x4 acc[4][2];
#pragma unroll
  for (int m = 0; m < 4; ++m)
#pragma unroll
    for (int c = 0; c < 2; ++c) acc[m][c] = (f32x4){0.f, 0.f, 0.f, 0.f};
  const short* bp = spk + (size_t)(half * 8 + wave * 2) * 4096 + (size_t)lane * 8;
  short8v b0 = *(const short8v*)(bp);
  short8v b1 = *(const short8v*)(bp + 4096);
#pragma unroll
  for (int kt = 0; kt < 8; ++kt) {
    short8v bn0, bn1;
    if (kt < 7) {
      bn0 = *(const short8v*)(bp + (kt + 1) * 512);
      bn1 = *(const short8v*)(bp + 4096 + (kt + 1) * 512);
    }
    short8v a[4];
#pragma unroll
    for (int m = 0; m < 4; ++m) {
      int row = m * 16 + l15;
      a[m] = *(const short8v*)(lA + ((row * 512 + kt * 64 + lg * 16) ^ ((row & 7) << 4)));
    }
#pragma unroll
    for (int m = 0; m < 4; ++m) {
      acc[m][0] = __builtin_amdgcn_mfma_f32_16x16x32_bf16(a[m], b0, acc[m][0], 0, 0, 0);
      acc[m][1] = __builtin_amdgcn_mfma_f32_16x16x32_bf16(a[m], b1, acc[m][1], 0, 0, 0);
    }
    if (kt < 7) { b0 = bn0; b1 = bn1; }
  }
  if (SB) {
    __syncthreads();                          // done reading lA
#pragma unroll
    for (int m = 0; m < 4; ++m)
#pragma unroll
      for (int j = 0; j < 4; ++j) {
        int row = m * 16 + lg * 4 + j;
        int rb = row * 512, sw = (row & 7) << 4;
#pragma unroll
        for (int c = 0; c < 2; ++c) {
          int col = wave * 32 + c * 16 + l15;
          *(unsigned short*)(lA + ((rb + col * 2) ^ sw)) = f2bf(acc[m][c][j]);
        }
      }
    __syncthreads();
#pragma unroll
    for (int u = 0; u < 4; ++u) {
      int idx = u * 256 + tid;
      int row = idx >> 4, q = idx & 15;
      if (row < rows) {
        short8v vv = *(const short8v*)(lA + ((row * 512 + q * 16) ^ ((row & 7) << 4)));
        *(short8v*)(sbuf + (size_t)(n0 + row) * 256 + half * 128 + q * 8) = vv;
      }
    }
  } else {
#pragma unroll
    for (int m = 0; m < 4; ++m)
#pragma unroll
      for (int j = 0; j < 4; ++j) {
        int n = n0 + m * 16 + lg * 4 + j;
        if (n < NN) {
          float* op = out + (size_t)n * 256 + half * 128 + wave * 32 + l15;
          op[0]  = acc[m][0][j];
          op[16] = acc[m][1][j];
        }
      }
  }
}

// ---------------------------------------------------------------------------
// Aggregate. SB=true: out[n] = sbuf[n] + sum fp8 msg rows (single write).
// SB=false: RMW out. msg is dst-sorted -> contiguous rows; 2x unrolled MLP.
template <bool SB>
__global__ __launch_bounds__(256) void k_aggregate(
    const unsigned char* __restrict__ msg, const int* __restrict__ row_ptr,
    const unsigned short* __restrict__ sbuf, float* __restrict__ out) {
  int g = blockIdx.x * 8 + (threadIdx.x >> 5);
  if (g >= NN) return;
  int hl = threadIdx.x & 31;
  int lo = row_ptr[g], hi = row_ptr[g + 1];
  float a[8];
  if (SB) {
    short8v s0 = *(const short8v*)(sbuf + (size_t)g * 256 + hl * 8);
#pragma unroll
    for (int k = 0; k < 8; ++k) a[k] = bf2f((unsigned short)s0[k]);
  } else {
    if (lo >= hi) return;
#pragma unroll
    for (int k = 0; k < 8; ++k) a[k] = 0.f;
  }
  int p = lo;
  for (; p + 1 < hi; p += 2) {
    unsigned long long pk0 = *(const unsigned long long*)(msg + (size_t)p * 256 + hl * 8);
    unsigned long long pk1 = *(const unsigned long long*)(msg + (size_t)(p + 1) * 256 + hl * 8);
#pragma unroll
    for (int k = 0; k < 8; ++k) {
      a[k] += e4m32f((unsigned char)(pk0 >> (k * 8)));
      a[k] += e4m32f((unsigned char)(pk1 >> (k * 8)));
    }
  }
  if (p < hi) {
    unsigned long long pk0 = *(const unsigned long long*)(msg + (size_t)p * 256 + hl * 8);
#pragma unroll
    for (int k = 0; k < 8; ++k) a[k] += e4m32f((unsigned char)(pk0 >> (k * 8)));
  }
  float* op = out + (size_t)g * 256 + hl * 8;
  if (SB) {
#pragma unroll
    for (int c = 0; c < 2; ++c) {
      f32x4 o;
      o[0] = a[c * 4]; o[1] = a[c * 4 + 1]; o[2] = a[c * 4 + 2]; o[3] = a[c * 4 + 3];
      *(f32x4*)(op + c * 4) = o;
    }
  } else {
#pragma unroll
    for (int c = 0; c < 2; ++c) {
      f32x4 o = *(const f32x4*)(op + c * 4);
      o[0] += a[c * 4]; o[1] += a[c * 4 + 1]; o[2] += a[c * 4 + 2]; o[3] += a[c * 4 + 3];
      *(f32x4*)(op + c * 4) = o;
    }
  }
}

// ---------------------------------------------------------------------------
// Tier B/C fallbacks (atomic epilogue), using flat gsrc/gdst/ginv metadata.
__device__ __forceinline__ void gemm64(const char* lA, const short* __restrict__ wpk,
                                       f32x4 acc[4][4], int wave, int lane) {
  int l15 = lane & 15, lg = lane >> 4;
  const short* bp = wpk + (size_t)wave * 4 * 4096 + (size_t)lane * 8;
#pragma unroll
  for (int kt = 0; kt < 8; ++kt) {
    short8v a[4], b[4];
#pragma unroll
    for (int c = 0; c < 4; ++c) b[c] = *(const short8v*)(bp + c * 4096 + kt * 512);
#pragma unroll
    for (int m = 0; m < 4; ++m) {
      int row = m * 16 + l15;
      a[m] = *(const short8v*)(lA + ((row * 512 + kt * 64 + lg * 16) ^ ((row & 7) << 4)));
    }
#pragma unroll
    for (int m = 0; m < 4; ++m)
#pragma unroll
      for (int c = 0; c < 4; ++c)
        acc[m][c] = __builtin_amdgcn_mfma_f32_16x16x32_bf16(a[m], b[c], acc[m][c], 0, 0, 0);
  }
}

template <bool B16>
__global__ __launch_bounds__(256) void k_self_gemm(const float* __restrict__ in_feat,
                                                   const unsigned short* __restrict__ featb,
                                                   const short* __restrict__ spk,
                                                   float* __restrict__ out) {
  __shared__ __align__(16) char lA[32768];
  int n0 = blockIdx.x * 64;
  int tid = threadIdx.x;
  if (B16) {
    short8v sv[8];
#pragma unroll
    for (int u = 0; u < 8; ++u) {
      int idx = u * 256 + tid;
      int row = idx >> 5, q = idx & 31;
      int n = min(n0 + row, NN - 1);
      sv[u] = *(const short8v*)(featb + (size_t)n * 256 + q * 8);
    }
#pragma unroll
    for (int u = 0; u < 8; ++u) {
      int idx = u * 256 + tid;
      int row = idx >> 5, q = idx & 31;
      *(short8v*)(lA + ((row * 512 + q * 16) ^ ((row & 7) << 4))) = sv[u];
    }
  } else {
#pragma unroll
    for (int half = 0; half < 2; ++half) {
      float4 v[8];
#pragma unroll
      for (int u = 0; u < 8; ++u) {
        int it = half * 2048 + u * 256 + tid;
        int row = it >> 6, q = it & 63;
        int n = n0 + row;
        v[u] = (n < NN) ? ((const float4*)(in_feat + (size_t)n * 256))[q]
                        : make_float4(0.f, 0.f, 0.f, 0.f);
      }
#pragma unroll
      for (int u = 0; u < 8; ++u) {
        int it = half * 2048 + u * 256 + tid;
        int row = it >> 6, q = it & 63;
        ushort4 hh;
        hh.x = f2bf(v[u].x); hh.y = f2bf(v[u].y); hh.z = f2bf(v[u].z); hh.w = f2bf(v[u].w);
        *(ushort4*)(lA + ((row * 512 + q * 8) ^ ((row & 7) << 4))) = hh;
      }
    }
  }
  __syncthreads();
  f32x4 acc[4][4];
#pragma unroll
  for (int m = 0; m < 4; ++m)
#pragma unroll
    for (int c = 0; c < 4; ++c) acc[m][c] = (f32x4){0.f, 0.f, 0.f, 0.f};
  int wave = tid >> 6, lane = tid & 63;
  gemm64(lA, spk, acc, wave, lane);
  int l15 = lane & 15, lg = lane >> 4;
#pragma unroll
  for (int m = 0; m < 4; ++m)
#pragma unroll
    for (int j = 0; j < 4; ++j) {
      int n = n0 + m * 16 + lg * 4 + j;
      if (n < NN) {
        float* op = out + (size_t)n * 256 + wave * 64 + l15;
#pragma unroll
        for (int c = 0; c < 4; ++c) op[c * 16] = acc[m][c][j];
      }
    }
}

template <int MODE>   // 0: f32 feat, 1: bf16 feat; atomic mean-scatter into out
__global__ __launch_bounds__(256) void k_edge_gemmBC(const float* __restrict__ in_feat,
                                                     const unsigned short* __restrict__ featb,
                                                     const short* __restrict__ wpk,
                                                     const int* __restrict__ gsrc,
                                                     const int* __restrict__ gdst,
                                                     const float* __restrict__ ginv,
                                                     const int4* __restrict__ tdesc,
                                                     float* __restrict__ out) {
  __shared__ __align__(16) char lA[32768];
  __shared__ int lsrc[64];
  __shared__ int ldst[64];
  __shared__ float linv[64];
  int bid = blockIdx.x;
  int tile = (bid & 7) * (MAXTILES / 8) + (bid >> 3);
  int4 d = tdesc[tile];
  int rows = d.z;
  if (rows <= 0) return;
  int r = d.x, rs = d.y;
  int tid = threadIdx.x;
  if (tid < 64) {
    if (tid < rows) {
      lsrc[tid] = gsrc[rs + tid];
      ldst[tid] = gdst[rs + tid];
      linv[tid] = ginv[rs + tid];
    } else {
      lsrc[tid] = -1; ldst[tid] = -1; linv[tid] = 0.f;
    }
  }
  __syncthreads();
  if (MODE == 1) {
    short8v sv[8];
#pragma unroll
    for (int u = 0; u < 8; ++u) {
      int idx = u * 256 + tid;
      int row = idx >> 5, q = idx & 31;
      int s = lsrc[row];
      sv[u] = (s >= 0) ? *(const short8v*)(featb + (size_t)s * 256 + q * 8)
                       : (short8v){0, 0, 0, 0, 0, 0, 0, 0};
    }
#pragma unroll
    for (int u = 0; u < 8; ++u) {
      int idx = u * 256 + tid;
      int row = idx >> 5, q = idx & 31;
      *(short8v*)(lA + ((row * 512 + q * 16) ^ ((row & 7) << 4))) = sv[u];
    }
  } else {
#pragma unroll
    for (int half = 0; half < 2; ++half) {
      float4 v[8];
#pragma unroll
      for (int u = 0; u < 8; ++u) {
        int it = half * 2048 + u * 256 + tid;
        int row = it >> 6, q = it & 63;
        int s = lsrc[row];
        v[u] = (s >= 0) ? ((const float4*)(in_feat + (size_t)s * 256))[q]
                        : make_float4(0.f, 0.f, 0.f, 0.f);
      }
#pragma unroll
      for (int u = 0; u < 8; ++u) {
        int it = half * 2048 + u * 256 + tid;
        int row = it >> 6, q = it & 63;
        ushort4 hh;
        hh.x = f2bf(v[u].x); hh.y = f2bf(v[u].y); hh.z = f2bf(v[u].z); hh.w = f2bf(v[u].w);
        *(ushort4*)(lA + ((row * 512 + q * 8) ^ ((row & 7) << 4))) = hh;
      }
    }
  }
  __syncthreads();
  f32x4 acc[4][4];
#pragma unroll
  for (int m = 0; m < 4; ++m)
#pragma unroll
    for (int c = 0; c < 4; ++c) acc[m][c] = (f32x4){0.f, 0.f, 0.f, 0.f};
  int wave = tid >> 6, lane = tid & 63;
  gemm64(lA, wpk + (size_t)r * 65536, acc, wave, lane);
  int l15 = lane & 15, lg = lane >> 4;
#pragma unroll
  for (int m = 0; m < 4; ++m)
#pragma unroll
    for (int j = 0; j < 4; ++j) {
      int row = m * 16 + lg * 4 + j;
      int dd = ldst[row];
      if (dd >= 0) {
        float inv = linv[row];
        float* op = out + (size_t)dd * 256 + wave * 64 + l15;
#pragma unroll
        for (int c = 0; c < 4; ++c) unsafeAtomicAdd(op + c * 16, acc[m][c][j] * inv);
      }
    }
}

// ---------------------------------------------------------------------------
extern "C" void kernel_launch(void* const* d_in, const int* in_sizes, int n_in,
                              void* d_out, int out_size, void* d_ws, size_t ws_size,
                              hipStream_t stream) {
  const float* in_feat = (const float*)d_in[0];
  const float* basis   = (const float*)d_in[1];
  const float* coef    = (const float*)d_in[2];
  const float* slw     = (const float*)d_in[3];
  const int*   src     = (const int*)d_in[4];
  const int*   dst     = (const int*)d_in[5];
  const int*   etype   = (const int*)d_in[6];
  float* out = (float*)d_out;

  char* base = (char*)d_ws;
  char* w = base;
  auto alloc = [&](size_t bytes) {
    char* p = w;
    w += (bytes + 255) & ~(size_t)255;
    return p;
  };
  // base group (tiers B/C)
  short* wpk  = (short*)alloc((size_t)RR * 65536 * 2);   // 26.2 MB
  short* spk  = (short*)alloc(65536 * 2);
  int*   gsrc = (int*)alloc((size_t)EE * 4);
  int*   gdst = (int*)alloc((size_t)EE * 4);
  float* ginv = (float*)alloc((size_t)EE * 4);
  int*   deg  = (int*)alloc((size_t)NN * 4);
  int*   hist = (int*)alloc(RR * 4);
  int*   cur  = (int*)alloc(RR * 4);
  int4*  tdesc = (int4*)alloc((size_t)MAXTILES * 16);
  int*   bsum = (int*)alloc(NSCAN * 4);
  // tier B adds bf16 feat
  unsigned short* featb = (unsigned short*)alloc((size_t)NN * 256 * 2);  // 51.2 MB
  size_t need_b = (size_t)(w - base);
  // tier A adds dst-CSR + fp8 msg buffer
  int* row_ptr = (int*)alloc((size_t)(NN + 1) * 4);
  int* cur2    = (int*)alloc((size_t)NN * 4);
  int* gout    = (int*)alloc((size_t)EE * 4);
  unsigned char* msg = (unsigned char*)alloc((size_t)EE * 256);          // 102.4 MB
  size_t need_a = (size_t)(w - base);
  // tier A+ adds bf16 self buffer
  unsigned short* sbuf = (unsigned short*)alloc((size_t)NN * 256 * 2);   // 51.2 MB
  size_t need_ap = (size_t)(w - base);

  bool tierAP = ws_size >= need_ap;
  bool tierA  = ws_size >= need_a;
  bool tierB  = ws_size >= need_b;

  hipMemsetAsync(hist, 0, RR * 4, stream);
  hipMemsetAsync(deg, 0, (size_t)NN * 4, stream);

  if (tierA || tierAP) {
    k_prep1<true><<<1344, 256, 0, stream>>>(basis, coef, slw, etype, dst, in_feat,
                                            wpk, spk, hist, deg, featb);
    k_prep2<<<NSCAN + 1, 256, 0, stream>>>(hist, deg, cur, tdesc, bsum);
    k_prep3<<<NSCAN, 256, 0, stream>>>(deg, bsum, row_ptr, cur2);
    k_prep4<true><<<(EE + SCHUNK - 1) / SCHUNK, 256, 0, stream>>>(
        etype, src, dst, deg, cur, gsrc, gdst, ginv, cur2, gout);
    if (tierAP) {
      k_main<true><<<EGRID2 + SGRID, 256, 0, stream>>>(featb, wpk, spk, gsrc, ginv,
                                                       gout, tdesc, msg, out, sbuf);
      k_aggregate<true><<<(NN + 7) / 8, 256, 0, stream>>>(msg, row_ptr, sbuf, out);
    } else {
      k_main<false><<<EGRID2 + SGRID, 256, 0, stream>>>(featb, wpk, spk, gsrc, ginv,
                                                        gout, tdesc, msg, out, nullptr);
      k_aggregate<false><<<(NN + 7) / 8, 256, 0, stream>>>(msg, row_ptr, nullptr, out);
    }
  } else if (tierB) {
    k_prep1<true><<<1344, 256, 0, stream>>>(basis, coef, slw, etype, dst, in_feat,
                                            wpk, spk, hist, deg, featb);
    k_prep2<<<NSCAN + 1, 256, 0, stream>>>(hist, deg, cur, tdesc, bsum);
    k_prep4<false><<<(EE + SCHUNK - 1) / SCHUNK, 256, 0, stream>>>(
        etype, src, dst, deg, cur, gsrc, gdst, ginv, nullptr, nullptr);
    k_self_gemm<true><<<(NN + 63) / 64, 256, 0, stream>>>(in_feat, featb, spk, out);
    k_edge_gemmBC<1><<<MAXTILES, 256, 0, stream>>>(in_feat, featb, wpk, gsrc, gdst,
                                                   ginv, tdesc, out);
  } else {
    k_prep1<false><<<1344, 256, 0, stream>>>(basis, coef, slw, etype, dst, in_feat,
                                             wpk, spk, hist, deg, nullptr);
    k_prep2<<<NSCAN + 1, 256, 0, stream>>>(hist, deg, cur, tdesc, bsum);
    k_prep4<false><<<(EE + SCHUNK - 1) / SCHUNK, 256, 0, stream>>>(
        etype, src, dst, deg, cur, gsrc, gdst, ginv, nullptr, nullptr);
    k_self_gemm<false><<<(NN + 63) / 64, 256, 0, stream>>>(in_feat, nullptr, spk, out);
    k_edge_gemmBC<0><<<MAXTILES, 256, 0, stream>>>(in_feat, nullptr, wpk, gsrc, gdst,
                                                   ginv, tdesc, out);
  }
}

// Round 15
// 298.330 us; speedup vs baseline: 1.4434x; 1.0099x over previous
//
#include <hip/hip_runtime.h>
#include <hip/hip_bf16.h>
#include <hip/hip_fp8.h>

// RGCN forward, MI355X. N=100000, E=400000, IN=OUT=256, R=200, B=32.
// Tier A+: prep1{wgen|slwpk|hist+feat} -> prep2{etype-scan|deg-blocksums} ->
// prep3{deg-scan} -> prep4{scatter: gsrc/ginv/gout} ->
// k_main{edge GEMM (bf16 MFMA) -> fp8 e4m3 msg rows (converted ONCE in the
// scale phase, byte-swizzled LDS, zero-conversion store phase) + col-split
// selfA GEMM -> bf16 sbuf} -> aggregate{out[n] = sbuf[n] + sum fp8 msg rows}.

#define NN 100000
#define EE 400000
#define RR 200
#define BB 32
#define MAXTILES 6464   // >= E/64 + R ; divisible by 8
#define EQ2 (MAXTILES * 2 / 8)   // 1616 ords per XCD
#define EGRID2 (MAXTILES * 2)    // 12928 edge blocks
#define SGRID (((NN + 63) / 64) * 2)  // 3126 selfA blocks
#define SCHUNK 2048
#define NSCAN ((NN + 255) / 256) // 391

typedef __attribute__((ext_vector_type(8))) short short8v;   // 8 x bf16 (16B)
typedef __attribute__((ext_vector_type(4))) float f32x4;

__device__ __forceinline__ unsigned short f2bf(float f) {
  unsigned u = __float_as_uint(f);
  u += 0x7FFF + ((u >> 16) & 1);          // RNE
  return (unsigned short)(u >> 16);
}
__device__ __forceinline__ float bf2f(unsigned short h) {
  return __uint_as_float(((unsigned)h) << 16);
}
__device__ __forceinline__ unsigned char f2e4m3(float f) {
  __hip_fp8_e4m3 q(f);
  return (unsigned char)q.__x;
}
__device__ __forceinline__ float e4m32f(unsigned char b) {
  __hip_fp8_e4m3 q;
  q.__x = (__hip_fp8_storage_t)b;
  return (float)q;
}

// ---------------------------------------------------------------------------
// prep1: blocks [0,800): wgen (L2-blocked W_r pack); [800,832): slwpk;
// [832,1344): etype hist + dst degree + (FEAT) f32->bf16 feature convert.
// W_pk layout per relation: [ct=16][kt=8][lane=64][j=8] bf16 where
//   value = W_r[k = kt*32 + (lane>>4)*8 + j][n = ct*16 + (lane&15)].
template <bool FEAT>
__global__ __launch_bounds__(256) void k_prep1(
    const float* __restrict__ basis, const float* __restrict__ coef,
    const float* __restrict__ slw, const int* __restrict__ etype,
    const int* __restrict__ dst, const float* __restrict__ in_feat,
    short* __restrict__ wpk, short* __restrict__ spk,
    int* __restrict__ hist, int* __restrict__ deg,
    unsigned short* __restrict__ featb) {
  __shared__ int lh[RR];
  int b = blockIdx.x, tid = threadIdx.x;
  if (b < 800) {                       // ---- wgen ----
    int ord = (b & 7) * 100 + (b >> 3);
    int rg = ord % 25;
    int pk8 = (ord / 25) * 256 + tid;
    int lane = pk8 & 63;
    int kt = (pk8 >> 6) & 7;
    int ct = pk8 >> 9;
    int n  = ct * 16 + (lane & 15);
    int k0 = kt * 32 + ((lane >> 4) << 3);
    float acc[8][8];
#pragma unroll
    for (int r = 0; r < 8; ++r)
#pragma unroll
      for (int j = 0; j < 8; ++j) acc[r][j] = 0.f;
    for (int bb = 0; bb < BB; ++bb) {
      float bas[8];
#pragma unroll
      for (int j = 0; j < 8; ++j) bas[j] = basis[bb * 65536 + (k0 + j) * 256 + n];
#pragma unroll
      for (int r = 0; r < 8; ++r) {
        float c = coef[(rg * 8 + r) * BB + bb];
#pragma unroll
        for (int j = 0; j < 8; ++j) acc[r][j] += c * bas[j];
      }
    }
#pragma unroll
    for (int r = 0; r < 8; ++r) {
      short8v v;
#pragma unroll
      for (int j = 0; j < 8; ++j) v[j] = (short)f2bf(acc[r][j]);
      *(short8v*)(wpk + (size_t)(rg * 8 + r) * 65536 + (size_t)pk8 * 8) = v;
    }
    return;
  }
  if (b < 832) {                       // ---- slwpk ----
    int t = (b - 800) * 256 + tid;
    int lane = t & 63;
    int kt = (t >> 6) & 7;
    int ct = t >> 9;
    int n  = ct * 16 + (lane & 15);
    int k0 = kt * 32 + ((lane >> 4) << 3);
    short8v v;
#pragma unroll
    for (int j = 0; j < 8; ++j) v[j] = (short)f2bf(slw[(k0 + j) * 256 + n]);
    *(short8v*)(spk + (size_t)t * 8) = v;
    return;
  }
  // ---- hist + deg + feat ----
  int hb = b - 832;                    // 512 blocks
  for (int i = tid; i < RR; i += 256) lh[i] = 0;
  __syncthreads();
  for (int e = hb * 256 + tid; e < EE; e += 512 * 256) {
    atomicAdd(&lh[etype[e]], 1);
    atomicAdd(&deg[dst[e]], 1);
  }
  if (FEAT) {
    const int total = NN * 64;         // float4 count
    for (int i = hb * 256 + tid; i < total; i += 512 * 256) {
      float4 v = ((const float4*)in_feat)[i];
      ushort4 h;
      h.x = f2bf(v.x); h.y = f2bf(v.y); h.z = f2bf(v.z); h.w = f2bf(v.w);
      ((ushort4*)featb)[i] = h;
    }
  }
  __syncthreads();
  for (int i = tid; i < RR; i += 256)
    if (lh[i]) atomicAdd(&hist[i], lh[i]);
}

// ---------------------------------------------------------------------------
// prep2: block 0: etype-bin scan -> cur + tdesc; blocks 1..391: deg block sums.
__global__ __launch_bounds__(256) void k_prep2(const int* __restrict__ hist,
                                               const int* __restrict__ deg,
                                               int* __restrict__ cur,
                                               int4* __restrict__ tdesc,
                                               int* __restrict__ bsum) {
  __shared__ int h[RR];
  __shared__ int off[RR];
  __shared__ int toff[RR];
  __shared__ int tot;
  __shared__ int ws4[4];
  int b = blockIdx.x, tid = threadIdx.x;
  if (b == 0) {
    for (int i = tid; i < RR; i += 256) h[i] = hist[i];
    __syncthreads();
    if (tid == 0) {
      int s = 0, ts = 0;
      for (int r = 0; r < RR; ++r) {
        off[r] = s; s += h[r];
        toff[r] = ts; ts += (h[r] + 63) >> 6;
      }
      tot = ts;
    }
    __syncthreads();
    if (tid < RR) {
      int r = tid, cnt = h[r], base = off[r], to = toff[r];
      cur[r] = base;
      int nt = (cnt + 63) >> 6;
      for (int t2 = 0; t2 < nt; ++t2)
        tdesc[to + t2] = make_int4(r, base + t2 * 64, min(64, cnt - t2 * 64), 0);
    }
    for (int i = tot + tid; i < MAXTILES; i += 256)
      tdesc[i] = make_int4(0, 0, 0, 0);
    return;
  }
  int i = (b - 1) * 256 + tid;
  int v = (i < NN) ? deg[i] : 0;
#pragma unroll
  for (int d = 32; d; d >>= 1) v += __shfl_down(v, d, 64);
  if ((tid & 63) == 0) ws4[tid >> 6] = v;
  __syncthreads();
  if (tid == 0) bsum[b - 1] = ws4[0] + ws4[1] + ws4[2] + ws4[3];
}

// prep3 (tier A): deg exclusive scan -> row_ptr/cur2; bsum prefix inline.
__global__ __launch_bounds__(256) void k_prep3(const int* __restrict__ deg,
                                               const int* __restrict__ bsum,
                                               int* __restrict__ row_ptr,
                                               int* __restrict__ cur2) {
  __shared__ int ws4[4];
  __shared__ int wo4[4];
  __shared__ int psum[4];
  int tid = threadIdx.x, b = blockIdx.x;
  int sp = 0;
  for (int i = tid; i < b; i += 256) sp += bsum[i];
#pragma unroll
  for (int d = 32; d; d >>= 1) sp += __shfl_down(sp, d, 64);
  if ((tid & 63) == 0) psum[tid >> 6] = sp;
  int i = b * 256 + tid;
  int v = (i < NN) ? deg[i] : 0;
  int x = v;
#pragma unroll
  for (int d = 1; d < 64; d <<= 1) {
    int y = __shfl_up(x, d, 64);
    if ((tid & 63) >= d) x += y;
  }
  if ((tid & 63) == 63) ws4[tid >> 6] = x;
  __syncthreads();
  if (tid == 0) {
    int s = 0;
    for (int w2 = 0; w2 < 4; ++w2) { wo4[w2] = s; s += ws4[w2]; }
    psum[0] = psum[0] + psum[1] + psum[2] + psum[3];
  }
  __syncthreads();
  int excl = x - v + wo4[tid >> 6] + psum[0];
  if (i < NN) { row_ptr[i] = excl; cur2[i] = excl; }
  if (i == 0 && b == 0) row_ptr[NN] = EE;
}

// prep4: counting-sort scatter; materializes per-position gsrc/ginv and
// (DL) gout[s] = dst-sorted msg slot. gdst only written for tiers B/C (!DL).
template <bool DL>
__global__ __launch_bounds__(256) void k_prep4(const int* __restrict__ etype,
                                               const int* __restrict__ src,
                                               const int* __restrict__ dst,
                                               const int* __restrict__ deg,
                                               int* __restrict__ cur,
                                               int* __restrict__ gsrc,
                                               int* __restrict__ gdst,
                                               float* __restrict__ ginv,
                                               int* __restrict__ cur2,
                                               int* __restrict__ gout) {
  __shared__ int lh[RR];
  __shared__ int lbase[RR];
  __shared__ int lcur[RR];
  int tid = threadIdx.x;
  int e0 = blockIdx.x * SCHUNK;
  for (int i = tid; i < RR; i += 256) lh[i] = 0;
  __syncthreads();
  for (int i = tid; i < SCHUNK; i += 256) {
    int e = e0 + i;
    if (e < EE) atomicAdd(&lh[etype[e]], 1);
  }
  __syncthreads();
  for (int i = tid; i < RR; i += 256) {
    int c = lh[i];
    lbase[i] = c ? atomicAdd(&cur[i], c) : 0;
    lcur[i] = 0;
  }
  __syncthreads();
  for (int i = tid; i < SCHUNK; i += 256) {
    int e = e0 + i;
    if (e < EE) {
      int et = etype[e];
      int s = lbase[et] + atomicAdd(&lcur[et], 1);
      int d = dst[e];
      gsrc[s] = src[e];
      ginv[s] = 1.0f / (float)max(deg[d], 1);
      if (DL) {
        int pos = atomicAdd(&cur2[d], 1);
        gout[s] = pos;
      } else {
        gdst[s] = d;
      }
    }
  }
}

// ---------------------------------------------------------------------------
// Tier A/A+ main kernel. Blocks [0, EGRID2) = edge GEMM (r11 structure);
// blocks [EGRID2, EGRID2+SGRID) = col-split self-loop GEMM.
// Edge epilogue: acc scaled + converted to fp8 ONCE, byte-swizzled into LDS
// (row*128 + (col ^ ((row&7)<<3)) — XOR operand multiple of 8 keeps 8B chunks
// contiguous); store phase is pure ds_read_b64 + global_store (no VALU).
template <bool SB>
__global__ __launch_bounds__(256) void k_main(
    const unsigned short* __restrict__ featb, const short* __restrict__ wpk,
    const short* __restrict__ spk, const int* __restrict__ gsrc,
    const float* __restrict__ ginv, const int* __restrict__ gout,
    const int4* __restrict__ tdesc, unsigned char* __restrict__ msg,
    float* __restrict__ out, unsigned short* __restrict__ sbuf) {
  __shared__ __align__(16) char lA[32768];
  __shared__ int lsrc[64];
  __shared__ float linv[64];
  __shared__ int lout[64];
  int tid = threadIdx.x, wave = tid >> 6, lane = tid & 63;
  int l15 = lane & 15, lg = lane >> 4;
  int bid = blockIdx.x;

  if (bid < EGRID2) {
    // ---------------- edge path ----------------
    int ord = (bid & 7) * EQ2 + (bid >> 3);
    int tile = ord >> 1, half = ord & 1;
    int4 d = tdesc[tile];
    int rows = d.z;
    if (rows <= 0) return;
    int r = d.x, rs = d.y;
    if (tid < 64) {
      int s = min(rs + tid, EE - 1);
      lsrc[tid] = gsrc[s];
      linv[tid] = ginv[s];
      lout[tid] = gout[s];
    }
    __syncthreads();
    short8v sv[8];
#pragma unroll
    for (int u = 0; u < 8; ++u) {
      int idx = u * 256 + tid;
      int row = idx >> 5, q = idx & 31;
      sv[u] = *(const short8v*)(featb + (size_t)lsrc[row] * 256 + q * 8);
    }
#pragma unroll
    for (int u = 0; u < 8; ++u) {
      int idx = u * 256 + tid;
      int row = idx >> 5, q = idx & 31;
      *(short8v*)(lA + ((row * 512 + q * 16) ^ ((row & 7) << 4))) = sv[u];
    }
    __syncthreads();
    f32x4 acc[4][2];
#pragma unroll
    for (int m = 0; m < 4; ++m)
#pragma unroll
      for (int c = 0; c < 2; ++c) acc[m][c] = (f32x4){0.f, 0.f, 0.f, 0.f};
    const short* bp = wpk + (size_t)r * 65536 +
                      (size_t)(half * 8 + wave * 2) * 4096 + (size_t)lane * 8;
    short8v b0 = *(const short8v*)(bp);
    short8v b1 = *(const short8v*)(bp + 4096);
#pragma unroll
    for (int kt = 0; kt < 8; ++kt) {
      short8v bn0, bn1;
      if (kt < 7) {
        bn0 = *(const short8v*)(bp + (kt + 1) * 512);
        bn1 = *(const short8v*)(bp + 4096 + (kt + 1) * 512);
      }
      short8v a[4];
#pragma unroll
      for (int m = 0; m < 4; ++m) {
        int row = m * 16 + l15;
        a[m] = *(const short8v*)(lA + ((row * 512 + kt * 64 + lg * 16) ^ ((row & 7) << 4)));
      }
#pragma unroll
      for (int m = 0; m < 4; ++m) {
        acc[m][0] = __builtin_amdgcn_mfma_f32_16x16x32_bf16(a[m], b0, acc[m][0], 0, 0, 0);
        acc[m][1] = __builtin_amdgcn_mfma_f32_16x16x32_bf16(a[m], b1, acc[m][1], 0, 0, 0);
      }
      if (kt < 7) { b0 = bn0; b1 = bn1; }
    }
    __syncthreads();                          // done reading lA (bf16 A tile)
    // scale + convert to fp8 directly into LDS (64 rows x 128 B)
#pragma unroll
    for (int m = 0; m < 4; ++m)
#pragma unroll
      for (int j = 0; j < 4; ++j) {
        int row = m * 16 + lg * 4 + j;
        float inv = linv[row];
        int rb = row * 128, sw = (row & 7) << 3;
#pragma unroll
        for (int c = 0; c < 2; ++c) {
          int col = wave * 32 + c * 16 + l15;
          lA[rb + (col ^ sw)] = (char)f2e4m3(acc[m][c][j] * inv);
        }
      }
    __syncthreads();
    // store: pure LDS read + global store (64 rows x 16 chunks of 8B)
#pragma unroll
    for (int u = 0; u < 4; ++u) {
      int idx = u * 256 + tid;
      int row = idx >> 4, q = idx & 15;
      if (row < rows) {
        unsigned long long v =
            *(const unsigned long long*)(lA + row * 128 + ((q * 8) ^ ((row & 7) << 3)));
        *(unsigned long long*)(msg + (size_t)lout[row] * 256 + half * 128 + q * 8) = v;
      }
    }
    return;
  }

  // ---------------- selfA path (col-split, acc[4][2]) ----------------
  int b2 = bid - EGRID2;
  int n0 = (b2 >> 1) * 64, half = b2 & 1;
  int rows = min(64, NN - n0);
  short8v sv[8];
#pragma unroll
  for (int u = 0; u < 8; ++u) {
    int idx = u * 256 + tid;
    int row = idx >> 5, q = idx & 31;
    int n = min(n0 + row, NN - 1);
    sv[u] = *(const short8v*)(featb + (size_t)n * 256 + q * 8);
  }
#pragma unroll
  for (int u = 0; u < 8; ++u) {
    int idx = u * 256 + tid;
    int row = idx >> 5, q = idx & 31;
    *(short8v*)(lA + ((row * 512 + q * 16) ^ ((row & 7) << 4))) = sv[u];
  }
  __syncthreads();
  f32x4 acc[4][2];
#pragma unroll
  for (int m = 0; m < 4; ++m)
#pragma unroll
    for (int c = 0; c < 2; ++c) acc[m][c] = (f32x4){0.f, 0.f, 0.f, 0.f};
  const short* bp = spk + (size_t)(half * 8 + wave * 2) * 4096 + (size_t)lane * 8;
  short8v b0 = *(const short8v*)(bp);
  short8v b1 = *(const short8v*)(bp + 4096);
#pragma unroll
  for (int kt = 0; kt < 8; ++kt) {
    short8v bn0, bn1;
    if (kt < 7) {
      bn0 = *(const short8v*)(bp + (kt + 1) * 512);
      bn1 = *(const short8v*)(bp + 4096 + (kt + 1) * 512);
    }
    short8v a[4];
#pragma unroll
    for (int m = 0; m < 4; ++m) {
      int row = m * 16 + l15;
      a[m] = *(const short8v*)(lA + ((row * 512 + kt * 64 + lg * 16) ^ ((row & 7) << 4)));
    }
#pragma unroll
    for (int m = 0; m < 4; ++m) {
      acc[m][0] = __builtin_amdgcn_mfma_f32_16x16x32_bf16(a[m], b0, acc[m][0], 0, 0, 0);
      acc[m][1] = __builtin_amdgcn_mfma_f32_16x16x32_bf16(a[m], b1, acc[m][1], 0, 0, 0);
    }
    if (kt < 7) { b0 = bn0; b1 = bn1; }
  }
  if (SB) {
    __syncthreads();                          // done reading lA
#pragma unroll
    for (int m = 0; m < 4; ++m)
#pragma unroll
      for (int j = 0; j < 4; ++j) {
        int row = m * 16 + lg * 4 + j;
        int rb = row * 512, sw = (row & 7) << 4;
#pragma unroll
        for (int c = 0; c < 2; ++c) {
          int col = wave * 32 + c * 16 + l15;
          *(unsigned short*)(lA + ((rb + col * 2) ^ sw)) = f2bf(acc[m][c][j]);
        }
      }
    __syncthreads();
#pragma unroll
    for (int u = 0; u < 4; ++u) {
      int idx = u * 256 + tid;
      int row = idx >> 4, q = idx & 15;
      if (row < rows) {
        short8v vv = *(const short8v*)(lA + ((row * 512 + q * 16) ^ ((row & 7) << 4)));
        *(short8v*)(sbuf + (size_t)(n0 + row) * 256 + half * 128 + q * 8) = vv;
      }
    }
  } else {
#pragma unroll
    for (int m = 0; m < 4; ++m)
#pragma unroll
      for (int j = 0; j < 4; ++j) {
        int n = n0 + m * 16 + lg * 4 + j;
        if (n < NN) {
          float* op = out + (size_t)n * 256 + half * 128 + wave * 32 + l15;
          op[0]  = acc[m][0][j];
          op[16] = acc[m][1][j];
        }
      }
  }
}

// ---------------------------------------------------------------------------
// Aggregate. SB=true: out[n] = sbuf[n] + sum fp8 msg rows (single write).
// SB=false: RMW out. msg is dst-sorted -> contiguous rows; 2x unrolled MLP.
template <bool SB>
__global__ __launch_bounds__(256) void k_aggregate(
    const unsigned char* __restrict__ msg, const int* __restrict__ row_ptr,
    const unsigned short* __restrict__ sbuf, float* __restrict__ out) {
  int g = blockIdx.x * 8 + (threadIdx.x >> 5);
  if (g >= NN) return;
  int hl = threadIdx.x & 31;
  int lo = row_ptr[g], hi = row_ptr[g + 1];
  float a[8];
  if (SB) {
    short8v s0 = *(const short8v*)(sbuf + (size_t)g * 256 + hl * 8);
#pragma unroll
    for (int k = 0; k < 8; ++k) a[k] = bf2f((unsigned short)s0[k]);
  } else {
    if (lo >= hi) return;
#pragma unroll
    for (int k = 0; k < 8; ++k) a[k] = 0.f;
  }
  int p = lo;
  for (; p + 1 < hi; p += 2) {
    unsigned long long pk0 = *(const unsigned long long*)(msg + (size_t)p * 256 + hl * 8);
    unsigned long long pk1 = *(const unsigned long long*)(msg + (size_t)(p + 1) * 256 + hl * 8);
#pragma unroll
    for (int k = 0; k < 8; ++k) {
      a[k] += e4m32f((unsigned char)(pk0 >> (k * 8)));
      a[k] += e4m32f((unsigned char)(pk1 >> (k * 8)));
    }
  }
  if (p < hi) {
    unsigned long long pk0 = *(const unsigned long long*)(msg + (size_t)p * 256 + hl * 8);
#pragma unroll
    for (int k = 0; k < 8; ++k) a[k] += e4m32f((unsigned char)(pk0 >> (k * 8)));
  }
  float* op = out + (size_t)g * 256 + hl * 8;
  if (SB) {
#pragma unroll
    for (int c = 0; c < 2; ++c) {
      f32x4 o;
      o[0] = a[c * 4]; o[1] = a[c * 4 + 1]; o[2] = a[c * 4 + 2]; o[3] = a[c * 4 + 3];
      *(f32x4*)(op + c * 4) = o;
    }
  } else {
#pragma unroll
    for (int c = 0; c < 2; ++c) {
      f32x4 o = *(const f32x4*)(op + c * 4);
      o[0] += a[c * 4]; o[1] += a[c * 4 + 1]; o[2] += a[c * 4 + 2]; o[3] += a[c * 4 + 3];
      *(f32x4*)(op + c * 4) = o;
    }
  }
}

// ---------------------------------------------------------------------------
// Tier B/C fallbacks (atomic epilogue), using flat gsrc/gdst/ginv metadata.
__device__ __forceinline__ void gemm64(const char* lA, const short* __restrict__ wpk,
                                       f32x4 acc[4][4], int wave, int lane) {
  int l15 = lane & 15, lg = lane >> 4;
  const short* bp = wpk + (size_t)wave * 4 * 4096 + (size_t)lane * 8;
#pragma unroll
  for (int kt = 0; kt < 8; ++kt) {
    short8v a[4], b[4];
#pragma unroll
    for (int c = 0; c < 4; ++c) b[c] = *(const short8v*)(bp + c * 4096 + kt * 512);
#pragma unroll
    for (int m = 0; m < 4; ++m) {
      int row = m * 16 + l15;
      a[m] = *(const short8v*)(lA + ((row * 512 + kt * 64 + lg * 16) ^ ((row & 7) << 4)));
    }
#pragma unroll
    for (int m = 0; m < 4; ++m)
#pragma unroll
      for (int c = 0; c < 4; ++c)
        acc[m][c] = __builtin_amdgcn_mfma_f32_16x16x32_bf16(a[m], b[c], acc[m][c], 0, 0, 0);
  }
}

template <bool B16>
__global__ __launch_bounds__(256) void k_self_gemm(const float* __restrict__ in_feat,
                                                   const unsigned short* __restrict__ featb,
                                                   const short* __restrict__ spk,
                                                   float* __restrict__ out) {
  __shared__ __align__(16) char lA[32768];
  int n0 = blockIdx.x * 64;
  int tid = threadIdx.x;
  if (B16) {
    short8v sv[8];
#pragma unroll
    for (int u = 0; u < 8; ++u) {
      int idx = u * 256 + tid;
      int row = idx >> 5, q = idx & 31;
      int n = min(n0 + row, NN - 1);
      sv[u] = *(const short8v*)(featb + (size_t)n * 256 + q * 8);
    }
#pragma unroll
    for (int u = 0; u < 8; ++u) {
      int idx = u * 256 + tid;
      int row = idx >> 5, q = idx & 31;
      *(short8v*)(lA + ((row * 512 + q * 16) ^ ((row & 7) << 4))) = sv[u];
    }
  } else {
#pragma unroll
    for (int half = 0; half < 2; ++half) {
      float4 v[8];
#pragma unroll
      for (int u = 0; u < 8; ++u) {
        int it = half * 2048 + u * 256 + tid;
        int row = it >> 6, q = it & 63;
        int n = n0 + row;
        v[u] = (n < NN) ? ((const float4*)(in_feat + (size_t)n * 256))[q]
                        : make_float4(0.f, 0.f, 0.f, 0.f);
      }
#pragma unroll
      for (int u = 0; u < 8; ++u) {
        int it = half * 2048 + u * 256 + tid;
        int row = it >> 6, q = it & 63;
        ushort4 hh;
        hh.x = f2bf(v[u].x); hh.y = f2bf(v[u].y); hh.z = f2bf(v[u].z); hh.w = f2bf(v[u].w);
        *(ushort4*)(lA + ((row * 512 + q * 8) ^ ((row & 7) << 4))) = hh;
      }
    }
  }
  __syncthreads();
  f32x4 acc[4][4];
#pragma unroll
  for (int m = 0; m < 4; ++m)
#pragma unroll
    for (int c = 0; c < 4; ++c) acc[m][c] = (f32x4){0.f, 0.f, 0.f, 0.f};
  int wave = tid >> 6, lane = tid & 63;
  gemm64(lA, spk, acc, wave, lane);
  int l15 = lane & 15, lg = lane >> 4;
#pragma unroll
  for (int m = 0; m < 4; ++m)
#pragma unroll
    for (int j = 0; j < 4; ++j) {
      int n = n0 + m * 16 + lg * 4 + j;
      if (n < NN) {
        float* op = out + (size_t)n * 256 + wave * 64 + l15;
#pragma unroll
        for (int c = 0; c < 4; ++c) op[c * 16] = acc[m][c][j];
      }
    }
}

template <int MODE>   // 0: f32 feat, 1: bf16 feat; atomic mean-scatter into out
__global__ __launch_bounds__(256) void k_edge_gemmBC(const float* __restrict__ in_feat,
                                                     const unsigned short* __restrict__ featb,
                                                     const short* __restrict__ wpk,
                                                     const int* __restrict__ gsrc,
                                                     const int* __restrict__ gdst,
                                                     const float* __restrict__ ginv,
                                                     const int4* __restrict__ tdesc,
                                                     float* __restrict__ out) {
  __shared__ __align__(16) char lA[32768];
  __shared__ int lsrc[64];
  __shared__ int ldst[64];
  __shared__ float linv[64];
  int bid = blockIdx.x;
  int tile = (bid & 7) * (MAXTILES / 8) + (bid >> 3);
  int4 d = tdesc[tile];
  int rows = d.z;
  if (rows <= 0) return;
  int r = d.x, rs = d.y;
  int tid = threadIdx.x;
  if (tid < 64) {
    if (tid < rows) {
      lsrc[tid] = gsrc[rs + tid];
      ldst[tid] = gdst[rs + tid];
      linv[tid] = ginv[rs + tid];
    } else {
      lsrc[tid] = -1; ldst[tid] = -1; linv[tid] = 0.f;
    }
  }
  __syncthreads();
  if (MODE == 1) {
    short8v sv[8];
#pragma unroll
    for (int u = 0; u < 8; ++u) {
      int idx = u * 256 + tid;
      int row = idx >> 5, q = idx & 31;
      int s = lsrc[row];
      sv[u] = (s >= 0) ? *(const short8v*)(featb + (size_t)s * 256 + q * 8)
                       : (short8v){0, 0, 0, 0, 0, 0, 0, 0};
    }
#pragma unroll
    for (int u = 0; u < 8; ++u) {
      int idx = u * 256 + tid;
      int row = idx >> 5, q = idx & 31;
      *(short8v*)(lA + ((row * 512 + q * 16) ^ ((row & 7) << 4))) = sv[u];
    }
  } else {
#pragma unroll
    for (int half = 0; half < 2; ++half) {
      float4 v[8];
#pragma unroll
      for (int u = 0; u < 8; ++u) {
        int it = half * 2048 + u * 256 + tid;
        int row = it >> 6, q = it & 63;
        int s = lsrc[row];
        v[u] = (s >= 0) ? ((const float4*)(in_feat + (size_t)s * 256))[q]
                        : make_float4(0.f, 0.f, 0.f, 0.f);
      }
#pragma unroll
      for (int u = 0; u < 8; ++u) {
        int it = half * 2048 + u * 256 + tid;
        int row = it >> 6, q = it & 63;
        ushort4 hh;
        hh.x = f2bf(v[u].x); hh.y = f2bf(v[u].y); hh.z = f2bf(v[u].z); hh.w = f2bf(v[u].w);
        *(ushort4*)(lA + ((row * 512 + q * 8) ^ ((row & 7) << 4))) = hh;
      }
    }
  }
  __syncthreads();
  f32x4 acc[4][4];
#pragma unroll
  for (int m = 0; m < 4; ++m)
#pragma unroll
    for (int c = 0; c < 4; ++c) acc[m][c] = (f32x4){0.f, 0.f, 0.f, 0.f};
  int wave = tid >> 6, lane = tid & 63;
  gemm64(lA, wpk + (size_t)r * 65536, acc, wave, lane);
  int l15 = lane & 15, lg = lane >> 4;
#pragma unroll
  for (int m = 0; m < 4; ++m)
#pragma unroll
    for (int j = 0; j < 4; ++j) {
      int row = m * 16 + lg * 4 + j;
      int dd = ldst[row];
      if (dd >= 0) {
        float inv = linv[row];
        float* op = out + (size_t)dd * 256 + wave * 64 + l15;
#pragma unroll
        for (int c = 0; c < 4; ++c) unsafeAtomicAdd(op + c * 16, acc[m][c][j] * inv);
      }
    }
}

// ---------------------------------------------------------------------------
extern "C" void kernel_launch(void* const* d_in, const int* in_sizes, int n_in,
                              void* d_out, int out_size, void* d_ws, size_t ws_size,
                              hipStream_t stream) {
  const float* in_feat = (const float*)d_in[0];
  const float* basis   = (const float*)d_in[1];
  const float* coef    = (const float*)d_in[2];
  const float* slw     = (const float*)d_in[3];
  const int*   src     = (const int*)d_in[4];
  const int*   dst     = (const int*)d_in[5];
  const int*   etype   = (const int*)d_in[6];
  float* out = (float*)d_out;

  char* base = (char*)d_ws;
  char* w = base;
  auto alloc = [&](size_t bytes) {
    char* p = w;
    w += (bytes + 255) & ~(size_t)255;
    return p;
  };
  // base group (tiers B/C)
  short* wpk  = (short*)alloc((size_t)RR * 65536 * 2);   // 26.2 MB
  short* spk  = (short*)alloc(65536 * 2);
  int*   gsrc = (int*)alloc((size_t)EE * 4);
  int*   gdst = (int*)alloc((size_t)EE * 4);
  float* ginv = (float*)alloc((size_t)EE * 4);
  int*   deg  = (int*)alloc((size_t)NN * 4);
  int*   hist = (int*)alloc(RR * 4);
  int*   cur  = (int*)alloc(RR * 4);
  int4*  tdesc = (int4*)alloc((size_t)MAXTILES * 16);
  int*   bsum = (int*)alloc(NSCAN * 4);
  // tier B adds bf16 feat
  unsigned short* featb = (unsigned short*)alloc((size_t)NN * 256 * 2);  // 51.2 MB
  size_t need_b = (size_t)(w - base);
  // tier A adds dst-CSR + fp8 msg buffer
  int* row_ptr = (int*)alloc((size_t)(NN + 1) * 4);
  int* cur2    = (int*)alloc((size_t)NN * 4);
  int* gout    = (int*)alloc((size_t)EE * 4);
  unsigned char* msg = (unsigned char*)alloc((size_t)EE * 256);          // 102.4 MB
  size_t need_a = (size_t)(w - base);
  // tier A+ adds bf16 self buffer
  unsigned short* sbuf = (unsigned short*)alloc((size_t)NN * 256 * 2);   // 51.2 MB
  size_t need_ap = (size_t)(w - base);

  bool tierAP = ws_size >= need_ap;
  bool tierA  = ws_size >= need_a;
  bool tierB  = ws_size >= need_b;

  hipMemsetAsync(hist, 0, RR * 4, stream);
  hipMemsetAsync(deg, 0, (size_t)NN * 4, stream);

  if (tierA || tierAP) {
    k_prep1<true><<<1344, 256, 0, stream>>>(basis, coef, slw, etype, dst, in_feat,
                                            wpk, spk, hist, deg, featb);
    k_prep2<<<NSCAN + 1, 256, 0, stream>>>(hist, deg, cur, tdesc, bsum);
    k_prep3<<<NSCAN, 256, 0, stream>>>(deg, bsum, row_ptr, cur2);
    k_prep4<true><<<(EE + SCHUNK - 1) / SCHUNK, 256, 0, stream>>>(
        etype, src, dst, deg, cur, gsrc, gdst, ginv, cur2, gout);
    if (tierAP) {
      k_main<true><<<EGRID2 + SGRID, 256, 0, stream>>>(featb, wpk, spk, gsrc, ginv,
                                                       gout, tdesc, msg, out, sbuf);
      k_aggregate<true><<<(NN + 7) / 8, 256, 0, stream>>>(msg, row_ptr, sbuf, out);
    } else {
      k_main<false><<<EGRID2 + SGRID, 256, 0, stream>>>(featb, wpk, spk, gsrc, ginv,
                                                        gout, tdesc, msg, out, nullptr);
      k_aggregate<false><<<(NN + 7) / 8, 256, 0, stream>>>(msg, row_ptr, nullptr, out);
    }
  } else if (tierB) {
    k_prep1<true><<<1344, 256, 0, stream>>>(basis, coef, slw, etype, dst, in_feat,
                                            wpk, spk, hist, deg, featb);
    k_prep2<<<NSCAN + 1, 256, 0, stream>>>(hist, deg, cur, tdesc, bsum);
    k_prep4<false><<<(EE + SCHUNK - 1) / SCHUNK, 256, 0, stream>>>(
        etype, src, dst, deg, cur, gsrc, gdst, ginv, nullptr, nullptr);
    k_self_gemm<true><<<(NN + 63) / 64, 256, 0, stream>>>(in_feat, featb, spk, out);
    k_edge_gemmBC<1><<<MAXTILES, 256, 0, stream>>>(in_feat, featb, wpk, gsrc, gdst,
                                                   ginv, tdesc, out);
  } else {
    k_prep1<false><<<1344, 256, 0, stream>>>(basis, coef, slw, etype, dst, in_feat,
                                             wpk, spk, hist, deg, nullptr);
    k_prep2<<<NSCAN + 1, 256, 0, stream>>>(hist, deg, cur, tdesc, bsum);
    k_prep4<false><<<(EE + SCHUNK - 1) / SCHUNK, 256, 0, stream>>>(
        etype, src, dst, deg, cur, gsrc, gdst, ginv, nullptr, nullptr);
    k_self_gemm<false><<<(NN + 63) / 64, 256, 0, stream>>>(in_feat, nullptr, spk, out);
    k_edge_gemmBC<0><<<MAXTILES, 256, 0, stream>>>(in_feat, nullptr, wpk, gsrc, gdst,
                                                   ginv, tdesc, out);
  }
}

// Round 16
// 297.952 us; speedup vs baseline: 1.4453x; 1.0013x over previous
//
#include <hip/hip_runtime.h>
#include <hip/hip_bf16.h>
#include <hip/hip_fp8.h>

// RGCN forward, MI355X. N=100000, E=400000, IN=OUT=256, R=200, B=32.
// Tier A+: prep1{wgen|slwpk|hist+feat} -> prep2{etype-scan|deg-blocksums} ->
// prep3{deg-scan} -> prep4{scatter: gsrc/ginv/gout} ->
// k_main{edge GEMM (bf16 MFMA) -> fp8 e4m3 msg rows (dst-sorted) + col-split
// selfA GEMM -> bf16 sbuf} -> aggregate{out[n] = sbuf[n] + sum fp8 msg rows,
// HW packed v_cvt_pk_f32_fp8 decode}.

#define NN 100000
#define EE 400000
#define RR 200
#define BB 32
#define MAXTILES 6464   // >= E/64 + R ; divisible by 8
#define EQ2 (MAXTILES * 2 / 8)   // 1616 ords per XCD
#define EGRID2 (MAXTILES * 2)    // 12928 edge blocks
#define SGRID (((NN + 63) / 64) * 2)  // 3126 selfA blocks
#define SCHUNK 2048
#define NSCAN ((NN + 255) / 256) // 391

typedef __attribute__((ext_vector_type(8))) short short8v;   // 8 x bf16 (16B)
typedef __attribute__((ext_vector_type(4))) float f32x4;
typedef __attribute__((ext_vector_type(2))) float f32x2;

__device__ __forceinline__ unsigned short f2bf(float f) {
  unsigned u = __float_as_uint(f);
  u += 0x7FFF + ((u >> 16) & 1);          // RNE
  return (unsigned short)(u >> 16);
}
__device__ __forceinline__ float bf2f(unsigned short h) {
  return __uint_as_float(((unsigned)h) << 16);
}
__device__ __forceinline__ unsigned char f2e4m3(float f) {
  __hip_fp8_e4m3 q(f);
  return (unsigned char)q.__x;
}
__device__ __forceinline__ float e4m32f(unsigned char b) {
  __hip_fp8_e4m3 q;
  q.__x = (__hip_fp8_storage_t)b;
  return (float)q;
}
// decode 4 fp8 (one u32) into 4 f32 via HW packed cvt where available
__device__ __forceinline__ void fp8x4_to_f32(unsigned int pk, float* o) {
#if __has_builtin(__builtin_amdgcn_cvt_pk_f32_fp8)
  f32x2 lo = __builtin_amdgcn_cvt_pk_f32_fp8((int)pk, false);
  f32x2 hi = __builtin_amdgcn_cvt_pk_f32_fp8((int)pk, true);
  o[0] = lo[0]; o[1] = lo[1]; o[2] = hi[0]; o[3] = hi[1];
#else
  o[0] = e4m32f((unsigned char)pk);
  o[1] = e4m32f((unsigned char)(pk >> 8));
  o[2] = e4m32f((unsigned char)(pk >> 16));
  o[3] = e4m32f((unsigned char)(pk >> 24));
#endif
}

// ---------------------------------------------------------------------------
// prep1: blocks [0,800): wgen (L2-blocked W_r pack); [800,832): slwpk;
// [832,1344): etype hist + dst degree + (FEAT) f32->bf16 feature convert.
// W_pk layout per relation: [ct=16][kt=8][lane=64][j=8] bf16 where
//   value = W_r[k = kt*32 + (lane>>4)*8 + j][n = ct*16 + (lane&15)].
template <bool FEAT>
__global__ __launch_bounds__(256) void k_prep1(
    const float* __restrict__ basis, const float* __restrict__ coef,
    const float* __restrict__ slw, const int* __restrict__ etype,
    const int* __restrict__ dst, const float* __restrict__ in_feat,
    short* __restrict__ wpk, short* __restrict__ spk,
    int* __restrict__ hist, int* __restrict__ deg,
    unsigned short* __restrict__ featb) {
  __shared__ int lh[RR];
  int b = blockIdx.x, tid = threadIdx.x;
  if (b < 800) {                       // ---- wgen ----
    int ord = (b & 7) * 100 + (b >> 3);
    int rg = ord % 25;
    int pk8 = (ord / 25) * 256 + tid;
    int lane = pk8 & 63;
    int kt = (pk8 >> 6) & 7;
    int ct = pk8 >> 9;
    int n  = ct * 16 + (lane & 15);
    int k0 = kt * 32 + ((lane >> 4) << 3);
    float acc[8][8];
#pragma unroll
    for (int r = 0; r < 8; ++r)
#pragma unroll
      for (int j = 0; j < 8; ++j) acc[r][j] = 0.f;
    for (int bb = 0; bb < BB; ++bb) {
      float bas[8];
#pragma unroll
      for (int j = 0; j < 8; ++j) bas[j] = basis[bb * 65536 + (k0 + j) * 256 + n];
#pragma unroll
      for (int r = 0; r < 8; ++r) {
        float c = coef[(rg * 8 + r) * BB + bb];
#pragma unroll
        for (int j = 0; j < 8; ++j) acc[r][j] += c * bas[j];
      }
    }
#pragma unroll
    for (int r = 0; r < 8; ++r) {
      short8v v;
#pragma unroll
      for (int j = 0; j < 8; ++j) v[j] = (short)f2bf(acc[r][j]);
      *(short8v*)(wpk + (size_t)(rg * 8 + r) * 65536 + (size_t)pk8 * 8) = v;
    }
    return;
  }
  if (b < 832) {                       // ---- slwpk ----
    int t = (b - 800) * 256 + tid;
    int lane = t & 63;
    int kt = (t >> 6) & 7;
    int ct = t >> 9;
    int n  = ct * 16 + (lane & 15);
    int k0 = kt * 32 + ((lane >> 4) << 3);
    short8v v;
#pragma unroll
    for (int j = 0; j < 8; ++j) v[j] = (short)f2bf(slw[(k0 + j) * 256 + n]);
    *(short8v*)(spk + (size_t)t * 8) = v;
    return;
  }
  // ---- hist + deg + feat ----
  int hb = b - 832;                    // 512 blocks
  for (int i = tid; i < RR; i += 256) lh[i] = 0;
  __syncthreads();
  for (int e = hb * 256 + tid; e < EE; e += 512 * 256) {
    atomicAdd(&lh[etype[e]], 1);
    atomicAdd(&deg[dst[e]], 1);
  }
  if (FEAT) {
    const int total = NN * 64;         // float4 count
    for (int i = hb * 256 + tid; i < total; i += 512 * 256) {
      float4 v = ((const float4*)in_feat)[i];
      ushort4 h;
      h.x = f2bf(v.x); h.y = f2bf(v.y); h.z = f2bf(v.z); h.w = f2bf(v.w);
      ((ushort4*)featb)[i] = h;
    }
  }
  __syncthreads();
  for (int i = tid; i < RR; i += 256)
    if (lh[i]) atomicAdd(&hist[i], lh[i]);
}

// ---------------------------------------------------------------------------
// prep2: block 0: etype-bin scan -> cur + tdesc; blocks 1..391: deg block sums.
__global__ __launch_bounds__(256) void k_prep2(const int* __restrict__ hist,
                                               const int* __restrict__ deg,
                                               int* __restrict__ cur,
                                               int4* __restrict__ tdesc,
                                               int* __restrict__ bsum) {
  __shared__ int h[RR];
  __shared__ int off[RR];
  __shared__ int toff[RR];
  __shared__ int tot;
  __shared__ int ws4[4];
  int b = blockIdx.x, tid = threadIdx.x;
  if (b == 0) {
    for (int i = tid; i < RR; i += 256) h[i] = hist[i];
    __syncthreads();
    if (tid == 0) {
      int s = 0, ts = 0;
      for (int r = 0; r < RR; ++r) {
        off[r] = s; s += h[r];
        toff[r] = ts; ts += (h[r] + 63) >> 6;
      }
      tot = ts;
    }
    __syncthreads();
    if (tid < RR) {
      int r = tid, cnt = h[r], base = off[r], to = toff[r];
      cur[r] = base;
      int nt = (cnt + 63) >> 6;
      for (int t2 = 0; t2 < nt; ++t2)
        tdesc[to + t2] = make_int4(r, base + t2 * 64, min(64, cnt - t2 * 64), 0);
    }
    for (int i = tot + tid; i < MAXTILES; i += 256)
      tdesc[i] = make_int4(0, 0, 0, 0);
    return;
  }
  int i = (b - 1) * 256 + tid;
  int v = (i < NN) ? deg[i] : 0;
#pragma unroll
  for (int d = 32; d; d >>= 1) v += __shfl_down(v, d, 64);
  if ((tid & 63) == 0) ws4[tid >> 6] = v;
  __syncthreads();
  if (tid == 0) bsum[b - 1] = ws4[0] + ws4[1] + ws4[2] + ws4[3];
}

// prep3 (tier A): deg exclusive scan -> row_ptr/cur2; bsum prefix inline.
__global__ __launch_bounds__(256) void k_prep3(const int* __restrict__ deg,
                                               const int* __restrict__ bsum,
                                               int* __restrict__ row_ptr,
                                               int* __restrict__ cur2) {
  __shared__ int ws4[4];
  __shared__ int wo4[4];
  __shared__ int psum[4];
  int tid = threadIdx.x, b = blockIdx.x;
  int sp = 0;
  for (int i = tid; i < b; i += 256) sp += bsum[i];
#pragma unroll
  for (int d = 32; d; d >>= 1) sp += __shfl_down(sp, d, 64);
  if ((tid & 63) == 0) psum[tid >> 6] = sp;
  int i = b * 256 + tid;
  int v = (i < NN) ? deg[i] : 0;
  int x = v;
#pragma unroll
  for (int d = 1; d < 64; d <<= 1) {
    int y = __shfl_up(x, d, 64);
    if ((tid & 63) >= d) x += y;
  }
  if ((tid & 63) == 63) ws4[tid >> 6] = x;
  __syncthreads();
  if (tid == 0) {
    int s = 0;
    for (int w2 = 0; w2 < 4; ++w2) { wo4[w2] = s; s += ws4[w2]; }
    psum[0] = psum[0] + psum[1] + psum[2] + psum[3];
  }
  __syncthreads();
  int excl = x - v + wo4[tid >> 6] + psum[0];
  if (i < NN) { row_ptr[i] = excl; cur2[i] = excl; }
  if (i == 0 && b == 0) row_ptr[NN] = EE;
}

// prep4: counting-sort scatter; materializes per-position gsrc/ginv and
// (DL) gout[s] = dst-sorted msg slot. gdst only written for tiers B/C (!DL).
template <bool DL>
__global__ __launch_bounds__(256) void k_prep4(const int* __restrict__ etype,
                                               const int* __restrict__ src,
                                               const int* __restrict__ dst,
                                               const int* __restrict__ deg,
                                               int* __restrict__ cur,
                                               int* __restrict__ gsrc,
                                               int* __restrict__ gdst,
                                               float* __restrict__ ginv,
                                               int* __restrict__ cur2,
                                               int* __restrict__ gout) {
  __shared__ int lh[RR];
  __shared__ int lbase[RR];
  __shared__ int lcur[RR];
  int tid = threadIdx.x;
  int e0 = blockIdx.x * SCHUNK;
  for (int i = tid; i < RR; i += 256) lh[i] = 0;
  __syncthreads();
  for (int i = tid; i < SCHUNK; i += 256) {
    int e = e0 + i;
    if (e < EE) atomicAdd(&lh[etype[e]], 1);
  }
  __syncthreads();
  for (int i = tid; i < RR; i += 256) {
    int c = lh[i];
    lbase[i] = c ? atomicAdd(&cur[i], c) : 0;
    lcur[i] = 0;
  }
  __syncthreads();
  for (int i = tid; i < SCHUNK; i += 256) {
    int e = e0 + i;
    if (e < EE) {
      int et = etype[e];
      int s = lbase[et] + atomicAdd(&lcur[et], 1);
      int d = dst[e];
      gsrc[s] = src[e];
      ginv[s] = 1.0f / (float)max(deg[d], 1);
      if (DL) {
        int pos = atomicAdd(&cur2[d], 1);
        gout[s] = pos;
      } else {
        gdst[s] = d;
      }
    }
  }
}

// ---------------------------------------------------------------------------
// Tier A/A+ main kernel. Blocks [0, EGRID2) = edge GEMM (r11 structure);
// blocks [EGRID2, EGRID2+SGRID) = col-split self-loop GEMM.
// Edge epilogue: acc scaled + converted to fp8 ONCE, byte-swizzled into LDS;
// store phase is pure ds_read_b64 + global_store.
template <bool SB>
__global__ __launch_bounds__(256) void k_main(
    const unsigned short* __restrict__ featb, const short* __restrict__ wpk,
    const short* __restrict__ spk, const int* __restrict__ gsrc,
    const float* __restrict__ ginv, const int* __restrict__ gout,
    const int4* __restrict__ tdesc, unsigned char* __restrict__ msg,
    float* __restrict__ out, unsigned short* __restrict__ sbuf) {
  __shared__ __align__(16) char lA[32768];
  __shared__ int lsrc[64];
  __shared__ float linv[64];
  __shared__ int lout[64];
  int tid = threadIdx.x, wave = tid >> 6, lane = tid & 63;
  int l15 = lane & 15, lg = lane >> 4;
  int bid = blockIdx.x;

  if (bid < EGRID2) {
    // ---------------- edge path ----------------
    int ord = (bid & 7) * EQ2 + (bid >> 3);
    int tile = ord >> 1, half = ord & 1;
    int4 d = tdesc[tile];
    int rows = d.z;
    if (rows <= 0) return;
    int r = d.x, rs = d.y;
    if (tid < 64) {
      int s = min(rs + tid, EE - 1);
      lsrc[tid] = gsrc[s];
      linv[tid] = ginv[s];
      lout[tid] = gout[s];
    }
    __syncthreads();
    short8v sv[8];
#pragma unroll
    for (int u = 0; u < 8; ++u) {
      int idx = u * 256 + tid;
      int row = idx >> 5, q = idx & 31;
      sv[u] = *(const short8v*)(featb + (size_t)lsrc[row] * 256 + q * 8);
    }
#pragma unroll
    for (int u = 0; u < 8; ++u) {
      int idx = u * 256 + tid;
      int row = idx >> 5, q = idx & 31;
      *(short8v*)(lA + ((row * 512 + q * 16) ^ ((row & 7) << 4))) = sv[u];
    }
    __syncthreads();
    f32x4 acc[4][2];
#pragma unroll
    for (int m = 0; m < 4; ++m)
#pragma unroll
      for (int c = 0; c < 2; ++c) acc[m][c] = (f32x4){0.f, 0.f, 0.f, 0.f};
    const short* bp = wpk + (size_t)r * 65536 +
                      (size_t)(half * 8 + wave * 2) * 4096 + (size_t)lane * 8;
    short8v b0 = *(const short8v*)(bp);
    short8v b1 = *(const short8v*)(bp + 4096);
#pragma unroll
    for (int kt = 0; kt < 8; ++kt) {
      short8v bn0, bn1;
      if (kt < 7) {
        bn0 = *(const short8v*)(bp + (kt + 1) * 512);
        bn1 = *(const short8v*)(bp + 4096 + (kt + 1) * 512);
      }
      short8v a[4];
#pragma unroll
      for (int m = 0; m < 4; ++m) {
        int row = m * 16 + l15;
        a[m] = *(const short8v*)(lA + ((row * 512 + kt * 64 + lg * 16) ^ ((row & 7) << 4)));
      }
#pragma unroll
      for (int m = 0; m < 4; ++m) {
        acc[m][0] = __builtin_amdgcn_mfma_f32_16x16x32_bf16(a[m], b0, acc[m][0], 0, 0, 0);
        acc[m][1] = __builtin_amdgcn_mfma_f32_16x16x32_bf16(a[m], b1, acc[m][1], 0, 0, 0);
      }
      if (kt < 7) { b0 = bn0; b1 = bn1; }
    }
    __syncthreads();                          // done reading lA (bf16 A tile)
    // scale + convert to fp8 directly into LDS (64 rows x 128 B)
#pragma unroll
    for (int m = 0; m < 4; ++m)
#pragma unroll
      for (int j = 0; j < 4; ++j) {
        int row = m * 16 + lg * 4 + j;
        float inv = linv[row];
        int rb = row * 128, sw = (row & 7) << 3;
#pragma unroll
        for (int c = 0; c < 2; ++c) {
          int col = wave * 32 + c * 16 + l15;
          lA[rb + (col ^ sw)] = (char)f2e4m3(acc[m][c][j] * inv);
        }
      }
    __syncthreads();
    // store: pure LDS read + global store (64 rows x 16 chunks of 8B)
#pragma unroll
    for (int u = 0; u < 4; ++u) {
      int idx = u * 256 + tid;
      int row = idx >> 4, q = idx & 15;
      if (row < rows) {
        unsigned long long v =
            *(const unsigned long long*)(lA + row * 128 + ((q * 8) ^ ((row & 7) << 3)));
        *(unsigned long long*)(msg + (size_t)lout[row] * 256 + half * 128 + q * 8) = v;
      }
    }
    return;
  }

  // ---------------- selfA path (col-split, acc[4][2]) ----------------
  int b2 = bid - EGRID2;
  int n0 = (b2 >> 1) * 64, half = b2 & 1;
  int rows = min(64, NN - n0);
  short8v sv[8];
#pragma unroll
  for (int u = 0; u < 8; ++u) {
    int idx = u * 256 + tid;
    int row = idx >> 5, q = idx & 31;
    int n = min(n0 + row, NN - 1);
    sv[u] = *(const short8v*)(featb + (size_t)n * 256 + q * 8);
  }
#pragma unroll
  for (int u = 0; u < 8; ++u) {
    int idx = u * 256 + tid;
    int row = idx >> 5, q = idx & 31;
    *(short8v*)(lA + ((row * 512 + q * 16) ^ ((row & 7) << 4))) = sv[u];
  }
  __syncthreads();
  f32x4 acc[4][2];
#pragma unroll
  for (int m = 0; m < 4; ++m)
#pragma unroll
    for (int c = 0; c < 2; ++c) acc[m][c] = (f32x4){0.f, 0.f, 0.f, 0.f};
  const short* bp = spk + (size_t)(half * 8 + wave * 2) * 4096 + (size_t)lane * 8;
  short8v b0 = *(const short8v*)(bp);
  short8v b1 = *(const short8v*)(bp + 4096);
#pragma unroll
  for (int kt = 0; kt < 8; ++kt) {
    short8v bn0, bn1;
    if (kt < 7) {
      bn0 = *(const short8v*)(bp + (kt + 1) * 512);
      bn1 = *(const short8v*)(bp + 4096 + (kt + 1) * 512);
    }
    short8v a[4];
#pragma unroll
    for (int m = 0; m < 4; ++m) {
      int row = m * 16 + l15;
      a[m] = *(const short8v*)(lA + ((row * 512 + kt * 64 + lg * 16) ^ ((row & 7) << 4)));
    }
#pragma unroll
    for (int m = 0; m < 4; ++m) {
      acc[m][0] = __builtin_amdgcn_mfma_f32_16x16x32_bf16(a[m], b0, acc[m][0], 0, 0, 0);
      acc[m][1] = __builtin_amdgcn_mfma_f32_16x16x32_bf16(a[m], b1, acc[m][1], 0, 0, 0);
    }
    if (kt < 7) { b0 = bn0; b1 = bn1; }
  }
  if (SB) {
    __syncthreads();                          // done reading lA
#pragma unroll
    for (int m = 0; m < 4; ++m)
#pragma unroll
      for (int j = 0; j < 4; ++j) {
        int row = m * 16 + lg * 4 + j;
        int rb = row * 512, sw = (row & 7) << 4;
#pragma unroll
        for (int c = 0; c < 2; ++c) {
          int col = wave * 32 + c * 16 + l15;
          *(unsigned short*)(lA + ((rb + col * 2) ^ sw)) = f2bf(acc[m][c][j]);
        }
      }
    __syncthreads();
#pragma unroll
    for (int u = 0; u < 4; ++u) {
      int idx = u * 256 + tid;
      int row = idx >> 4, q = idx & 15;
      if (row < rows) {
        short8v vv = *(const short8v*)(lA + ((row * 512 + q * 16) ^ ((row & 7) << 4)));
        *(short8v*)(sbuf + (size_t)(n0 + row) * 256 + half * 128 + q * 8) = vv;
      }
    }
  } else {
#pragma unroll
    for (int m = 0; m < 4; ++m)
#pragma unroll
      for (int j = 0; j < 4; ++j) {
        int n = n0 + m * 16 + lg * 4 + j;
        if (n < NN) {
          float* op = out + (size_t)n * 256 + half * 128 + wave * 32 + l15;
          op[0]  = acc[m][0][j];
          op[16] = acc[m][1][j];
        }
      }
  }
}

// ---------------------------------------------------------------------------
// Aggregate. SB=true: out[n] = sbuf[n] + sum fp8 msg rows (single write).
// HW packed fp8->f32 decode (v_cvt_pk_f32_fp8); 2-row MLP.
template <bool SB>
__global__ __launch_bounds__(256) void k_aggregate(
    const unsigned char* __restrict__ msg, const int* __restrict__ row_ptr,
    const unsigned short* __restrict__ sbuf, float* __restrict__ out) {
  int g = blockIdx.x * 8 + (threadIdx.x >> 5);
  if (g >= NN) return;
  int hl = threadIdx.x & 31;
  int lo = row_ptr[g], hi = row_ptr[g + 1];
  float a[8];
  if (SB) {
    short8v s0 = *(const short8v*)(sbuf + (size_t)g * 256 + hl * 8);
#pragma unroll
    for (int k = 0; k < 8; ++k) a[k] = bf2f((unsigned short)s0[k]);
  } else {
    if (lo >= hi) return;
#pragma unroll
    for (int k = 0; k < 8; ++k) a[k] = 0.f;
  }
  int p = lo;
  for (; p + 1 < hi; p += 2) {
    uint2 pk0 = *(const uint2*)(msg + (size_t)p * 256 + hl * 8);
    uint2 pk1 = *(const uint2*)(msg + (size_t)(p + 1) * 256 + hl * 8);
    float f0[4], f1[4], f2[4], f3[4];
    fp8x4_to_f32(pk0.x, f0);
    fp8x4_to_f32(pk0.y, f1);
    fp8x4_to_f32(pk1.x, f2);
    fp8x4_to_f32(pk1.y, f3);
#pragma unroll
    for (int k = 0; k < 4; ++k) {
      a[k]     += f0[k] + f2[k];
      a[k + 4] += f1[k] + f3[k];
    }
  }
  if (p < hi) {
    uint2 pk0 = *(const uint2*)(msg + (size_t)p * 256 + hl * 8);
    float f0[4], f1[4];
    fp8x4_to_f32(pk0.x, f0);
    fp8x4_to_f32(pk0.y, f1);
#pragma unroll
    for (int k = 0; k < 4; ++k) {
      a[k]     += f0[k];
      a[k + 4] += f1[k];
    }
  }
  float* op = out + (size_t)g * 256 + hl * 8;
  if (SB) {
#pragma unroll
    for (int c = 0; c < 2; ++c) {
      f32x4 o;
      o[0] = a[c * 4]; o[1] = a[c * 4 + 1]; o[2] = a[c * 4 + 2]; o[3] = a[c * 4 + 3];
      *(f32x4*)(op + c * 4) = o;
    }
  } else {
#pragma unroll
    for (int c = 0; c < 2; ++c) {
      f32x4 o = *(const f32x4*)(op + c * 4);
      o[0] += a[c * 4]; o[1] += a[c * 4 + 1]; o[2] += a[c * 4 + 2]; o[3] += a[c * 4 + 3];
      *(f32x4*)(op + c * 4) = o;
    }
  }
}

// ---------------------------------------------------------------------------
// Tier B/C fallbacks (atomic epilogue), using flat gsrc/gdst/ginv metadata.
__device__ __forceinline__ void gemm64(const char* lA, const short* __restrict__ wpk,
                                       f32x4 acc[4][4], int wave, int lane) {
  int l15 = lane & 15, lg = lane >> 4;
  const short* bp = wpk + (size_t)wave * 4 * 4096 + (size_t)lane * 8;
#pragma unroll
  for (int kt = 0; kt < 8; ++kt) {
    short8v a[4], b[4];
#pragma unroll
    for (int c = 0; c < 4; ++c) b[c] = *(const short8v*)(bp + c * 4096 + kt * 512);
#pragma unroll
    for (int m = 0; m < 4; ++m) {
      int row = m * 16 + l15;
      a[m] = *(const short8v*)(lA + ((row * 512 + kt * 64 + lg * 16) ^ ((row & 7) << 4)));
    }
#pragma unroll
    for (int m = 0; m < 4; ++m)
#pragma unroll
      for (int c = 0; c < 4; ++c)
        acc[m][c] = __builtin_amdgcn_mfma_f32_16x16x32_bf16(a[m], b[c], acc[m][c], 0, 0, 0);
  }
}

template <bool B16>
__global__ __launch_bounds__(256) void k_self_gemm(const float* __restrict__ in_feat,
                                                   const unsigned short* __restrict__ featb,
                                                   const short* __restrict__ spk,
                                                   float* __restrict__ out) {
  __shared__ __align__(16) char lA[32768];
  int n0 = blockIdx.x * 64;
  int tid = threadIdx.x;
  if (B16) {
    short8v sv[8];
#pragma unroll
    for (int u = 0; u < 8; ++u) {
      int idx = u * 256 + tid;
      int row = idx >> 5, q = idx & 31;
      int n = min(n0 + row, NN - 1);
      sv[u] = *(const short8v*)(featb + (size_t)n * 256 + q * 8);
    }
#pragma unroll
    for (int u = 0; u < 8; ++u) {
      int idx = u * 256 + tid;
      int row = idx >> 5, q = idx & 31;
      *(short8v*)(lA + ((row * 512 + q * 16) ^ ((row & 7) << 4))) = sv[u];
    }
  } else {
#pragma unroll
    for (int half = 0; half < 2; ++half) {
      float4 v[8];
#pragma unroll
      for (int u = 0; u < 8; ++u) {
        int it = half * 2048 + u * 256 + tid;
        int row = it >> 6, q = it & 63;
        int n = n0 + row;
        v[u] = (n < NN) ? ((const float4*)(in_feat + (size_t)n * 256))[q]
                        : make_float4(0.f, 0.f, 0.f, 0.f);
      }
#pragma unroll
      for (int u = 0; u < 8; ++u) {
        int it = half * 2048 + u * 256 + tid;
        int row = it >> 6, q = it & 63;
        ushort4 hh;
        hh.x = f2bf(v[u].x); hh.y = f2bf(v[u].y); hh.z = f2bf(v[u].z); hh.w = f2bf(v[u].w);
        *(ushort4*)(lA + ((row * 512 + q * 8) ^ ((row & 7) << 4))) = hh;
      }
    }
  }
  __syncthreads();
  f32x4 acc[4][4];
#pragma unroll
  for (int m = 0; m < 4; ++m)
#pragma unroll
    for (int c = 0; c < 4; ++c) acc[m][c] = (f32x4){0.f, 0.f, 0.f, 0.f};
  int wave = tid >> 6, lane = tid & 63;
  gemm64(lA, spk, acc, wave, lane);
  int l15 = lane & 15, lg = lane >> 4;
#pragma unroll
  for (int m = 0; m < 4; ++m)
#pragma unroll
    for (int j = 0; j < 4; ++j) {
      int n = n0 + m * 16 + lg * 4 + j;
      if (n < NN) {
        float* op = out + (size_t)n * 256 + wave * 64 + l15;
#pragma unroll
        for (int c = 0; c < 4; ++c) op[c * 16] = acc[m][c][j];
      }
    }
}

template <int MODE>   // 0: f32 feat, 1: bf16 feat; atomic mean-scatter into out
__global__ __launch_bounds__(256) void k_edge_gemmBC(const float* __restrict__ in_feat,
                                                     const unsigned short* __restrict__ featb,
                                                     const short* __restrict__ wpk,
                                                     const int* __restrict__ gsrc,
                                                     const int* __restrict__ gdst,
                                                     const float* __restrict__ ginv,
                                                     const int4* __restrict__ tdesc,
                                                     float* __restrict__ out) {
  __shared__ __align__(16) char lA[32768];
  __shared__ int lsrc[64];
  __shared__ int ldst[64];
  __shared__ float linv[64];
  int bid = blockIdx.x;
  int tile = (bid & 7) * (MAXTILES / 8) + (bid >> 3);
  int4 d = tdesc[tile];
  int rows = d.z;
  if (rows <= 0) return;
  int r = d.x, rs = d.y;
  int tid = threadIdx.x;
  if (tid < 64) {
    if (tid < rows) {
      lsrc[tid] = gsrc[rs + tid];
      ldst[tid] = gdst[rs + tid];
      linv[tid] = ginv[rs + tid];
    } else {
      lsrc[tid] = -1; ldst[tid] = -1; linv[tid] = 0.f;
    }
  }
  __syncthreads();
  if (MODE == 1) {
    short8v sv[8];
#pragma unroll
    for (int u = 0; u < 8; ++u) {
      int idx = u * 256 + tid;
      int row = idx >> 5, q = idx & 31;
      int s = lsrc[row];
      sv[u] = (s >= 0) ? *(const short8v*)(featb + (size_t)s * 256 + q * 8)
                       : (short8v){0, 0, 0, 0, 0, 0, 0, 0};
    }
#pragma unroll
    for (int u = 0; u < 8; ++u) {
      int idx = u * 256 + tid;
      int row = idx >> 5, q = idx & 31;
      *(short8v*)(lA + ((row * 512 + q * 16) ^ ((row & 7) << 4))) = sv[u];
    }
  } else {
#pragma unroll
    for (int half = 0; half < 2; ++half) {
      float4 v[8];
#pragma unroll
      for (int u = 0; u < 8; ++u) {
        int it = half * 2048 + u * 256 + tid;
        int row = it >> 6, q = it & 63;
        int s = lsrc[row];
        v[u] = (s >= 0) ? ((const float4*)(in_feat + (size_t)s * 256))[q]
                        : make_float4(0.f, 0.f, 0.f, 0.f);
      }
#pragma unroll
      for (int u = 0; u < 8; ++u) {
        int it = half * 2048 + u * 256 + tid;
        int row = it >> 6, q = it & 63;
        ushort4 hh;
        hh.x = f2bf(v[u].x); hh.y = f2bf(v[u].y); hh.z = f2bf(v[u].z); hh.w = f2bf(v[u].w);
        *(ushort4*)(lA + ((row * 512 + q * 8) ^ ((row & 7) << 4))) = hh;
      }
    }
  }
  __syncthreads();
  f32x4 acc[4][4];
#pragma unroll
  for (int m = 0; m < 4; ++m)
#pragma unroll
    for (int c = 0; c < 4; ++c) acc[m][c] = (f32x4){0.f, 0.f, 0.f, 0.f};
  int wave = tid >> 6, lane = tid & 63;
  gemm64(lA, wpk + (size_t)r * 65536, acc, wave, lane);
  int l15 = lane & 15, lg = lane >> 4;
#pragma unroll
  for (int m = 0; m < 4; ++m)
#pragma unroll
    for (int j = 0; j < 4; ++j) {
      int row = m * 16 + lg * 4 + j;
      int dd = ldst[row];
      if (dd >= 0) {
        float inv = linv[row];
        float* op = out + (size_t)dd * 256 + wave * 64 + l15;
#pragma unroll
        for (int c = 0; c < 4; ++c) unsafeAtomicAdd(op + c * 16, acc[m][c][j] * inv);
      }
    }
}

// ---------------------------------------------------------------------------
extern "C" void kernel_launch(void* const* d_in, const int* in_sizes, int n_in,
                              void* d_out, int out_size, void* d_ws, size_t ws_size,
                              hipStream_t stream) {
  const float* in_feat = (const float*)d_in[0];
  const float* basis   = (const float*)d_in[1];
  const float* coef    = (const float*)d_in[2];
  const float* slw     = (const float*)d_in[3];
  const int*   src     = (const int*)d_in[4];
  const int*   dst     = (const int*)d_in[5];
  const int*   etype   = (const int*)d_in[6];
  float* out = (float*)d_out;

  char* base = (char*)d_ws;
  char* w = base;
  auto alloc = [&](size_t bytes) {
    char* p = w;
    w += (bytes + 255) & ~(size_t)255;
    return p;
  };
  // base group (tiers B/C)
  short* wpk  = (short*)alloc((size_t)RR * 65536 * 2);   // 26.2 MB
  short* spk  = (short*)alloc(65536 * 2);
  int*   gsrc = (int*)alloc((size_t)EE * 4);
  int*   gdst = (int*)alloc((size_t)EE * 4);
  float* ginv = (float*)alloc((size_t)EE * 4);
  int*   deg  = (int*)alloc((size_t)NN * 4);
  int*   hist = (int*)alloc(RR * 4);
  int*   cur  = (int*)alloc(RR * 4);
  int4*  tdesc = (int4*)alloc((size_t)MAXTILES * 16);
  int*   bsum = (int*)alloc(NSCAN * 4);
  // tier B adds bf16 feat
  unsigned short* featb = (unsigned short*)alloc((size_t)NN * 256 * 2);  // 51.2 MB
  size_t need_b = (size_t)(w - base);
  // tier A adds dst-CSR + fp8 msg buffer
  int* row_ptr = (int*)alloc((size_t)(NN + 1) * 4);
  int* cur2    = (int*)alloc((size_t)NN * 4);
  int* gout    = (int*)alloc((size_t)EE * 4);
  unsigned char* msg = (unsigned char*)alloc((size_t)EE * 256);          // 102.4 MB
  size_t need_a = (size_t)(w - base);
  // tier A+ adds bf16 self buffer
  unsigned short* sbuf = (unsigned short*)alloc((size_t)NN * 256 * 2);   // 51.2 MB
  size_t need_ap = (size_t)(w - base);

  bool tierAP = ws_size >= need_ap;
  bool tierA  = ws_size >= need_a;
  bool tierB  = ws_size >= need_b;

  hipMemsetAsync(hist, 0, RR * 4, stream);
  hipMemsetAsync(deg, 0, (size_t)NN * 4, stream);

  if (tierA || tierAP) {
    k_prep1<true><<<1344, 256, 0, stream>>>(basis, coef, slw, etype, dst, in_feat,
                                            wpk, spk, hist, deg, featb);
    k_prep2<<<NSCAN + 1, 256, 0, stream>>>(hist, deg, cur, tdesc, bsum);
    k_prep3<<<NSCAN, 256, 0, stream>>>(deg, bsum, row_ptr, cur2);
    k_prep4<true><<<(EE + SCHUNK - 1) / SCHUNK, 256, 0, stream>>>(
        etype, src, dst, deg, cur, gsrc, gdst, ginv, cur2, gout);
    if (tierAP) {
      k_main<true><<<EGRID2 + SGRID, 256, 0, stream>>>(featb, wpk, spk, gsrc, ginv,
                                                       gout, tdesc, msg, out, sbuf);
      k_aggregate<true><<<(NN + 7) / 8, 256, 0, stream>>>(msg, row_ptr, sbuf, out);
    } else {
      k_main<false><<<EGRID2 + SGRID, 256, 0, stream>>>(featb, wpk, spk, gsrc, ginv,
                                                        gout, tdesc, msg, out, nullptr);
      k_aggregate<false><<<(NN + 7) / 8, 256, 0, stream>>>(msg, row_ptr, nullptr, out);
    }
  } else if (tierB) {
    k_prep1<true><<<1344, 256, 0, stream>>>(basis, coef, slw, etype, dst, in_feat,
                                            wpk, spk, hist, deg, featb);
    k_prep2<<<NSCAN + 1, 256, 0, stream>>>(hist, deg, cur, tdesc, bsum);
    k_prep4<false><<<(EE + SCHUNK - 1) / SCHUNK, 256, 0, stream>>>(
        etype, src, dst, deg, cur, gsrc, gdst, ginv, nullptr, nullptr);
    k_self_gemm<true><<<(NN + 63) / 64, 256, 0, stream>>>(in_feat, featb, spk, out);
    k_edge_gemmBC<1><<<MAXTILES, 256, 0, stream>>>(in_feat, featb, wpk, gsrc, gdst,
                                                   ginv, tdesc, out);
  } else {
    k_prep1<false><<<1344, 256, 0, stream>>>(basis, coef, slw, etype, dst, in_feat,
                                             wpk, spk, hist, deg, nullptr);
    k_prep2<<<NSCAN + 1, 256, 0, stream>>>(hist, deg, cur, tdesc, bsum);
    k_prep4<false><<<(EE + SCHUNK - 1) / SCHUNK, 256, 0, stream>>>(
        etype, src, dst, deg, cur, gsrc, gdst, ginv, nullptr, nullptr);
    k_self_gemm<false><<<(NN + 63) / 64, 256, 0, stream>>>(in_feat, nullptr, spk, out);
    k_edge_gemmBC<0><<<MAXTILES, 256, 0, stream>>>(in_feat, nullptr, wpk, gsrc, gdst,
                                                   ginv, tdesc, out);
  }
}